// Round 4
// baseline (2102.022 us; speedup 1.0000x reference)
//
#include <hip/hip_runtime.h>

using short8 = __attribute__((ext_vector_type(8))) short;
using f32x4  = __attribute__((ext_vector_type(4))) float;
typedef unsigned short u16;
typedef unsigned int   u32;
typedef unsigned long long u64;

constexpr int Bn = 256;   // batch
constexpr int Tn = 200;   // time steps
constexpr int Dn = 512;   // hidden size

__device__ __forceinline__ u16 f2bf(float x) {
  union { float f; unsigned u; } v; v.f = x;
  unsigned r = v.u + 0x7FFFu + ((v.u >> 16) & 1u);  // RNE
  return (u16)(r >> 16);
}
__device__ __forceinline__ float sigm(float x) { return 1.0f / (1.0f + __expf(-x)); }
__device__ __forceinline__ float tanhe(float x) { return 1.0f - 2.0f / (__expf(2.0f * x) + 1.0f); }

// ---------- prep: x f32 [B][T][D] -> xf fragment-major bf16 [mtile4][t200][rf4][kkd16][lane64][8] ----------
__global__ void cvt_x_frag(const float* __restrict__ x, u16* __restrict__ xf) {
  int i = blockIdx.x * 256 + threadIdx.x;          // exactly 3,276,800 lane-tasks
  int lane = i & 63;
  int kkd  = (i >> 6) & 15;
  int rf   = (i >> 10) & 3;
  int mt_t = i >> 12;                              // mtile*200 + t
  int t = mt_t % 200, mtile = mt_t / 200;
  int row = mtile * 64 + rf * 16 + (lane & 15);
  int k0  = kkd * 32 + (lane >> 4) * 8;
  const float* s = x + ((size_t)row * Tn + t) * Dn + k0;
  float4 v0 = *reinterpret_cast<const float4*>(s);
  float4 v1 = *reinterpret_cast<const float4*>(s + 4);
  short8 r;
  r[0]=(short)f2bf(v0.x); r[1]=(short)f2bf(v0.y); r[2]=(short)f2bf(v0.z); r[3]=(short)f2bf(v0.w);
  r[4]=(short)f2bf(v1.x); r[5]=(short)f2bf(v1.y); r[6]=(short)f2bf(v1.z); r[7]=(short)f2bf(v1.w);
  reinterpret_cast<short8*>(xf)[i] = r;
}

// ---------- prep: W [1024][2048] f32 -> Wf fragment-major bf16 [role2][dsl32][g4][kk32][lane64][8] ----------
__global__ void cvt_w_frag(const float* __restrict__ W0, const float* __restrict__ W1,
                           u16* __restrict__ Wf) {
  __shared__ u16 T[64][65];                        // [k][n] tile, padded
  int b = blockIdx.x;                              // 1024 blocks: role(2) x kt(16) x nt(32)
  int nt = b & 31, kt = (b >> 5) & 15, role = b >> 9;
  const float* W = role ? W1 : W0;
  int t = threadIdx.x;
  int k0 = kt * 64, n0 = nt * 64;
  int kr = t >> 6, nl = t & 63;
#pragma unroll
  for (int r = 0; r < 16; ++r) {
    int k = r * 4 + kr;
    T[k][nl] = f2bf(W[(size_t)(k0 + k) * 2048 + n0 + nl]);   // coalesced over n
  }
  __syncthreads();
  int g = n0 >> 9;
  int dslBase = (n0 & 511) >> 4;
  int kkBase  = k0 >> 5;
  int lane = t & 63, grp = t >> 6;
  int lr = lane & 15, lk = lane >> 4;
#pragma unroll
  for (int c = grp; c < 8; c += 4) {
    int dslL = c & 3, kkL = c >> 2;
    int dsl = dslBase + dslL, kk = kkBase + kkL;
    short8 v;
#pragma unroll
    for (int e = 0; e < 8; ++e)
      v[e] = (short)T[kkL * 32 + lk * 8 + e][dslL * 16 + lr];
    *reinterpret_cast<short8*>(Wf + ((((size_t)(role * 32 + dsl) * 4 + g) * 32 + kk) * 64 + lane) * 8) = v;
  }
}

#define MFMA16 __builtin_amdgcn_mfma_f32_16x16x32_bf16
#define GLOAD_LDS(g, l) __builtin_amdgcn_global_load_lds(                    \
    (const __attribute__((address_space(1))) void*)(g),                      \
    (__attribute__((address_space(3))) void*)(l), 16, 0, 0)

// coherent (LLC point-of-coherence) 4x16B load batch: bypasses L1+L2 via sc0 sc1
#define ISS4C(A0, A1, A2, A3, P)                                             \
  asm volatile("global_load_dwordx4 %0, %4, off sc0 sc1\n\t"                 \
               "global_load_dwordx4 %1, %4, off offset:1024 sc0 sc1\n\t"     \
               "global_load_dwordx4 %2, %4, off offset:2048 sc0 sc1\n\t"     \
               "global_load_dwordx4 %3, %4, off offset:3072 sc0 sc1"         \
               : "=v"(A0), "=v"(A1), "=v"(A2), "=v"(A3) : "v"(P))
// normal cached 4x16B load batch (iteration-private x data)
#define ISS4N(A0, A1, A2, A3, P)                                             \
  asm volatile("global_load_dwordx4 %0, %4, off\n\t"                         \
               "global_load_dwordx4 %1, %4, off offset:1024\n\t"             \
               "global_load_dwordx4 %2, %4, off offset:2048\n\t"             \
               "global_load_dwordx4 %3, %4, off offset:3072"                 \
               : "=v"(A0), "=v"(A1), "=v"(A2), "=v"(A3) : "v"(P))
// counted wait; sched_barrier(0x3F7) = everything EXCEPT MFMA may cross (rule #18)
#define WAITV(N)                                                             \
  asm volatile("s_waitcnt vmcnt(" #N ")");                                   \
  __builtin_amdgcn_sched_barrier(0x3F7)
#define MMK(av, kk) {                                                        \
    short8 w0 = *reinterpret_cast<const short8*>(WL + (kk) * 1024);          \
    short8 w1 = *reinterpret_cast<const short8*>(WL + 32768 + (kk) * 1024);  \
    short8 w2 = *reinterpret_cast<const short8*>(WL + 65536 + (kk) * 1024);  \
    short8 w3 = *reinterpret_cast<const short8*>(WL + 98304 + (kk) * 1024);  \
    ac0 = MFMA16(av, w0, ac0, 0, 0, 0);                                      \
    ac1 = MFMA16(av, w1, ac1, 0, 0, 0);                                      \
    ac2 = MFMA16(av, w2, ac2, 0, 0, 0);                                      \
    ac3 = MFMA16(av, w3, ac3, 0, 0, 0); }
// per-wave poll of own 64-wave group's flags (lane l watches member l)
#define POLL(tgtexpr) {                                                      \
    const int tgt_ = (tgtexpr); u32 fv_;                                     \
    do {                                                                     \
      asm volatile("global_load_dword %0, %1, off sc0 sc1\n\t"               \
                   "s_waitcnt vmcnt(0)" : "=v"(fv_) : "v"(fbw) : "memory");  \
    } while (!__all((int)fv_ >= tgt_));                                      \
  }
// post own flag (1 store per wave, after own vmcnt(0) h-drain)
#define FLAG(val) if (lane == 0) {                                           \
    u32 tv_ = (u32)(val);                                                    \
    asm volatile("global_store_dword %0, %1, off sc0 sc1" :: "v"(flagme), "v"(tv_) : "memory"); }
// role0: x-half of step (tstep)'s gate matmul; zeroes acc, leaves x-part accumulated
#define X_PHASE(tstep) {                                                     \
    const char* An_ = xfb + ((size_t)mtile * Tn + (tstep)) * 65536 + aoff;   \
    ISS4N(A0,A1,A2,A3,    An_);                                              \
    ISS4N(A4,A5,A6,A7,    An_ + 4096);                                       \
    ISS4N(A8,A9,A10,A11,  An_ + 8192);                                       \
    ISS4N(A12,A13,A14,A15,An_ + 12288);                                      \
    ac0 = z4; ac1 = z4; ac2 = z4; ac3 = z4;                                  \
    __builtin_amdgcn_s_setprio(1);                                           \
    WAITV(12); MMK(A0,0)  MMK(A1,1)  MMK(A2,2)  MMK(A3,3)                    \
    WAITV(8);  MMK(A4,4)  MMK(A5,5)  MMK(A6,6)  MMK(A7,7)                    \
    WAITV(4);  MMK(A8,8)  MMK(A9,9)  MMK(A10,10) MMK(A11,11)                 \
    WAITV(0);  MMK(A12,12) MMK(A13,13) MMK(A14,14) MMK(A15,15)               \
    __builtin_amdgcn_s_setprio(0); }

// ---------- persistent cooperative kernel: entire 200-step scan in ONE launch ----------
// 256 blocks x 256 threads, 1 block/CU. q=blk&7: role=q&1, mtile=q>>1, dsl=blk>>3.
// W staged into LDS ONCE. v4: ZERO intra-block barriers in the loop — the stg staging
// and the h fragment layout are both rf-partitioned, so each WAVE is an independent
// pipeline. Sync = 16 independent 64-wave groups (rf x mtile): per-wave LLC flag
// posted after own h-slice drain; per-wave 64-lane coalesced poll. role0 computes the
// x-half of the NEXT step's MMKs between flag-post and poll (h-independent work).
extern "C" __global__ void __launch_bounds__(256, 1)
rnn_persist(const u16* __restrict__ xf, const u16* __restrict__ Wf,
            const float* __restrict__ b0, const float* __restrict__ b1,
            const int* __restrict__ seq,
            u16* __restrict__ hf0, u16* __restrict__ hf1,
            u32* __restrict__ bar, float* __restrict__ out) {
  extern __shared__ __align__(16) char smem[];
  const int blk = blockIdx.x;
  const int q = blk & 7;
  const int role = q & 1;
  const int mtile = q >> 1;
  const int dsl = blk >> 3;
  const int tid = threadIdx.x;
  const int rf = tid >> 6, lane = tid & 63;

  // ---- one-time W staging: 32 direct global->LDS 16B ops per thread ----
  {
    const char* gsrc = reinterpret_cast<const char*>(Wf)
                     + (size_t)(role * 32 + dsl) * 131072 + tid * 16;
    char* lds = smem + tid * 16;
#pragma unroll
    for (int i = 0; i < 32; ++i)
      GLOAD_LDS(gsrc + i * 4096, lds + i * 4096);
  }

  const char* xfb = reinterpret_cast<const char*>(xf);
  const char* h0b = reinterpret_cast<const char*>(hf0);
  const char* h1b = reinterpret_cast<const char*>(hf1);
  const int aoff = rf * 16384 + lane * 16;
  const char* WL = smem + lane * 16;               // + g*32768 + kk*1024 (ds_read_b128)

  const int d0 = dsl * 16 + (lane & 15);
  const float* bias = role ? b1 : b0;
  const float bg0 = bias[d0], bg1 = bias[512 + d0], bg2 = bias[1024 + d0], bg3 = bias[1536 + d0];
  const int rowB = mtile * 64 + rf * 16 + (lane >> 4) * 4;
  int sl[4];
#pragma unroll
  for (int e = 0; e < 4; ++e) sl[e] = seq[rowB + e];

  // fragment-layout u16 offset of this thread's (rowB+e, d0) values in h buffers
  const int kkd = dsl >> 1;
  const int lane_t_base = ((((dsl & 1) << 1) | ((lane & 15) >> 3)) << 4) + (lane >> 4) * 4;
  const size_t hoff0 = (size_t)mtile * 32768 + (size_t)(rf * 16 + kkd) * 512
                     + (size_t)lane_t_base * 8 + (lane & 7);

  u16* hfSelf = role ? hf1 : hf0;
  u16* stg = reinterpret_cast<u16*>(smem + 131072);   // per-wave-private regions
  const size_t o8 = (size_t)((mtile * 4 + rf) * 16 + kkd) * 128
                  + ((dsl & 1) * 32 + (lane >> 1)) * 2 + (lane & 1);
  // per-wave flags: group = (rf, mtile) = 64 waves (both roles x 32 dsl)
  u32* flagme = bar + rf * 256 + mtile * 64 + role * 32 + dsl;
  const u32* fbw = bar + rf * 256 + mtile * 64 + lane;

  float creg[4]  = {0.f, 0.f, 0.f, 0.f};           // c-state in registers
  float hkeep[4] = {0.f, 0.f, 0.f, 0.f};           // copy-through h in registers
  const f32x4 z4 = {0.f, 0.f, 0.f, 0.f};

  __syncthreads();                                 // W resident in LDS from here on

  if (role == 0) {
    short8 A0,A1,A2,A3,A4,A5,A6,A7,A8,A9,A10,A11,A12,A13,A14,A15;
    short8 B0,B1,B2,B3,B4,B5,B6,B7,B8,B9,B10,B11,B12,B13,B14,B15;
    f32x4 ac0, ac1, ac2, ac3;
    X_PHASE(0);                                    // x-part of step 0 into acc
#pragma unroll 1
    for (int p = 0; p < Tn; ++p) {
      const int Rp = (p & 1) ^ 1, Wp = p & 1;
      // ---- h-half: B = h0[Rp] (LLC-coherent), 16 MMK ----
      const char* Bh = h0b + (size_t)Rp * 262144 + (size_t)mtile * 65536 + aoff;
      ISS4C(B0,B1,B2,B3,    Bh);
      ISS4C(B4,B5,B6,B7,    Bh + 4096);
      ISS4C(B8,B9,B10,B11,  Bh + 8192);
      ISS4C(B12,B13,B14,B15,Bh + 12288);
      __builtin_amdgcn_s_setprio(1);
      WAITV(12); MMK(B0,16) MMK(B1,17) MMK(B2,18) MMK(B3,19)
      WAITV(8);  MMK(B4,20) MMK(B5,21) MMK(B6,22) MMK(B7,23)
      WAITV(4);  MMK(B8,24) MMK(B9,25) MMK(B10,26) MMK(B11,27)
      WAITV(0);  MMK(B12,28) MMK(B13,29) MMK(B14,30) MMK(B15,31)
      __builtin_amdgcn_s_setprio(0);
      // ---- epilogue: gates (i,j,f,o), state update, stg (wave-private) ----
#pragma unroll
      for (int e = 0; e < 4; ++e) {
        float zi = ac0[e] + bg0, zj = ac1[e] + bg1, zf = ac2[e] + bg2, zo = ac3[e] + bg3;
        float cprev = creg[e];
        float cn = cprev * sigm(zf + 1.0f) + sigm(zi) * tanhe(zj);
        float hn = tanhe(cn) * sigm(zo);
        bool valid = p < sl[e];
        float hk = valid ? hn : hkeep[e];
        creg[e] = valid ? cn : cprev;
        hkeep[e] = hk;
        stg[rf * 256 + (((lane & 15) >> 3) * 16 + (lane >> 4) * 4 + e) * 8 + (lane & 7)] = f2bf(hk);
      }
      asm volatile("s_waitcnt lgkmcnt(0)" ::: "memory");   // own wave's stg writes done
      {  // wave-private gather -> coalesced LLC-coherent h0 store
        u64 v = reinterpret_cast<const u64*>(stg)[tid];
        u64* ha = reinterpret_cast<u64*>(hf0 + (size_t)Wp * 131072) + o8;
        asm volatile("global_store_dwordx2 %0, %1, off sc0 sc1" :: "v"(ha), "v"(v) : "memory");
      }
      asm volatile("s_waitcnt vmcnt(0)" ::: "memory");     // own h slice at LLC
      FLAG(p + 1);
      if (p == Tn - 1) break;                      // nothing left to wait for
      X_PHASE(p + 1);                              // h-independent work hides the wait
      POLL(p + 1);
    }
  } else {
    short8 A0,A1,A2,A3,A4,A5,A6,A7,A8,A9,A10,A11,A12,A13,A14,A15;
    short8 B0,B1,B2,B3,B4,B5,B6,B7,B8,B9,B10,B11,B12,B13,B14,B15;
#pragma unroll 1
    for (int p = 0; p <= Tn; ++p) {
      const int Rp = (p & 1) ^ 1, Wp = p & 1;
      float outv[4] = {0.f, 0.f, 0.f, 0.f};
      if (p >= 1) {
        const size_t hRp = (size_t)Rp * 262144 + (size_t)mtile * 65536;
        // residual h0n + A (h0) + B (h1): 36 LLC-coherent loads, counted ladder
        const char* hra = reinterpret_cast<const char*>(
            reinterpret_cast<const u16*>(h0b) + (size_t)Rp * 131072 + hoff0);
        u32 hn0, hn1, hn2, hn3;
        asm volatile("global_load_ushort %0, %4, off sc0 sc1\n\t"
                     "global_load_ushort %1, %4, off offset:16 sc0 sc1\n\t"
                     "global_load_ushort %2, %4, off offset:32 sc0 sc1\n\t"
                     "global_load_ushort %3, %4, off offset:48 sc0 sc1"
                     : "=v"(hn0), "=v"(hn1), "=v"(hn2), "=v"(hn3) : "v"(hra));
        const char* Alo = h0b + hRp + aoff;
        const char* Ahi = h1b + hRp + aoff;
        ISS4C(A0,A1,A2,A3,    Alo);
        ISS4C(A4,A5,A6,A7,    Alo + 4096);
        ISS4C(A8,A9,A10,A11,  Alo + 8192);
        ISS4C(A12,A13,A14,A15,Alo + 12288);
        ISS4C(B0,B1,B2,B3,    Ahi);
        ISS4C(B4,B5,B6,B7,    Ahi + 4096);
        ISS4C(B8,B9,B10,B11,  Ahi + 8192);
        ISS4C(B12,B13,B14,B15,Ahi + 12288);
        f32x4 ac0 = z4, ac1 = z4, ac2 = z4, ac3 = z4;
        __builtin_amdgcn_s_setprio(1);
        WAITV(28); MMK(A0,0)  MMK(A1,1)  MMK(A2,2)  MMK(A3,3)
        WAITV(24); MMK(A4,4)  MMK(A5,5)  MMK(A6,6)  MMK(A7,7)
        WAITV(20); MMK(A8,8)  MMK(A9,9)  MMK(A10,10) MMK(A11,11)
        WAITV(16); MMK(A12,12) MMK(A13,13) MMK(A14,14) MMK(A15,15)
        WAITV(12); MMK(B0,16) MMK(B1,17) MMK(B2,18) MMK(B3,19)
        WAITV(8);  MMK(B4,20) MMK(B5,21) MMK(B6,22) MMK(B7,23)
        WAITV(4);  MMK(B8,24) MMK(B9,25) MMK(B10,26) MMK(B11,27)
        WAITV(0);  MMK(B12,28) MMK(B13,29) MMK(B14,30) MMK(B15,31)
        __builtin_amdgcn_s_setprio(0);
        // epilogue
        const u32 hnv[4] = {hn0, hn1, hn2, hn3};
#pragma unroll
        for (int e = 0; e < 4; ++e) {
          float zi = ac0[e] + bg0, zj = ac1[e] + bg1, zf = ac2[e] + bg2, zo = ac3[e] + bg3;
          float cprev = creg[e];
          float cn = cprev * sigm(zf + 1.0f) + sigm(zi) * tanhe(zj);
          float hn = tanhe(cn) * sigm(zo);
          bool valid = (p - 1) < sl[e];
          float hk = valid ? hn : hkeep[e];
          creg[e] = valid ? cn : cprev;
          hkeep[e] = hk;
          stg[rf * 256 + (((lane & 15) >> 3) * 16 + (lane >> 4) * 4 + e) * 8 + (lane & 7)] = f2bf(hk);
          union { float f; u32 u; } hv; hv.u = hnv[e] << 16;               // h0n (bf16)
          outv[e] = valid ? (hn + hv.f) : 0.0f;
        }
        if (p < Tn) {                              // last step's h is never read
          asm volatile("s_waitcnt lgkmcnt(0)" ::: "memory");
          u64 v = reinterpret_cast<const u64*>(stg)[tid];
          u64* ha = reinterpret_cast<u64*>(hf1 + (size_t)Wp * 131072) + o8;
          asm volatile("global_store_dwordx2 %0, %1, off sc0 sc1" :: "v"(ha), "v"(v) : "memory");
          asm volatile("s_waitcnt vmcnt(0)" ::: "memory");
        }
        if (p == Tn) {
#pragma unroll
          for (int e = 0; e < 4; ++e)
            out[((size_t)(rowB + e) * Tn + (Tn - 1)) * Dn + d0] = outv[e];
          break;
        }
      }
      FLAG(p + 1);
      if (p >= 1) {                                // deferred out-stores (plain, L2-ack)
#pragma unroll
        for (int e = 0; e < 4; ++e)
          out[((size_t)(rowB + e) * Tn + (p - 1)) * Dn + d0] = outv[e];
      }
      POLL(p + 1);
    }
  }
}

// ---------- fallback per-step kernel (only used if cooperative launch is rejected) ----------
#define LDA(kk) (*reinterpret_cast<const short8*>(                           \
    (kk) < 16 ? (Alo + (size_t)(kk) * 1024) : (Ahi + (size_t)((kk) - 16) * 1024)))

extern "C" __global__ void __launch_bounds__(256, 1)
rnn_step(const u16* __restrict__ xf, const u16* __restrict__ Wf,
         const float* __restrict__ b0, const float* __restrict__ b1,
         const int* __restrict__ seq,
         u16* __restrict__ hf0, u16* __restrict__ hf1,
         float* __restrict__ cbuf, float* __restrict__ out, int p) {
  extern __shared__ __align__(16) char smem[];
  const int blk = blockIdx.x;
  const int role = blk & 1;
  const int mtile = (blk >> 1) & 3;
  const int dsl = blk >> 3;
  const bool act = role ? (p >= 1) : (p < Tn);
  if (!act) return;

  const int tid = threadIdx.x;
  const int rf = tid >> 6, lane = tid & 63;
  const int Rp = (p & 1) ^ 1, Wp = p & 1;
  const int tcur = role ? (p - 1) : p;

  {
    const char* gsrc = reinterpret_cast<const char*>(Wf)
                     + (size_t)(role * 32 + dsl) * 131072 + tid * 16;
    char* lds = smem + tid * 16;
#pragma unroll
    for (int i = 0; i < 32; ++i)
      GLOAD_LDS(gsrc + i * 4096, lds + i * 4096);
  }

  const char* h0base = reinterpret_cast<const char*>(hf0);
  const char* h1base = reinterpret_cast<const char*>(hf1);
  const size_t hRp = (size_t)Rp * 262144 + (size_t)mtile * 65536;
  const int aoff = rf * 16384 + lane * 16;

  const char* Alo;
  const char* Ahi;
  if (role == 0) {
    Alo = reinterpret_cast<const char*>(xf) + ((size_t)mtile * Tn + p) * 65536 + aoff;
    Ahi = h0base + hRp + aoff;
  } else {
    Alo = h0base + hRp + aoff;
    Ahi = h1base + hRp + aoff;
  }
  const char* WL = smem + lane * 16;

  short8 ca0 = LDA(0), ca1 = LDA(1), ca2 = LDA(2), ca3 = LDA(3);

  const int d0 = dsl * 16 + (lane & 15);
  const float* bias = role ? b1 : b0;
  const float bg0 = bias[d0], bg1 = bias[512 + d0], bg2 = bias[1024 + d0], bg3 = bias[1536 + d0];
  const int rowB = mtile * 64 + rf * 16 + (lane >> 4) * 4;
  int sl[4];
#pragma unroll
  for (int e = 0; e < 4; ++e) sl[e] = seq[rowB + e];

  const int kkd = dsl >> 1;
  const int lane_t_base = ((((dsl & 1) << 1) | ((lane & 15) >> 3)) << 4) + (lane >> 4) * 4;
  const size_t hoff0 = (size_t)mtile * 32768 + (size_t)(rf * 16 + kkd) * 512
                     + (size_t)lane_t_base * 8 + (lane & 7);

  u16 h0nraw[4];
  if (role) {
    const u16* hr = reinterpret_cast<const u16*>(h0base) + (size_t)Rp * 131072;
#pragma unroll
    for (int e = 0; e < 4; ++e) h0nraw[e] = hr[hoff0 + e * 8];
  }
  float* cme = cbuf + ((size_t)blk * 256 + tid) * 4;
  float cpre[4];
#pragma unroll
  for (int e = 0; e < 4; ++e) cpre[e] = cme[e];
  u16* hfSelf = role ? hf1 : hf0;
  const u16* hprev = hfSelf + (size_t)Rp * 131072;
  u16 hp16[4];
#pragma unroll
  for (int e = 0; e < 4; ++e) hp16[e] = hprev[hoff0 + e * 8];

  __syncthreads();

  f32x4 ac0 = {0.f,0.f,0.f,0.f}, ac1 = {0.f,0.f,0.f,0.f};
  f32x4 ac2 = {0.f,0.f,0.f,0.f}, ac3 = {0.f,0.f,0.f,0.f};
  short8 na0, na1, na2, na3;
#pragma unroll
  for (int c = 0; c < 8; ++c) {
    const int k0 = c * 4;
    if (c < 7) {
      na0 = LDA(k0 + 4); na1 = LDA(k0 + 5); na2 = LDA(k0 + 6); na3 = LDA(k0 + 7);
    }
#pragma unroll
    for (int j = 0; j < 4; ++j) {
      const int kk = k0 + j;
      short8 a = (j == 0) ? ca0 : (j == 1) ? ca1 : (j == 2) ? ca2 : ca3;
      short8 w0 = *reinterpret_cast<const short8*>(WL + kk * 1024);
      short8 w1 = *reinterpret_cast<const short8*>(WL + 32768 + kk * 1024);
      short8 w2 = *reinterpret_cast<const short8*>(WL + 65536 + kk * 1024);
      short8 w3 = *reinterpret_cast<const short8*>(WL + 98304 + kk * 1024);
      ac0 = MFMA16(a, w0, ac0, 0, 0, 0);
      ac1 = MFMA16(a, w1, ac1, 0, 0, 0);
      ac2 = MFMA16(a, w2, ac2, 0, 0, 0);
      ac3 = MFMA16(a, w3, ac3, 0, 0, 0);
    }
    ca0 = na0; ca1 = na1; ca2 = na2; ca3 = na3;
  }

  u16* stg = reinterpret_cast<u16*>(smem + 131072);
#pragma unroll
  for (int e = 0; e < 4; ++e) {
    float zi = ac0[e] + bg0, zj = ac1[e] + bg1, zf = ac2[e] + bg2, zo = ac3[e] + bg3;
    float cprev = cpre[e];
    float cn = cprev * sigm(zf + 1.0f) + sigm(zi) * tanhe(zj);
    float hn = tanhe(cn) * sigm(zo);
    bool valid = tcur < sl[e];
    union { float f; u32 u; } hp; hp.u = ((u32)hp16[e]) << 16;
    float hkeep = valid ? hn : hp.f;
    cme[e] = valid ? cn : cprev;
    stg[rf * 256 + (((lane & 15) >> 3) * 16 + (lane >> 4) * 4 + e) * 8 + (lane & 7)] = f2bf(hkeep);
    if (role) {
      union { float f; u32 u; } hv; hv.u = ((u32)h0nraw[e]) << 16;
      out[((size_t)(rowB + e) * Tn + tcur) * Dn + d0] = valid ? (hn + hv.f) : 0.0f;
    }
  }
  __syncthreads();
  {
    const int rft = tid >> 6, u = tid & 63;
    u64 v = reinterpret_cast<const u64*>(stg)[tid];
    u64* hw8 = reinterpret_cast<u64*>(hfSelf + (size_t)Wp * 131072);
    size_t o8 = (size_t)((mtile * 4 + rft) * 16 + kkd) * 128 + ((dsl & 1) * 32 + (u >> 1)) * 2 + (u & 1);
    hw8[o8] = v;
  }
}

extern "C" void kernel_launch(void* const* d_in, const int* in_sizes, int n_in,
                              void* d_out, int out_size, void* d_ws, size_t ws_size,
                              hipStream_t stream) {
  (void)in_sizes; (void)n_in; (void)out_size; (void)ws_size;
  const float* x  = (const float*)d_in[0];
  const int* seq  = (const int*)d_in[1];
  const float* W0 = (const float*)d_in[2];
  const float* b0 = (const float*)d_in[3];
  const float* W1 = (const float*)d_in[4];
  const float* b1 = (const float*)d_in[5];
  float* out = (float*)d_out;

  char* ws = (char*)d_ws;
  // ws layout (bytes):
  //   xf   : 0          .. 52,428,800   bf16 fragment-major x
  //   Wf   : 52,428,800 .. 60,817,408   bf16 fragment-major weights
  //   hf0  : 60,817,408 .. 61,341,696   bf16 frag h0 [2 parities]
  //   hf1  : 61,341,696 .. 61,865,984   bf16 frag h1 [2 parities]
  //   bar  : 61,865,984 ..              u32 per-wave flags [rf4][mtile4][role2][dsl32]
  //          (same region doubles as cbuf for the fallback path)
  u16*  xf   = (u16*)(ws);
  u16*  Wf   = (u16*)(ws + 52428800);
  u16*  hf0  = (u16*)(ws + 60817408);
  u16*  hf1  = (u16*)(ws + 61341696);
  u32*  bar  = (u32*)(ws + 61865984);
  float* cbuf = (float*)(ws + 61865984);

  hipMemsetAsync(ws + 60817408, 0, 2097152, stream);  // h frags (both parities) + flags
  hipLaunchKernelGGL(cvt_x_frag, dim3(12800), dim3(256), 0, stream, x, xf);
  hipLaunchKernelGGL(cvt_w_frag, dim3(1024), dim3(256), 0, stream, W0, W1, Wf);

  hipFuncSetAttribute((const void*)rnn_persist,
                      hipFuncAttributeMaxDynamicSharedMemorySize, 133120);
  hipFuncSetAttribute((const void*)rnn_step,
                      hipFuncAttributeMaxDynamicSharedMemorySize, 133120);

  void* args[] = { (void*)&xf, (void*)&Wf, (void*)&b0, (void*)&b1, (void*)&seq,
                   (void*)&hf0, (void*)&hf1, (void*)&bar, (void*)&out };
  hipError_t err = hipLaunchCooperativeKernel((void*)rnn_persist, dim3(256), dim3(256),
                                              args, 133120, stream);
  if (err != hipSuccess) {
    // fallback: proven multi-launch skewed pipeline
    for (int p = 0; p <= Tn; ++p) {
      hipLaunchKernelGGL(rnn_step, dim3(256), dim3(256), 133120, stream,
                         xf, Wf, b0, b1, seq, hf0, hf1, cbuf, out, p);
    }
  }
}

// Round 5
// 1826.238 us; speedup vs baseline: 1.1510x; 1.1510x over previous
//
#include <hip/hip_runtime.h>

using short8 = __attribute__((ext_vector_type(8))) short;
using f32x4  = __attribute__((ext_vector_type(4))) float;
typedef unsigned short u16;
typedef unsigned int   u32;
typedef unsigned long long u64;

constexpr int Bn = 256;   // batch
constexpr int Tn = 200;   // time steps
constexpr int Dn = 512;   // hidden size

__device__ __forceinline__ u16 f2bf(float x) {
  union { float f; unsigned u; } v; v.f = x;
  unsigned r = v.u + 0x7FFFu + ((v.u >> 16) & 1u);  // RNE
  return (u16)(r >> 16);
}
__device__ __forceinline__ float sigm(float x) { return 1.0f / (1.0f + __expf(-x)); }
__device__ __forceinline__ float tanhe(float x) { return 1.0f - 2.0f / (__expf(2.0f * x) + 1.0f); }

// ---------- prep: x f32 [B][T][D] -> xf fragment-major bf16 [mtile4][t200][rf4][kkd16][lane64][8] ----------
__global__ void cvt_x_frag(const float* __restrict__ x, u16* __restrict__ xf) {
  int i = blockIdx.x * 256 + threadIdx.x;          // exactly 3,276,800 lane-tasks
  int lane = i & 63;
  int kkd  = (i >> 6) & 15;
  int rf   = (i >> 10) & 3;
  int mt_t = i >> 12;                              // mtile*200 + t
  int t = mt_t % 200, mtile = mt_t / 200;
  int row = mtile * 64 + rf * 16 + (lane & 15);
  int k0  = kkd * 32 + (lane >> 4) * 8;
  const float* s = x + ((size_t)row * Tn + t) * Dn + k0;
  float4 v0 = *reinterpret_cast<const float4*>(s);
  float4 v1 = *reinterpret_cast<const float4*>(s + 4);
  short8 r;
  r[0]=(short)f2bf(v0.x); r[1]=(short)f2bf(v0.y); r[2]=(short)f2bf(v0.z); r[3]=(short)f2bf(v0.w);
  r[4]=(short)f2bf(v1.x); r[5]=(short)f2bf(v1.y); r[6]=(short)f2bf(v1.z); r[7]=(short)f2bf(v1.w);
  reinterpret_cast<short8*>(xf)[i] = r;
}

// ---------- prep: W [1024][2048] f32 -> Wf fragment-major bf16 [role2][dsl32][g4][kk32][lane64][8] ----------
__global__ void cvt_w_frag(const float* __restrict__ W0, const float* __restrict__ W1,
                           u16* __restrict__ Wf) {
  __shared__ u16 T[64][65];                        // [k][n] tile, padded
  int b = blockIdx.x;                              // 1024 blocks: role(2) x kt(16) x nt(32)
  int nt = b & 31, kt = (b >> 5) & 15, role = b >> 9;
  const float* W = role ? W1 : W0;
  int t = threadIdx.x;
  int k0 = kt * 64, n0 = nt * 64;
  int kr = t >> 6, nl = t & 63;
#pragma unroll
  for (int r = 0; r < 16; ++r) {
    int k = r * 4 + kr;
    T[k][nl] = f2bf(W[(size_t)(k0 + k) * 2048 + n0 + nl]);   // coalesced over n
  }
  __syncthreads();
  int g = n0 >> 9;
  int dslBase = (n0 & 511) >> 4;
  int kkBase  = k0 >> 5;
  int lane = t & 63, grp = t >> 6;
  int lr = lane & 15, lk = lane >> 4;
#pragma unroll
  for (int c = grp; c < 8; c += 4) {
    int dslL = c & 3, kkL = c >> 2;
    int dsl = dslBase + dslL, kk = kkBase + kkL;
    short8 v;
#pragma unroll
    for (int e = 0; e < 8; ++e)
      v[e] = (short)T[kkL * 32 + lk * 8 + e][dslL * 16 + lr];
    *reinterpret_cast<short8*>(Wf + ((((size_t)(role * 32 + dsl) * 4 + g) * 32 + kk) * 64 + lane) * 8) = v;
  }
}

#define MFMA16 __builtin_amdgcn_mfma_f32_16x16x32_bf16
#define GLOAD_LDS(g, l) __builtin_amdgcn_global_load_lds(                    \
    (const __attribute__((address_space(1))) void*)(g),                      \
    (__attribute__((address_space(3))) void*)(l), 16, 0, 0)

// coherent (LLC point-of-coherence) 4x16B load batch: bypasses L1+L2 via sc0 sc1
#define ISS4C(A0, A1, A2, A3, P)                                             \
  asm volatile("global_load_dwordx4 %0, %4, off sc0 sc1\n\t"                 \
               "global_load_dwordx4 %1, %4, off offset:1024 sc0 sc1\n\t"     \
               "global_load_dwordx4 %2, %4, off offset:2048 sc0 sc1\n\t"     \
               "global_load_dwordx4 %3, %4, off offset:3072 sc0 sc1"         \
               : "=v"(A0), "=v"(A1), "=v"(A2), "=v"(A3) : "v"(P))
// normal cached 4x16B load batch (iteration-private x data)
#define ISS4N(A0, A1, A2, A3, P)                                             \
  asm volatile("global_load_dwordx4 %0, %4, off\n\t"                         \
               "global_load_dwordx4 %1, %4, off offset:1024\n\t"             \
               "global_load_dwordx4 %2, %4, off offset:2048\n\t"             \
               "global_load_dwordx4 %3, %4, off offset:3072"                 \
               : "=v"(A0), "=v"(A1), "=v"(A2), "=v"(A3) : "v"(P))
// counted wait; sched_barrier(0x3F7) = everything EXCEPT MFMA may cross (rule #18):
// blocks the MFMA hoist hazard, lets W ds_reads pipeline across wait boundaries.
#define WAITV(N)                                                             \
  asm volatile("s_waitcnt vmcnt(" #N ")");                                   \
  __builtin_amdgcn_sched_barrier(0x3F7)
// one kk-step for TWO row-fragments sharing one set of W reads (the LDS-BW halving)
#define MMK2(alo, ahi, kk) {                                                 \
    short8 w0 = *reinterpret_cast<const short8*>(WL + (kk) * 1024);          \
    short8 w1 = *reinterpret_cast<const short8*>(WL + 32768 + (kk) * 1024);  \
    short8 w2 = *reinterpret_cast<const short8*>(WL + 65536 + (kk) * 1024);  \
    short8 w3 = *reinterpret_cast<const short8*>(WL + 98304 + (kk) * 1024);  \
    pa0 = MFMA16(alo, w0, pa0, 0, 0, 0); qa0 = MFMA16(ahi, w0, qa0, 0, 0, 0);\
    pa1 = MFMA16(alo, w1, pa1, 0, 0, 0); qa1 = MFMA16(ahi, w1, qa1, 0, 0, 0);\
    pa2 = MFMA16(alo, w2, pa2, 0, 0, 0); qa2 = MFMA16(ahi, w2, qa2, 0, 0, 0);\
    pa3 = MFMA16(alo, w3, pa3, 0, 0, 0); qa3 = MFMA16(ahi, w3, qa3, 0, 0, 0); }
// chunk = 4 kk x 2 rfrags (8 loads / 32 MFMA)
#define ISSN_SLOT(S, P) ISS4N(S##a0,S##a1,S##a2,S##a3,(P));                  \
                        ISS4N(S##b0,S##b1,S##b2,S##b3,(P)+16384);
#define ISSC_SLOT(S, P) ISS4C(S##a0,S##a1,S##a2,S##a3,(P));                  \
                        ISS4C(S##b0,S##b1,S##b2,S##b3,(P)+16384);
#define CONS_SLOT(S, KK) MMK2(S##a0,S##b0,(KK))   MMK2(S##a1,S##b1,(KK)+1)   \
                         MMK2(S##a2,S##b2,(KK)+2) MMK2(S##a3,S##b3,(KK)+3)
// block-level flag + wave0 poll (v2-proven)
#define POLL(tgtexpr) {                                                      \
    const int tgt_ = (tgtexpr); u32 fv_;                                     \
    do {                                                                     \
      asm volatile("global_load_dword %0, %1, off sc0 sc1\n\t"               \
                   "s_waitcnt vmcnt(0)" : "=v"(fv_) : "v"(fbw) : "memory");  \
    } while (!__all((int)fv_ >= tgt_));                                      \
  }
#define FLAG(val) {                                                          \
    u32 tv_ = (u32)(val);                                                    \
    asm volatile("global_store_dword %0, %1, off sc0 sc1" :: "v"(flagme), "v"(tv_) : "memory"); }

// ---------- persistent cooperative kernel: entire 200-step scan in ONE launch ----------
// v5: 256 blocks x 128 threads (2 waves), 1 block/CU. role=blk&1, mtile=(blk>>1)&3, dsl=blk>>3.
// Each wave owns TWO row-fragments (rfrag 2*wid, 2*wid+1): every W fragment read from LDS
// feeds 8 MFMAs instead of 4 -> LDS W traffic per CU halves (512KB -> 256KB per iter),
// which the v2 counters identified as the dominant per-iteration cost.
// Sync = v2's proven block-flag + wave0 poll; raw s_barrier (waves pre-drain own vmcnt).
extern "C" __global__ void __launch_bounds__(128, 1)
rnn_persist(const u16* __restrict__ xf, const u16* __restrict__ Wf,
            const float* __restrict__ b0, const float* __restrict__ b1,
            const int* __restrict__ seq,
            u16* __restrict__ hf0, u16* __restrict__ hf1,
            u32* __restrict__ bar, float* __restrict__ out) {
  extern __shared__ __align__(16) char smem[];
  const int blk = blockIdx.x;
  const int role = blk & 1;
  const int mtile = (blk >> 1) & 3;
  const int dsl = blk >> 3;
  const int tid = threadIdx.x;
  const int wid = tid >> 6, lane = tid & 63;
  const int rlo = wid * 2;                         // this wave's lower rfrag

  // ---- one-time W staging: 64 direct global->LDS 16B ops per thread (128 thr) ----
  {
    const char* gsrc = reinterpret_cast<const char*>(Wf)
                     + (size_t)(role * 32 + dsl) * 131072 + tid * 16;
    char* lds = smem + tid * 16;
#pragma unroll
    for (int i = 0; i < 64; ++i)
      GLOAD_LDS(gsrc + i * 2048, lds + i * 2048);
  }

  const char* xfb = reinterpret_cast<const char*>(xf);
  const char* h0b = reinterpret_cast<const char*>(hf0);
  const char* h1b = reinterpret_cast<const char*>(hf1);
  const char* WL = smem + lane * 16;               // + g*32768 + kk*1024 (ds_read_b128)

  const int d0 = dsl * 16 + (lane & 15);
  const float* bias = role ? b1 : b0;
  const float bg0 = bias[d0], bg1 = bias[512 + d0], bg2 = bias[1024 + d0], bg3 = bias[1536 + d0];
  const int rowB0 = mtile * 64 + rlo * 16 + (lane >> 4) * 4;
  const int rowB1 = rowB0 + 16;
  int sl0[4], sl1[4];
#pragma unroll
  for (int e = 0; e < 4; ++e) { sl0[e] = seq[rowB0 + e]; sl1[e] = seq[rowB1 + e]; }

  const int kkd = dsl >> 1;
  const int lane_t_base = ((((dsl & 1) << 1) | ((lane & 15) >> 3)) << 4) + (lane >> 4) * 4;
  const size_t hoffA = (size_t)mtile * 32768 + (size_t)(rlo * 16 + kkd) * 512
                     + (size_t)lane_t_base * 8 + (lane & 7);     // u16 units; rfrag+1 = +8192

  u16* stg = reinterpret_cast<u16*>(smem + 131072);    // per-wave-private regions
  const size_t o8A = (size_t)((mtile * 4 + rlo) * 16 + kkd) * 128
                   + ((dsl & 1) * 32 + (lane >> 1)) * 2 + (lane & 1);
  const size_t o8B = o8A + 2048;                        // next rfrag: +16*128 u64
  u32* flagme = bar + mtile * 64 + role * 32 + dsl;
  const u32* fbw = bar + mtile * 64 + lane;             // wave0 poll addresses

  float creg0[4] = {0.f,0.f,0.f,0.f}, creg1[4] = {0.f,0.f,0.f,0.f};
  float hk0[4]   = {0.f,0.f,0.f,0.f}, hk1[4]   = {0.f,0.f,0.f,0.f};
  const f32x4 z4 = {0.f, 0.f, 0.f, 0.f};

  __syncthreads();                                 // W resident in LDS from here on

#pragma unroll 1
  for (int p = 0; p <= Tn; ++p) {
    const int Rp = (p & 1) ^ 1, Wp = p & 1;
    float ov0[4] = {0.f,0.f,0.f,0.f}, ov1[4] = {0.f,0.f,0.f,0.f};
    const bool act = role ? (p >= 1) : (p < Tn);
    if (act) {
      const int tcur = role ? (p - 1) : p;
      const size_t hRp = (size_t)Rp * 262144 + (size_t)mtile * 65536;
      f32x4 pa0 = z4, pa1 = z4, pa2 = z4, pa3 = z4;  // rfrag rlo accumulators (i,j,f,o)
      f32x4 qa0 = z4, qa1 = z4, qa2 = z4, qa3 = z4;  // rfrag rlo+1 accumulators
      u32 hA0=0,hA1=0,hA2=0,hA3=0, hB0=0,hB1=0,hB2=0,hB3=0;
      short8 s0a0,s0a1,s0a2,s0a3,s0b0,s0b1,s0b2,s0b3;
      short8 s1a0,s1a1,s1a2,s1a3,s1b0,s1b1,s1b2,s1b3;
      short8 s2a0,s2a1,s2a2,s2a3,s2b0,s2b1,s2b2,s2b3;
      short8 s3a0,s3a1,s3a2,s3a3,s3b0,s3b1,s3b2,s3b3;

      if (role == 0) {
        // A = x (cached), B = h0 (LLC-coherent); rotating 4-slot chunked ladder
        const char* AX = xfb + ((size_t)mtile * Tn + p) * 65536 + rlo * 16384 + lane * 16;
        const char* AH = h0b + hRp + rlo * 16384 + lane * 16;
        ISSN_SLOT(s0, AX);         ISSN_SLOT(s1, AX + 4096);
        ISSN_SLOT(s2, AX + 8192);  ISSN_SLOT(s3, AX + 12288);
        WAITV(24); CONS_SLOT(s0, 0);  ISSC_SLOT(s0, AH);
        WAITV(24); CONS_SLOT(s1, 4);  ISSC_SLOT(s1, AH + 4096);
        WAITV(24); CONS_SLOT(s2, 8);  ISSC_SLOT(s2, AH + 8192);
        WAITV(24); CONS_SLOT(s3, 12); ISSC_SLOT(s3, AH + 12288);
        WAITV(24); CONS_SLOT(s0, 16);
        WAITV(16); CONS_SLOT(s1, 20);
        WAITV(8);  CONS_SLOT(s2, 24);
        WAITV(0);  CONS_SLOT(s3, 28);
      } else {
        // residual h0n (8 ushorts, oldest) + A = h0, B = h1 (all LLC-coherent)
        const char* hraA = h0b + (size_t)Rp * 262144 + hoffA * 2;
        const char* hraB = hraA + 16384;
        asm volatile("global_load_ushort %0, %4, off sc0 sc1\n\t"
                     "global_load_ushort %1, %4, off offset:16 sc0 sc1\n\t"
                     "global_load_ushort %2, %4, off offset:32 sc0 sc1\n\t"
                     "global_load_ushort %3, %4, off offset:48 sc0 sc1"
                     : "=v"(hA0), "=v"(hA1), "=v"(hA2), "=v"(hA3) : "v"(hraA));
        asm volatile("global_load_ushort %0, %4, off sc0 sc1\n\t"
                     "global_load_ushort %1, %4, off offset:16 sc0 sc1\n\t"
                     "global_load_ushort %2, %4, off offset:32 sc0 sc1\n\t"
                     "global_load_ushort %3, %4, off offset:48 sc0 sc1"
                     : "=v"(hB0), "=v"(hB1), "=v"(hB2), "=v"(hB3) : "v"(hraB));
        const char* AA = h0b + hRp + rlo * 16384 + lane * 16;
        const char* AB = h1b + hRp + rlo * 16384 + lane * 16;
        ISSC_SLOT(s0, AA);         ISSC_SLOT(s1, AA + 4096);
        ISSC_SLOT(s2, AA + 8192);  ISSC_SLOT(s3, AA + 12288);
        WAITV(24); CONS_SLOT(s0, 0);  ISSC_SLOT(s0, AB);
        WAITV(24); CONS_SLOT(s1, 4);  ISSC_SLOT(s1, AB + 4096);
        WAITV(24); CONS_SLOT(s2, 8);  ISSC_SLOT(s2, AB + 8192);
        WAITV(24); CONS_SLOT(s3, 12); ISSC_SLOT(s3, AB + 12288);
        WAITV(24); CONS_SLOT(s0, 16);
        WAITV(16); CONS_SLOT(s1, 20);
        WAITV(8);  CONS_SLOT(s2, 24);
        WAITV(0);  CONS_SLOT(s3, 28);
      }

      // epilogue for both rfrags: gates (i,j,f,o), state update from registers
      const u32 hAv[4] = {hA0, hA1, hA2, hA3};
      const u32 hBv[4] = {hB0, hB1, hB2, hB3};
#pragma unroll
      for (int e = 0; e < 4; ++e) {
        {
          float zi = pa0[e] + bg0, zj = pa1[e] + bg1, zf = pa2[e] + bg2, zo = pa3[e] + bg3;
          float cp = creg0[e];
          float cn = cp * sigm(zf + 1.0f) + sigm(zi) * tanhe(zj);
          float hn = tanhe(cn) * sigm(zo);
          bool valid = tcur < sl0[e];
          float hk = valid ? hn : hk0[e];
          creg0[e] = valid ? cn : cp;
          hk0[e] = hk;
          stg[rlo * 256 + (((lane & 15) >> 3) * 16 + (lane >> 4) * 4 + e) * 8 + (lane & 7)] = f2bf(hk);
          if (role) { union { float f; u32 u; } hv; hv.u = hAv[e] << 16;
                      ov0[e] = valid ? (hn + hv.f) : 0.0f; }
        }
        {
          float zi = qa0[e] + bg0, zj = qa1[e] + bg1, zf = qa2[e] + bg2, zo = qa3[e] + bg3;
          float cp = creg1[e];
          float cn = cp * sigm(zf + 1.0f) + sigm(zi) * tanhe(zj);
          float hn = tanhe(cn) * sigm(zo);
          bool valid = tcur < sl1[e];
          float hk = valid ? hn : hk1[e];
          creg1[e] = valid ? cn : cp;
          hk1[e] = hk;
          stg[(rlo + 1) * 256 + (((lane & 15) >> 3) * 16 + (lane >> 4) * 4 + e) * 8 + (lane & 7)] = f2bf(hk);
          if (role) { union { float f; u32 u; } hv; hv.u = hBv[e] << 16;
                      ov1[e] = valid ? (hn + hv.f) : 0.0f; }
        }
      }
      if (!role || p < Tn) {                        // last role1 h is never read
        asm volatile("s_waitcnt lgkmcnt(0)" ::: "memory");  // own wave's stg writes done
        u16* hw = (role ? hf1 : hf0) + (size_t)Wp * 131072;
        u64 v0 = reinterpret_cast<const u64*>(stg)[rlo * 64 + lane];
        u64 v1 = reinterpret_cast<const u64*>(stg)[(rlo + 1) * 64 + lane];
        u64* haA = reinterpret_cast<u64*>(hw) + o8A;
        u64* haB = reinterpret_cast<u64*>(hw) + o8B;
        asm volatile("global_store_dwordx2 %0, %1, off sc0 sc1" :: "v"(haA), "v"(v0) : "memory");
        asm volatile("global_store_dwordx2 %0, %1, off sc0 sc1" :: "v"(haB), "v"(v1) : "memory");
        asm volatile("s_waitcnt vmcnt(0)" ::: "memory");     // own h slices at LLC
      }
    }

    if (p == Tn) {                                 // final step: direct out, no barrier
      if (role) {
#pragma unroll
        for (int e = 0; e < 4; ++e) {
          out[((size_t)(rowB0 + e) * Tn + (Tn - 1)) * Dn + d0] = ov0[e];
          out[((size_t)(rowB1 + e) * Tn + (Tn - 1)) * Dn + d0] = ov1[e];
        }
      }
      break;
    }

    // ---- per-mtile 64-block barrier: flag + wave0 poll; raw s_barrier (no forced drain) ----
    __builtin_amdgcn_s_barrier();                  // both waves' h-stores drained (explicit vmcnt0)
    if (tid == 0) FLAG(p + 1);
    if (role && p >= 1) {                          // deferred out-stores: off the flag chain
#pragma unroll
      for (int e = 0; e < 4; ++e) {
        out[((size_t)(rowB0 + e) * Tn + (p - 1)) * Dn + d0] = ov0[e];
        out[((size_t)(rowB1 + e) * Tn + (p - 1)) * Dn + d0] = ov1[e];
      }
    }
    if (tid < 64) POLL(p + 1);                     // wave0: lane l watches group block l
    __builtin_amdgcn_s_barrier();                  // release wave1
  }
}

// ---------- fallback per-step kernel (only used if cooperative launch is rejected) ----------
#define MMK(av, kk) {                                                        \
    short8 w0 = *reinterpret_cast<const short8*>(WL + (kk) * 1024);          \
    short8 w1 = *reinterpret_cast<const short8*>(WL + 32768 + (kk) * 1024);  \
    short8 w2 = *reinterpret_cast<const short8*>(WL + 65536 + (kk) * 1024);  \
    short8 w3 = *reinterpret_cast<const short8*>(WL + 98304 + (kk) * 1024);  \
    ac0 = MFMA16(av, w0, ac0, 0, 0, 0);                                      \
    ac1 = MFMA16(av, w1, ac1, 0, 0, 0);                                      \
    ac2 = MFMA16(av, w2, ac2, 0, 0, 0);                                      \
    ac3 = MFMA16(av, w3, ac3, 0, 0, 0); }
#define LDA(kk) (*reinterpret_cast<const short8*>(                           \
    (kk) < 16 ? (Alo + (size_t)(kk) * 1024) : (Ahi + (size_t)((kk) - 16) * 1024)))

extern "C" __global__ void __launch_bounds__(256, 1)
rnn_step(const u16* __restrict__ xf, const u16* __restrict__ Wf,
         const float* __restrict__ b0, const float* __restrict__ b1,
         const int* __restrict__ seq,
         u16* __restrict__ hf0, u16* __restrict__ hf1,
         float* __restrict__ cbuf, float* __restrict__ out, int p) {
  extern __shared__ __align__(16) char smem[];
  const int blk = blockIdx.x;
  const int role = blk & 1;
  const int mtile = (blk >> 1) & 3;
  const int dsl = blk >> 3;
  const bool act = role ? (p >= 1) : (p < Tn);
  if (!act) return;

  const int tid = threadIdx.x;
  const int rf = tid >> 6, lane = tid & 63;
  const int Rp = (p & 1) ^ 1, Wp = p & 1;
  const int tcur = role ? (p - 1) : p;

  {
    const char* gsrc = reinterpret_cast<const char*>(Wf)
                     + (size_t)(role * 32 + dsl) * 131072 + tid * 16;
    char* lds = smem + tid * 16;
#pragma unroll
    for (int i = 0; i < 32; ++i)
      GLOAD_LDS(gsrc + i * 4096, lds + i * 4096);
  }

  const char* h0base = reinterpret_cast<const char*>(hf0);
  const char* h1base = reinterpret_cast<const char*>(hf1);
  const size_t hRp = (size_t)Rp * 262144 + (size_t)mtile * 65536;
  const int aoff = rf * 16384 + lane * 16;

  const char* Alo;
  const char* Ahi;
  if (role == 0) {
    Alo = reinterpret_cast<const char*>(xf) + ((size_t)mtile * Tn + p) * 65536 + aoff;
    Ahi = h0base + hRp + aoff;
  } else {
    Alo = h0base + hRp + aoff;
    Ahi = h1base + hRp + aoff;
  }
  const char* WL = smem + lane * 16;

  short8 ca0 = LDA(0), ca1 = LDA(1), ca2 = LDA(2), ca3 = LDA(3);

  const int d0 = dsl * 16 + (lane & 15);
  const float* bias = role ? b1 : b0;
  const float bg0 = bias[d0], bg1 = bias[512 + d0], bg2 = bias[1024 + d0], bg3 = bias[1536 + d0];
  const int rowB = mtile * 64 + rf * 16 + (lane >> 4) * 4;
  int sl[4];
#pragma unroll
  for (int e = 0; e < 4; ++e) sl[e] = seq[rowB + e];

  const int kkd = dsl >> 1;
  const int lane_t_base = ((((dsl & 1) << 1) | ((lane & 15) >> 3)) << 4) + (lane >> 4) * 4;
  const size_t hoff0 = (size_t)mtile * 32768 + (size_t)(rf * 16 + kkd) * 512
                     + (size_t)lane_t_base * 8 + (lane & 7);

  u16 h0nraw[4];
  if (role) {
    const u16* hr = reinterpret_cast<const u16*>(h0base) + (size_t)Rp * 131072;
#pragma unroll
    for (int e = 0; e < 4; ++e) h0nraw[e] = hr[hoff0 + e * 8];
  }
  float* cme = cbuf + ((size_t)blk * 256 + tid) * 4;
  float cpre[4];
#pragma unroll
  for (int e = 0; e < 4; ++e) cpre[e] = cme[e];
  u16* hfSelf = role ? hf1 : hf0;
  const u16* hprev = hfSelf + (size_t)Rp * 131072;
  u16 hp16[4];
#pragma unroll
  for (int e = 0; e < 4; ++e) hp16[e] = hprev[hoff0 + e * 8];

  __syncthreads();

  f32x4 ac0 = {0.f,0.f,0.f,0.f}, ac1 = {0.f,0.f,0.f,0.f};
  f32x4 ac2 = {0.f,0.f,0.f,0.f}, ac3 = {0.f,0.f,0.f,0.f};
  short8 na0, na1, na2, na3;
#pragma unroll
  for (int c = 0; c < 8; ++c) {
    const int k0 = c * 4;
    if (c < 7) {
      na0 = LDA(k0 + 4); na1 = LDA(k0 + 5); na2 = LDA(k0 + 6); na3 = LDA(k0 + 7);
    }
#pragma unroll
    for (int j = 0; j < 4; ++j) {
      const int kk = k0 + j;
      short8 a = (j == 0) ? ca0 : (j == 1) ? ca1 : (j == 2) ? ca2 : ca3;
      MMK(a, kk)
    }
    ca0 = na0; ca1 = na1; ca2 = na2; ca3 = na3;
  }

  u16* stg = reinterpret_cast<u16*>(smem + 131072);
#pragma unroll
  for (int e = 0; e < 4; ++e) {
    float zi = ac0[e] + bg0, zj = ac1[e] + bg1, zf = ac2[e] + bg2, zo = ac3[e] + bg3;
    float cprev = cpre[e];
    float cn = cprev * sigm(zf + 1.0f) + sigm(zi) * tanhe(zj);
    float hn = tanhe(cn) * sigm(zo);
    bool valid = tcur < sl[e];
    union { float f; u32 u; } hp; hp.u = ((u32)hp16[e]) << 16;
    float hkeep = valid ? hn : hp.f;
    cme[e] = valid ? cn : cprev;
    stg[rf * 256 + (((lane & 15) >> 3) * 16 + (lane >> 4) * 4 + e) * 8 + (lane & 7)] = f2bf(hkeep);
    if (role) {
      union { float f; u32 u; } hv; hv.u = ((u32)h0nraw[e]) << 16;
      out[((size_t)(rowB + e) * Tn + tcur) * Dn + d0] = valid ? (hn + hv.f) : 0.0f;
    }
  }
  __syncthreads();
  {
    const int rft = tid >> 6, u = tid & 63;
    u64 v = reinterpret_cast<const u64*>(stg)[tid];
    u64* hw8 = reinterpret_cast<u64*>(hfSelf + (size_t)Wp * 131072);
    size_t o8 = (size_t)((mtile * 4 + rft) * 16 + kkd) * 128 + ((dsl & 1) * 32 + (u >> 1)) * 2 + (u & 1);
    hw8[o8] = v;
  }
}

extern "C" void kernel_launch(void* const* d_in, const int* in_sizes, int n_in,
                              void* d_out, int out_size, void* d_ws, size_t ws_size,
                              hipStream_t stream) {
  (void)in_sizes; (void)n_in; (void)out_size; (void)ws_size;
  const float* x  = (const float*)d_in[0];
  const int* seq  = (const int*)d_in[1];
  const float* W0 = (const float*)d_in[2];
  const float* b0 = (const float*)d_in[3];
  const float* W1 = (const float*)d_in[4];
  const float* b1 = (const float*)d_in[5];
  float* out = (float*)d_out;

  char* ws = (char*)d_ws;
  // ws layout (bytes):
  //   xf   : 0          .. 52,428,800   bf16 fragment-major x
  //   Wf   : 52,428,800 .. 60,817,408   bf16 fragment-major weights
  //   hf0  : 60,817,408 .. 61,341,696   bf16 frag h0 [2 parities]
  //   hf1  : 61,341,696 .. 61,865,984   bf16 frag h1 [2 parities]
  //   bar  : 61,865,984 ..              u32 flags (4 mtiles x 64 blocks)
  //          (same region doubles as cbuf for the fallback path)
  u16*  xf   = (u16*)(ws);
  u16*  Wf   = (u16*)(ws + 52428800);
  u16*  hf0  = (u16*)(ws + 60817408);
  u16*  hf1  = (u16*)(ws + 61341696);
  u32*  bar  = (u32*)(ws + 61865984);
  float* cbuf = (float*)(ws + 61865984);

  hipMemsetAsync(ws + 60817408, 0, 2097152, stream);  // h frags (both parities) + flags
  hipLaunchKernelGGL(cvt_x_frag, dim3(12800), dim3(256), 0, stream, x, xf);
  hipLaunchKernelGGL(cvt_w_frag, dim3(1024), dim3(256), 0, stream, W0, W1, Wf);

  hipFuncSetAttribute((const void*)rnn_persist,
                      hipFuncAttributeMaxDynamicSharedMemorySize, 133120);
  hipFuncSetAttribute((const void*)rnn_step,
                      hipFuncAttributeMaxDynamicSharedMemorySize, 133120);

  void* args[] = { (void*)&xf, (void*)&Wf, (void*)&b0, (void*)&b1, (void*)&seq,
                   (void*)&hf0, (void*)&hf1, (void*)&bar, (void*)&out };
  hipError_t err = hipLaunchCooperativeKernel((void*)rnn_persist, dim3(256), dim3(128),
                                              args, 133120, stream);
  if (err != hipSuccess) {
    // fallback: proven multi-launch skewed pipeline
    for (int p = 0; p <= Tn; ++p) {
      hipLaunchKernelGGL(rnn_step, dim3(256), dim3(256), 133120, stream,
                         xf, Wf, b0, b1, seq, hf0, hf1, cbuf, out, p);
    }
  }
}

// Round 6
// 1273.187 us; speedup vs baseline: 1.6510x; 1.4344x over previous
//
#include <hip/hip_runtime.h>

using short8 = __attribute__((ext_vector_type(8))) short;
using f32x4  = __attribute__((ext_vector_type(4))) float;
typedef unsigned short u16;
typedef unsigned int   u32;
typedef unsigned long long u64;

constexpr int Bn = 256;   // batch
constexpr int Tn = 200;   // time steps
constexpr int Dn = 512;   // hidden size

__device__ __forceinline__ u16 f2bf(float x) {
  union { float f; unsigned u; } v; v.f = x;
  unsigned r = v.u + 0x7FFFu + ((v.u >> 16) & 1u);  // RNE
  return (u16)(r >> 16);
}
__device__ __forceinline__ float sigm(float x) { return 1.0f / (1.0f + __expf(-x)); }
__device__ __forceinline__ float tanhe(float x) { return 1.0f - 2.0f / (__expf(2.0f * x) + 1.0f); }

// ---------- prep: x f32 [B][T][D] -> xf fragment-major bf16 [mtile4][t200][rf4][kkd16][lane64][8] ----------
__global__ void cvt_x_frag(const float* __restrict__ x, u16* __restrict__ xf) {
  int i = blockIdx.x * 256 + threadIdx.x;          // exactly 3,276,800 lane-tasks
  int lane = i & 63;
  int kkd  = (i >> 6) & 15;
  int rf   = (i >> 10) & 3;
  int mt_t = i >> 12;                              // mtile*200 + t
  int t = mt_t % 200, mtile = mt_t / 200;
  int row = mtile * 64 + rf * 16 + (lane & 15);
  int k0  = kkd * 32 + (lane >> 4) * 8;
  const float* s = x + ((size_t)row * Tn + t) * Dn + k0;
  float4 v0 = *reinterpret_cast<const float4*>(s);
  float4 v1 = *reinterpret_cast<const float4*>(s + 4);
  short8 r;
  r[0]=(short)f2bf(v0.x); r[1]=(short)f2bf(v0.y); r[2]=(short)f2bf(v0.z); r[3]=(short)f2bf(v0.w);
  r[4]=(short)f2bf(v1.x); r[5]=(short)f2bf(v1.y); r[6]=(short)f2bf(v1.z); r[7]=(short)f2bf(v1.w);
  reinterpret_cast<short8*>(xf)[i] = r;
}

// ---------- prep: W [1024][2048] f32 -> Wf fragment-major bf16 [role2][dsl32][g4][kk32][lane64][8] ----------
__global__ void cvt_w_frag(const float* __restrict__ W0, const float* __restrict__ W1,
                           u16* __restrict__ Wf) {
  __shared__ u16 T[64][65];                        // [k][n] tile, padded
  int b = blockIdx.x;                              // 1024 blocks: role(2) x kt(16) x nt(32)
  int nt = b & 31, kt = (b >> 5) & 15, role = b >> 9;
  const float* W = role ? W1 : W0;
  int t = threadIdx.x;
  int k0 = kt * 64, n0 = nt * 64;
  int kr = t >> 6, nl = t & 63;
#pragma unroll
  for (int r = 0; r < 16; ++r) {
    int k = r * 4 + kr;
    T[k][nl] = f2bf(W[(size_t)(k0 + k) * 2048 + n0 + nl]);   // coalesced over n
  }
  __syncthreads();
  int g = n0 >> 9;
  int dslBase = (n0 & 511) >> 4;
  int kkBase  = k0 >> 5;
  int lane = t & 63, grp = t >> 6;
  int lr = lane & 15, lk = lane >> 4;
#pragma unroll
  for (int c = grp; c < 8; c += 4) {
    int dslL = c & 3, kkL = c >> 2;
    int dsl = dslBase + dslL, kk = kkBase + kkL;
    short8 v;
#pragma unroll
    for (int e = 0; e < 8; ++e)
      v[e] = (short)T[kkL * 32 + lk * 8 + e][dslL * 16 + lr];
    *reinterpret_cast<short8*>(Wf + ((((size_t)(role * 32 + dsl) * 4 + g) * 32 + kk) * 64 + lane) * 8) = v;
  }
}

#define MFMA16 __builtin_amdgcn_mfma_f32_16x16x32_bf16
#define GLOAD_LDS(g, l) __builtin_amdgcn_global_load_lds(                    \
    (const __attribute__((address_space(1))) void*)(g),                      \
    (__attribute__((address_space(3))) void*)(l), 16, 0, 0)

// coherent (LLC point-of-coherence) 4x16B load batch: bypasses L1+L2 via sc0 sc1
#define ISS4C(A0, A1, A2, A3, P)                                             \
  asm volatile("global_load_dwordx4 %0, %4, off sc0 sc1\n\t"                 \
               "global_load_dwordx4 %1, %4, off offset:1024 sc0 sc1\n\t"     \
               "global_load_dwordx4 %2, %4, off offset:2048 sc0 sc1\n\t"     \
               "global_load_dwordx4 %3, %4, off offset:3072 sc0 sc1"         \
               : "=v"(A0), "=v"(A1), "=v"(A2), "=v"(A3) : "v"(P))
// normal cached 4x16B load batch (iteration-private x data)
#define ISS4N(A0, A1, A2, A3, P)                                             \
  asm volatile("global_load_dwordx4 %0, %4, off\n\t"                         \
               "global_load_dwordx4 %1, %4, off offset:1024\n\t"             \
               "global_load_dwordx4 %2, %4, off offset:2048\n\t"             \
               "global_load_dwordx4 %3, %4, off offset:3072"                 \
               : "=v"(A0), "=v"(A1), "=v"(A2), "=v"(A3) : "v"(P))
// counted wait + scheduling fence (v2-exact: MFMA must not hoist above the wait)
#define WAITV(N)                                                             \
  asm volatile("s_waitcnt vmcnt(" #N ")" ::: "memory");                      \
  __builtin_amdgcn_sched_barrier(0)
#define MMK(av, kk) {                                                        \
    short8 w0 = *reinterpret_cast<const short8*>(WL + (kk) * 1024);          \
    short8 w1 = *reinterpret_cast<const short8*>(WL + 32768 + (kk) * 1024);  \
    short8 w2 = *reinterpret_cast<const short8*>(WL + 65536 + (kk) * 1024);  \
    short8 w3 = *reinterpret_cast<const short8*>(WL + 98304 + (kk) * 1024);  \
    ac0 = MFMA16(av, w0, ac0, 0, 0, 0);                                      \
    ac1 = MFMA16(av, w1, ac1, 0, 0, 0);                                      \
    ac2 = MFMA16(av, w2, ac2, 0, 0, 0);                                      \
    ac3 = MFMA16(av, w3, ac3, 0, 0, 0); }

// ---------- persistent cooperative kernel: entire 200-step scan in ONE launch ----------
// v6 = v2 (proven 1257us) + three serial-chain deltas, nothing else:
//  (a) post-epilogue __syncthreads -> per-wave lgkmcnt(0) (stg staging is wave-private:
//      wave rf writes u16[rf*256..rf*256+256), gather reads u64[tid] = same range);
//  (b) role1 out-stores moved from epilogue to after the flag store, so the h-drain
//      vmcnt(0) no longer waits on 4 scattered HBM stores (stale-store vmcnt accounting:
//      4 oldest stores shift every WAITV(N) target by exactly the 4 that retire first);
//  (c) the two remaining __syncthreads -> raw s_barrier (each wave already drained its
//      own vmcnt; no redundant full drain on the serial chain).
extern "C" __global__ void __launch_bounds__(256, 1)
rnn_persist(const u16* __restrict__ xf, const u16* __restrict__ Wf,
            const float* __restrict__ b0, const float* __restrict__ b1,
            const int* __restrict__ seq,
            u16* __restrict__ hf0, u16* __restrict__ hf1,
            u32* __restrict__ bar, float* __restrict__ out) {
  extern __shared__ __align__(16) char smem[];
  const int blk = blockIdx.x;
  const int q = blk & 7;
  const int role = q & 1;
  const int mtile = q >> 1;
  const int dsl = blk >> 3;
  const int tid = threadIdx.x;
  const int rf = tid >> 6, lane = tid & 63;

  // ---- one-time W staging: 32 direct global->LDS 16B ops per thread ----
  {
    const char* gsrc = reinterpret_cast<const char*>(Wf)
                     + (size_t)(role * 32 + dsl) * 131072 + tid * 16;
    char* lds = smem + tid * 16;
#pragma unroll
    for (int i = 0; i < 32; ++i)
      GLOAD_LDS(gsrc + i * 4096, lds + i * 4096);
  }

  const char* xfb = reinterpret_cast<const char*>(xf);
  const char* h0b = reinterpret_cast<const char*>(hf0);
  const char* h1b = reinterpret_cast<const char*>(hf1);
  const int aoff = rf * 16384 + lane * 16;
  const char* WL = smem + lane * 16;               // + g*32768 + kk*1024 (ds_read_b128)

  const int d0 = dsl * 16 + (lane & 15);
  const float* bias = role ? b1 : b0;
  const float bg0 = bias[d0], bg1 = bias[512 + d0], bg2 = bias[1024 + d0], bg3 = bias[1536 + d0];
  const int rowB = mtile * 64 + rf * 16 + (lane >> 4) * 4;
  int sl[4];
#pragma unroll
  for (int e = 0; e < 4; ++e) sl[e] = seq[rowB + e];

  // fragment-layout u16 offset of this thread's (rowB+e, d0) values in h buffers
  const int kkd = dsl >> 1;
  const int lane_t_base = ((((dsl & 1) << 1) | ((lane & 15) >> 3)) << 4) + (lane >> 4) * 4;
  const size_t hoff0 = (size_t)mtile * 32768 + (size_t)(rf * 16 + kkd) * 512
                     + (size_t)lane_t_base * 8 + (lane & 7);

  u16* hfSelf = role ? hf1 : hf0;
  u16* stg = reinterpret_cast<u16*>(smem + 131072);    // wave-private regions
  const size_t o8 = (size_t)((mtile * 4 + rf) * 16 + kkd) * 128
                  + ((dsl & 1) * 32 + (lane >> 1)) * 2 + (lane & 1);
  u32* flagme = bar + mtile * 64 + role * 32 + dsl;
  const u32* fb = bar + mtile * 64 + tid;          // poll address (tid<64 only)

  float creg[4]  = {0.f, 0.f, 0.f, 0.f};           // c-state in registers
  float hkeep[4] = {0.f, 0.f, 0.f, 0.f};           // copy-through h in registers

  __syncthreads();                                 // W resident in LDS from here on

#pragma unroll 1
  for (int p = 0; p <= Tn; ++p) {
    const bool act = role ? (p >= 1) : (p < Tn);
    const int Rp = (p & 1) ^ 1, Wp = p & 1;
    float outv[4] = {0.f, 0.f, 0.f, 0.f};
    if (act) {
      const int tcur = role ? (p - 1) : p;
      const size_t hRp = (size_t)Rp * 262144 + (size_t)mtile * 65536;
      const char* Alo = (role == 0)
          ? xfb + ((size_t)mtile * Tn + p) * 65536 + aoff
          : h0b + hRp + aoff;
      const char* Ahi = (role == 0) ? h0b + hRp + aoff : h1b + hRp + aoff;

      // residual h0n (role1 consumes; role0 issues harmlessly for uniform vmcnt counting)
      const char* hra = reinterpret_cast<const char*>(
          reinterpret_cast<const u16*>(h0b) + (size_t)Rp * 131072 + hoff0);
      u32 hn0, hn1, hn2, hn3;
      asm volatile("global_load_ushort %0, %4, off sc0 sc1\n\t"
                   "global_load_ushort %1, %4, off offset:16 sc0 sc1\n\t"
                   "global_load_ushort %2, %4, off offset:32 sc0 sc1\n\t"
                   "global_load_ushort %3, %4, off offset:48 sc0 sc1"
                   : "=v"(hn0), "=v"(hn1), "=v"(hn2), "=v"(hn3) : "v"(hra));

      short8 A0,A1,A2,A3,A4,A5,A6,A7,A8,A9,A10,A11,A12,A13,A14,A15;
      short8 B0,B1,B2,B3,B4,B5,B6,B7,B8,B9,B10,B11,B12,B13,B14,B15;
      if (role == 0) {                             // x: normal cached
        ISS4N(A0,A1,A2,A3,    Alo);
        ISS4N(A4,A5,A6,A7,    Alo + 4096);
        ISS4N(A8,A9,A10,A11,  Alo + 8192);
        ISS4N(A12,A13,A14,A15,Alo + 12288);
      } else {                                     // h0: LLC-coherent
        ISS4C(A0,A1,A2,A3,    Alo);
        ISS4C(A4,A5,A6,A7,    Alo + 4096);
        ISS4C(A8,A9,A10,A11,  Alo + 8192);
        ISS4C(A12,A13,A14,A15,Alo + 12288);
      }
      ISS4C(B0,B1,B2,B3,    Ahi);                  // h: LLC-coherent
      ISS4C(B4,B5,B6,B7,    Ahi + 4096);
      ISS4C(B8,B9,B10,B11,  Ahi + 8192);
      ISS4C(B12,B13,B14,B15,Ahi + 12288);

      f32x4 ac0 = {0.f,0.f,0.f,0.f}, ac1 = {0.f,0.f,0.f,0.f};
      f32x4 ac2 = {0.f,0.f,0.f,0.f}, ac3 = {0.f,0.f,0.f,0.f};

      // 36 loads outstanding (+4 stale out-stores at the head for role1 p>=2:
      // each WAITV retires them first, so the per-batch load guarantees hold)
      WAITV(28); MMK(A0,0)  MMK(A1,1)  MMK(A2,2)  MMK(A3,3)
      WAITV(24); MMK(A4,4)  MMK(A5,5)  MMK(A6,6)  MMK(A7,7)
      WAITV(20); MMK(A8,8)  MMK(A9,9)  MMK(A10,10) MMK(A11,11)
      WAITV(16); MMK(A12,12) MMK(A13,13) MMK(A14,14) MMK(A15,15)
      WAITV(12); MMK(B0,16) MMK(B1,17) MMK(B2,18) MMK(B3,19)
      WAITV(8);  MMK(B4,20) MMK(B5,21) MMK(B6,22) MMK(B7,23)
      WAITV(4);  MMK(B8,24) MMK(B9,25) MMK(B10,26) MMK(B11,27)
      WAITV(0);  MMK(B12,28) MMK(B13,29) MMK(B14,30) MMK(B15,31)

      // epilogue: gates (i,j,f,o), state update from registers; out kept in regs
      const u32 hnv[4] = {hn0, hn1, hn2, hn3};
#pragma unroll
      for (int e = 0; e < 4; ++e) {
        float zi = ac0[e] + bg0, zj = ac1[e] + bg1, zf = ac2[e] + bg2, zo = ac3[e] + bg3;
        float cprev = creg[e];
        float cn = cprev * sigm(zf + 1.0f) + sigm(zi) * tanhe(zj);
        float hn = tanhe(cn) * sigm(zo);
        bool valid = tcur < sl[e];
        float hk = valid ? hn : hkeep[e];
        creg[e] = valid ? cn : cprev;
        hkeep[e] = hk;
        stg[rf * 256 + (((lane & 15) >> 3) * 16 + (lane >> 4) * 4 + e) * 8 + (lane & 7)] = f2bf(hk);
        if (role) {
          union { float f; u32 u; } hv; hv.u = hnv[e] << 16;               // h0n (bf16)
          outv[e] = valid ? (hn + hv.f) : 0.0f;
        }
      }
      // (a) stg is wave-private: own-wave LDS drain only, no block barrier
      asm volatile("s_waitcnt lgkmcnt(0)" ::: "memory");
      {  // coalesced LLC-coherent store of this wave's 512B h slice into write parity
        u64 v = reinterpret_cast<const u64*>(stg)[tid];
        u64* ha = reinterpret_cast<u64*>(hfSelf + (size_t)Wp * 131072) + o8;
        asm volatile("global_store_dwordx2 %0, %1, off sc0 sc1" :: "v"(ha), "v"(v) : "memory");
      }
      asm volatile("s_waitcnt vmcnt(0)" ::: "memory");   // own h slice at point of coherence
    }

    if (p == Tn) {                                 // last step: store out, no barrier
      if (role) {
#pragma unroll
        for (int e = 0; e < 4; ++e)
          out[((size_t)(rowB + e) * Tn + (Tn - 1)) * Dn + d0] = outv[e];
      }
      break;
    }

    // ---- per-mtile 64-block barrier: flag + wave0 poll; raw s_barrier (no re-drain) ----
    __builtin_amdgcn_s_barrier();                  // all waves drained their own vmcnt
    if (tid == 0) {
      u32 tv = (u32)(p + 1);
      asm volatile("global_store_dword %0, %1, off sc0 sc1" :: "v"(flagme), "v"(tv) : "memory");
    }
    if (role && p >= 1) {                          // (b) deferred out-stores: off the flag chain
#pragma unroll
      for (int e = 0; e < 4; ++e)
        out[((size_t)(rowB + e) * Tn + (p - 1)) * Dn + d0] = outv[e];
    }
    if (tid < 64) {                                // wave 0: lane l watches flag l
      const int tgt = p + 1;
      u32 fv;
      do {
        asm volatile("global_load_dword %0, %1, off sc0 sc1\n\t"
                     "s_waitcnt vmcnt(0)"
                     : "=v"(fv) : "v"(fb) : "memory");
      } while (!__all((int)fv >= tgt));
    }
    __builtin_amdgcn_s_barrier();                  // (c) release waves 1-3
  }
}

// ---------- fallback per-step kernel (only used if cooperative launch is rejected) ----------
#define LDA(kk) (*reinterpret_cast<const short8*>(                           \
    (kk) < 16 ? (Alo + (size_t)(kk) * 1024) : (Ahi + (size_t)((kk) - 16) * 1024)))

extern "C" __global__ void __launch_bounds__(256, 1)
rnn_step(const u16* __restrict__ xf, const u16* __restrict__ Wf,
         const float* __restrict__ b0, const float* __restrict__ b1,
         const int* __restrict__ seq,
         u16* __restrict__ hf0, u16* __restrict__ hf1,
         float* __restrict__ cbuf, float* __restrict__ out, int p) {
  extern __shared__ __align__(16) char smem[];
  const int blk = blockIdx.x;
  const int role = blk & 1;
  const int mtile = (blk >> 1) & 3;
  const int dsl = blk >> 3;
  const bool act = role ? (p >= 1) : (p < Tn);
  if (!act) return;

  const int tid = threadIdx.x;
  const int rf = tid >> 6, lane = tid & 63;
  const int Rp = (p & 1) ^ 1, Wp = p & 1;
  const int tcur = role ? (p - 1) : p;

  {
    const char* gsrc = reinterpret_cast<const char*>(Wf)
                     + (size_t)(role * 32 + dsl) * 131072 + tid * 16;
    char* lds = smem + tid * 16;
#pragma unroll
    for (int i = 0; i < 32; ++i)
      GLOAD_LDS(gsrc + i * 4096, lds + i * 4096);
  }

  const char* h0base = reinterpret_cast<const char*>(hf0);
  const char* h1base = reinterpret_cast<const char*>(hf1);
  const size_t hRp = (size_t)Rp * 262144 + (size_t)mtile * 65536;
  const int aoff = rf * 16384 + lane * 16;

  const char* Alo;
  const char* Ahi;
  if (role == 0) {
    Alo = reinterpret_cast<const char*>(xf) + ((size_t)mtile * Tn + p) * 65536 + aoff;
    Ahi = h0base + hRp + aoff;
  } else {
    Alo = h0base + hRp + aoff;
    Ahi = h1base + hRp + aoff;
  }
  const char* WL = smem + lane * 16;

  short8 ca0 = LDA(0), ca1 = LDA(1), ca2 = LDA(2), ca3 = LDA(3);

  const int d0 = dsl * 16 + (lane & 15);
  const float* bias = role ? b1 : b0;
  const float bg0 = bias[d0], bg1 = bias[512 + d0], bg2 = bias[1024 + d0], bg3 = bias[1536 + d0];
  const int rowB = mtile * 64 + rf * 16 + (lane >> 4) * 4;
  int sl[4];
#pragma unroll
  for (int e = 0; e < 4; ++e) sl[e] = seq[rowB + e];

  const int kkd = dsl >> 1;
  const int lane_t_base = ((((dsl & 1) << 1) | ((lane & 15) >> 3)) << 4) + (lane >> 4) * 4;
  const size_t hoff0 = (size_t)mtile * 32768 + (size_t)(rf * 16 + kkd) * 512
                     + (size_t)lane_t_base * 8 + (lane & 7);

  u16 h0nraw[4];
  if (role) {
    const u16* hr = reinterpret_cast<const u16*>(h0base) + (size_t)Rp * 131072;
#pragma unroll
    for (int e = 0; e < 4; ++e) h0nraw[e] = hr[hoff0 + e * 8];
  }
  float* cme = cbuf + ((size_t)blk * 256 + tid) * 4;
  float cpre[4];
#pragma unroll
  for (int e = 0; e < 4; ++e) cpre[e] = cme[e];
  u16* hfSelf = role ? hf1 : hf0;
  const u16* hprev = hfSelf + (size_t)Rp * 131072;
  u16 hp16[4];
#pragma unroll
  for (int e = 0; e < 4; ++e) hp16[e] = hprev[hoff0 + e * 8];

  __syncthreads();

  f32x4 ac0 = {0.f,0.f,0.f,0.f}, ac1 = {0.f,0.f,0.f,0.f};
  f32x4 ac2 = {0.f,0.f,0.f,0.f}, ac3 = {0.f,0.f,0.f,0.f};
  short8 na0, na1, na2, na3;
#pragma unroll
  for (int c = 0; c < 8; ++c) {
    const int k0 = c * 4;
    if (c < 7) {
      na0 = LDA(k0 + 4); na1 = LDA(k0 + 5); na2 = LDA(k0 + 6); na3 = LDA(k0 + 7);
    }
#pragma unroll
    for (int j = 0; j < 4; ++j) {
      const int kk = k0 + j;
      short8 a = (j == 0) ? ca0 : (j == 1) ? ca1 : (j == 2) ? ca2 : ca3;
      short8 w0 = *reinterpret_cast<const short8*>(WL + kk * 1024);
      short8 w1 = *reinterpret_cast<const short8*>(WL + 32768 + kk * 1024);
      short8 w2 = *reinterpret_cast<const short8*>(WL + 65536 + kk * 1024);
      short8 w3 = *reinterpret_cast<const short8*>(WL + 98304 + kk * 1024);
      ac0 = MFMA16(a, w0, ac0, 0, 0, 0);
      ac1 = MFMA16(a, w1, ac1, 0, 0, 0);
      ac2 = MFMA16(a, w2, ac2, 0, 0, 0);
      ac3 = MFMA16(a, w3, ac3, 0, 0, 0);
    }
    ca0 = na0; ca1 = na1; ca2 = na2; ca3 = na3;
  }

  u16* stg = reinterpret_cast<u16*>(smem + 131072);
#pragma unroll
  for (int e = 0; e < 4; ++e) {
    float zi = ac0[e] + bg0, zj = ac1[e] + bg1, zf = ac2[e] + bg2, zo = ac3[e] + bg3;
    float cprev = cpre[e];
    float cn = cprev * sigm(zf + 1.0f) + sigm(zi) * tanhe(zj);
    float hn = tanhe(cn) * sigm(zo);
    bool valid = tcur < sl[e];
    union { float f; u32 u; } hp; hp.u = ((u32)hp16[e]) << 16;
    float hkeep = valid ? hn : hp.f;
    cme[e] = valid ? cn : cprev;
    stg[rf * 256 + (((lane & 15) >> 3) * 16 + (lane >> 4) * 4 + e) * 8 + (lane & 7)] = f2bf(hkeep);
    if (role) {
      union { float f; u32 u; } hv; hv.u = ((u32)h0nraw[e]) << 16;
      out[((size_t)(rowB + e) * Tn + tcur) * Dn + d0] = valid ? (hn + hv.f) : 0.0f;
    }
  }
  __syncthreads();
  {
    const int rft = tid >> 6, u = tid & 63;
    u64 v = reinterpret_cast<const u64*>(stg)[tid];
    u64* hw8 = reinterpret_cast<u64*>(hfSelf + (size_t)Wp * 131072);
    size_t o8 = (size_t)((mtile * 4 + rft) * 16 + kkd) * 128 + ((dsl & 1) * 32 + (u >> 1)) * 2 + (u & 1);
    hw8[o8] = v;
  }
}

extern "C" void kernel_launch(void* const* d_in, const int* in_sizes, int n_in,
                              void* d_out, int out_size, void* d_ws, size_t ws_size,
                              hipStream_t stream) {
  (void)in_sizes; (void)n_in; (void)out_size; (void)ws_size;
  const float* x  = (const float*)d_in[0];
  const int* seq  = (const int*)d_in[1];
  const float* W0 = (const float*)d_in[2];
  const float* b0 = (const float*)d_in[3];
  const float* W1 = (const float*)d_in[4];
  const float* b1 = (const float*)d_in[5];
  float* out = (float*)d_out;

  char* ws = (char*)d_ws;
  // ws layout (bytes):
  //   xf   : 0          .. 52,428,800   bf16 fragment-major x
  //   Wf   : 52,428,800 .. 60,817,408   bf16 fragment-major weights
  //   hf0  : 60,817,408 .. 61,341,696   bf16 frag h0 [2 parities]
  //   hf1  : 61,341,696 .. 61,865,984   bf16 frag h1 [2 parities]
  //   bar  : 61,865,984 ..              u32 flags (4 mtiles x 64 blocks)
  //          (same region doubles as cbuf for the fallback path)
  u16*  xf   = (u16*)(ws);
  u16*  Wf   = (u16*)(ws + 52428800);
  u16*  hf0  = (u16*)(ws + 60817408);
  u16*  hf1  = (u16*)(ws + 61341696);
  u32*  bar  = (u32*)(ws + 61865984);
  float* cbuf = (float*)(ws + 61865984);

  hipMemsetAsync(ws + 60817408, 0, 2097152, stream);  // h frags (both parities) + flags
  hipLaunchKernelGGL(cvt_x_frag, dim3(12800), dim3(256), 0, stream, x, xf);
  hipLaunchKernelGGL(cvt_w_frag, dim3(1024), dim3(256), 0, stream, W0, W1, Wf);

  hipFuncSetAttribute((const void*)rnn_persist,
                      hipFuncAttributeMaxDynamicSharedMemorySize, 133120);
  hipFuncSetAttribute((const void*)rnn_step,
                      hipFuncAttributeMaxDynamicSharedMemorySize, 133120);

  void* args[] = { (void*)&xf, (void*)&Wf, (void*)&b0, (void*)&b1, (void*)&seq,
                   (void*)&hf0, (void*)&hf1, (void*)&bar, (void*)&out };
  hipError_t err = hipLaunchCooperativeKernel((void*)rnn_persist, dim3(256), dim3(256),
                                              args, 133120, stream);
  if (err != hipSuccess) {
    // fallback: proven multi-launch skewed pipeline
    for (int p = 0; p <= Tn; ++p) {
      hipLaunchKernelGGL(rnn_step, dim3(256), dim3(256), 133120, stream,
                         xf, Wf, b0, b1, seq, hf0, hf1, cbuf, out, p);
    }
  }
}

// Round 8
// 1143.510 us; speedup vs baseline: 1.8382x; 1.1134x over previous
//
#include <hip/hip_runtime.h>

using short8 = __attribute__((ext_vector_type(8))) short;
using f32x4  = __attribute__((ext_vector_type(4))) float;
typedef unsigned short u16;
typedef unsigned int   u32;
typedef unsigned long long u64;

constexpr int Bn = 256;   // batch
constexpr int Tn = 200;   // time steps
constexpr int Dn = 512;   // hidden size

__device__ __forceinline__ u16 f2bf(float x) {
  union { float f; unsigned u; } v; v.f = x;
  unsigned r = v.u + 0x7FFFu + ((v.u >> 16) & 1u);  // RNE
  return (u16)(r >> 16);
}
__device__ __forceinline__ float sigm(float x) { return 1.0f / (1.0f + __expf(-x)); }
__device__ __forceinline__ float tanhe(float x) { return 1.0f - 2.0f / (__expf(2.0f * x) + 1.0f); }

// ---------- prep: x f32 [B][T][D] -> xf fragment-major bf16 [mtile4][t200][rf4][kkd16][lane64][8] ----------
__global__ void cvt_x_frag(const float* __restrict__ x, u16* __restrict__ xf) {
  int i = blockIdx.x * 256 + threadIdx.x;          // exactly 3,276,800 lane-tasks
  int lane = i & 63;
  int kkd  = (i >> 6) & 15;
  int rf   = (i >> 10) & 3;
  int mt_t = i >> 12;                              // mtile*200 + t
  int t = mt_t % 200, mtile = mt_t / 200;
  int row = mtile * 64 + rf * 16 + (lane & 15);
  int k0  = kkd * 32 + (lane >> 4) * 8;
  const float* s = x + ((size_t)row * Tn + t) * Dn + k0;
  float4 v0 = *reinterpret_cast<const float4*>(s);
  float4 v1 = *reinterpret_cast<const float4*>(s + 4);
  short8 r;
  r[0]=(short)f2bf(v0.x); r[1]=(short)f2bf(v0.y); r[2]=(short)f2bf(v0.z); r[3]=(short)f2bf(v0.w);
  r[4]=(short)f2bf(v1.x); r[5]=(short)f2bf(v1.y); r[6]=(short)f2bf(v1.z); r[7]=(short)f2bf(v1.w);
  reinterpret_cast<short8*>(xf)[i] = r;
}

// ---------- prep: W [1024][2048] f32 -> Wf fragment-major bf16 [role2][dsl32][g4][kk32][lane64][8] ----------
__global__ void cvt_w_frag(const float* __restrict__ W0, const float* __restrict__ W1,
                           u16* __restrict__ Wf) {
  __shared__ u16 T[64][65];                        // [k][n] tile, padded
  int b = blockIdx.x;                              // 1024 blocks: role(2) x kt(16) x nt(32)
  int nt = b & 31, kt = (b >> 5) & 15, role = b >> 9;
  const float* W = role ? W1 : W0;
  int t = threadIdx.x;
  int k0 = kt * 64, n0 = nt * 64;
  int kr = t >> 6, nl = t & 63;
#pragma unroll
  for (int r = 0; r < 16; ++r) {
    int k = r * 4 + kr;
    T[k][nl] = f2bf(W[(size_t)(k0 + k) * 2048 + n0 + nl]);   // coalesced over n
  }
  __syncthreads();
  int g = n0 >> 9;
  int dslBase = (n0 & 511) >> 4;
  int kkBase  = k0 >> 5;
  int lane = t & 63, grp = t >> 6;
  int lr = lane & 15, lk = lane >> 4;
#pragma unroll
  for (int c = grp; c < 8; c += 4) {
    int dslL = c & 3, kkL = c >> 2;
    int dsl = dslBase + dslL, kk = kkBase + kkL;
    short8 v;
#pragma unroll
    for (int e = 0; e < 8; ++e)
      v[e] = (short)T[kkL * 32 + lk * 8 + e][dslL * 16 + lr];
    *reinterpret_cast<short8*>(Wf + ((((size_t)(role * 32 + dsl) * 4 + g) * 32 + kk) * 64 + lane) * 8) = v;
  }
}

#define MFMA16 __builtin_amdgcn_mfma_f32_16x16x32_bf16
#define GLOAD_LDS(g, l) __builtin_amdgcn_global_load_lds(                    \
    (const __attribute__((address_space(1))) void*)(g),                      \
    (__attribute__((address_space(3))) void*)(l), 16, 0, 0)

// LLC-coherent (cross-XCD) 4x16B load batch: bypasses L1+L2 via sc0 sc1
#define ISS4C(A0, A1, A2, A3, P)                                             \
  asm volatile("global_load_dwordx4 %0, %4, off sc0 sc1\n\t"                 \
               "global_load_dwordx4 %1, %4, off offset:1024 sc0 sc1\n\t"     \
               "global_load_dwordx4 %2, %4, off offset:2048 sc0 sc1\n\t"     \
               "global_load_dwordx4 %3, %4, off offset:3072 sc0 sc1"         \
               : "=v"(A0), "=v"(A1), "=v"(A2), "=v"(A3) : "v"(P))
// XCD-L2-coherent 4x16B load batch: sc0 only (L1 bypassed, served by local L2).
// Producer blocks are on the SAME XCD (q=blk&7 grouping + blk%8 round-robin dispatch).
#define ISS4L(A0, A1, A2, A3, P)                                             \
  asm volatile("global_load_dwordx4 %0, %4, off sc0\n\t"                     \
               "global_load_dwordx4 %1, %4, off offset:1024 sc0\n\t"         \
               "global_load_dwordx4 %2, %4, off offset:2048 sc0\n\t"         \
               "global_load_dwordx4 %3, %4, off offset:3072 sc0"             \
               : "=v"(A0), "=v"(A1), "=v"(A2), "=v"(A3) : "v"(P))
// normal cached 4x16B load batch (iteration-private x data)
#define ISS4N(A0, A1, A2, A3, P)                                             \
  asm volatile("global_load_dwordx4 %0, %4, off\n\t"                         \
               "global_load_dwordx4 %1, %4, off offset:1024\n\t"             \
               "global_load_dwordx4 %2, %4, off offset:2048\n\t"             \
               "global_load_dwordx4 %3, %4, off offset:3072"                 \
               : "=v"(A0), "=v"(A1), "=v"(A2), "=v"(A3) : "v"(P))
// counted wait + scheduling fence (v2-exact: MFMA must not hoist above the wait)
#define WAITV(N)                                                             \
  asm volatile("s_waitcnt vmcnt(" #N ")" ::: "memory");                      \
  __builtin_amdgcn_sched_barrier(0)
#define MMK(av, kk) {                                                        \
    short8 w0 = *reinterpret_cast<const short8*>(WL + (kk) * 1024);          \
    short8 w1 = *reinterpret_cast<const short8*>(WL + 32768 + (kk) * 1024);  \
    short8 w2 = *reinterpret_cast<const short8*>(WL + 65536 + (kk) * 1024);  \
    short8 w3 = *reinterpret_cast<const short8*>(WL + 98304 + (kk) * 1024);  \
    ac0 = MFMA16(av, w0, ac0, 0, 0, 0);                                      \
    ac1 = MFMA16(av, w1, ac1, 0, 0, 0);                                      \
    ac2 = MFMA16(av, w2, ac2, 0, 0, 0);                                      \
    ac3 = MFMA16(av, w3, ac3, 0, 0, 0); }

// ---------- persistent cooperative kernel: entire 200-step scan in ONE launch ----------
// v8 = v2 (proven 1257us persist) with ONLY cache-locality deltas; sync/ladders/epilogue
// byte-identical. q=blk&7 groups each (role,mtile)'s 32 dsl-blocks on one XCD:
//  - h1 (role1 produce+consume, same XCD): sc0-only stores/loads -> local L2, no LLC.
//  - h0 role0 self-reads (same XCD): sc0-only loads from h0 local buffer.
//  - h0 role0->role1 handoff (cross-XCD): role0 dual-stores an EXPORT copy sc0sc1;
//    role1 reads export via sc0sc1 (LLC) exactly as v2 did.
// LLC broadcast traffic per iter drops ~33MB -> ~8.6MB; role-local h latency ~600->~250cy.
// CORRECTNESS NOTE: relies on blk%8 XCD round-robin; a different dispatch mapping makes
// role-local reads stale -> refcheck fails loudly (falsifiable; revert if so).
extern "C" __global__ void __launch_bounds__(256, 1)
rnn_persist(const u16* __restrict__ xf, const u16* __restrict__ Wf,
            const float* __restrict__ b0, const float* __restrict__ b1,
            const int* __restrict__ seq,
            u16* __restrict__ hf0, u16* __restrict__ hf1, u16* __restrict__ hx,
            u32* __restrict__ bar, float* __restrict__ out) {
  extern __shared__ __align__(16) char smem[];
  const int blk = blockIdx.x;
  const int q = blk & 7;
  const int role = q & 1;
  const int mtile = q >> 1;
  const int dsl = blk >> 3;
  const int tid = threadIdx.x;
  const int rf = tid >> 6, lane = tid & 63;

  // ---- one-time W staging: 32 direct global->LDS 16B ops per thread ----
  {
    const char* gsrc = reinterpret_cast<const char*>(Wf)
                     + (size_t)(role * 32 + dsl) * 131072 + tid * 16;
    char* lds = smem + tid * 16;
#pragma unroll
    for (int i = 0; i < 32; ++i)
      GLOAD_LDS(gsrc + i * 4096, lds + i * 4096);
  }

  const char* xfb = reinterpret_cast<const char*>(xf);
  const char* h0b = reinterpret_cast<const char*>(hf0);
  const char* h1b = reinterpret_cast<const char*>(hf1);
  const char* hxb = reinterpret_cast<const char*>(hx);
  const int aoff = rf * 16384 + lane * 16;
  const char* WL = smem + lane * 16;               // + g*32768 + kk*1024 (ds_read_b128)

  const int d0 = dsl * 16 + (lane & 15);
  const float* bias = role ? b1 : b0;
  const float bg0 = bias[d0], bg1 = bias[512 + d0], bg2 = bias[1024 + d0], bg3 = bias[1536 + d0];
  const int rowB = mtile * 64 + rf * 16 + (lane >> 4) * 4;
  int sl[4];
#pragma unroll
  for (int e = 0; e < 4; ++e) sl[e] = seq[rowB + e];

  // fragment-layout u16 offset of this thread's (rowB+e, d0) values in h buffers
  const int kkd = dsl >> 1;
  const int lane_t_base = ((((dsl & 1) << 1) | ((lane & 15) >> 3)) << 4) + (lane >> 4) * 4;
  const size_t hoff0 = (size_t)mtile * 32768 + (size_t)(rf * 16 + kkd) * 512
                     + (size_t)lane_t_base * 8 + (lane & 7);

  u16* hfSelf = role ? hf1 : hf0;
  u16* stg = reinterpret_cast<u16*>(smem + 131072);
  const size_t o8 = (size_t)((mtile * 4 + rf) * 16 + kkd) * 128
                  + ((dsl & 1) * 32 + (lane >> 1)) * 2 + (lane & 1);
  u32* flagme = bar + mtile * 64 + role * 32 + dsl;
  const u32* fb = bar + mtile * 64 + tid;          // poll address (tid<64 only)

  float creg[4]  = {0.f, 0.f, 0.f, 0.f};           // c-state in registers
  float hkeep[4] = {0.f, 0.f, 0.f, 0.f};           // copy-through h in registers

  __syncthreads();                                 // W resident in LDS from here on

#pragma unroll 1
  for (int p = 0; p <= Tn; ++p) {
    const bool act = role ? (p >= 1) : (p < Tn);
    const int Rp = (p & 1) ^ 1, Wp = p & 1;
    float outv[4] = {0.f, 0.f, 0.f, 0.f};
    if (act) {
      const int tcur = role ? (p - 1) : p;
      const size_t hRp = (size_t)Rp * 262144 + (size_t)mtile * 65536;

      // residual h0n: role1 reads the cross-XCD EXPORT copy (sc0sc1);
      // role0 issues same-count dummy loads from its local h0 (sc0) for vmcnt parity.
      u32 hn0, hn1, hn2, hn3;
      if (role) {
        const char* hra = hxb + (size_t)Rp * 262144 + hoff0 * 2;
        asm volatile("global_load_ushort %0, %4, off sc0 sc1\n\t"
                     "global_load_ushort %1, %4, off offset:16 sc0 sc1\n\t"
                     "global_load_ushort %2, %4, off offset:32 sc0 sc1\n\t"
                     "global_load_ushort %3, %4, off offset:48 sc0 sc1"
                     : "=v"(hn0), "=v"(hn1), "=v"(hn2), "=v"(hn3) : "v"(hra));
      } else {
        const char* hra = h0b + (size_t)Rp * 262144 + hoff0 * 2;
        asm volatile("global_load_ushort %0, %4, off sc0\n\t"
                     "global_load_ushort %1, %4, off offset:16 sc0\n\t"
                     "global_load_ushort %2, %4, off offset:32 sc0\n\t"
                     "global_load_ushort %3, %4, off offset:48 sc0"
                     : "=v"(hn0), "=v"(hn1), "=v"(hn2), "=v"(hn3) : "v"(hra));
      }

      short8 A0,A1,A2,A3,A4,A5,A6,A7,A8,A9,A10,A11,A12,A13,A14,A15;
      short8 B0,B1,B2,B3,B4,B5,B6,B7,B8,B9,B10,B11,B12,B13,B14,B15;
      if (role == 0) {                             // A = x (normal cached)
        const char* Alo = xfb + ((size_t)mtile * Tn + p) * 65536 + aoff;
        ISS4N(A0,A1,A2,A3,    Alo);
        ISS4N(A4,A5,A6,A7,    Alo + 4096);
        ISS4N(A8,A9,A10,A11,  Alo + 8192);
        ISS4N(A12,A13,A14,A15,Alo + 12288);
        const char* Ahi = h0b + hRp + aoff;        // B = own h0, same-XCD L2
        ISS4L(B0,B1,B2,B3,    Ahi);
        ISS4L(B4,B5,B6,B7,    Ahi + 4096);
        ISS4L(B8,B9,B10,B11,  Ahi + 8192);
        ISS4L(B12,B13,B14,B15,Ahi + 12288);
      } else {                                     // A = h0 export (cross-XCD, LLC)
        const char* Alo = hxb + hRp + aoff;
        ISS4C(A0,A1,A2,A3,    Alo);
        ISS4C(A4,A5,A6,A7,    Alo + 4096);
        ISS4C(A8,A9,A10,A11,  Alo + 8192);
        ISS4C(A12,A13,A14,A15,Alo + 12288);
        const char* Ahi = h1b + hRp + aoff;        // B = own h1, same-XCD L2
        ISS4L(B0,B1,B2,B3,    Ahi);
        ISS4L(B4,B5,B6,B7,    Ahi + 4096);
        ISS4L(B8,B9,B10,B11,  Ahi + 8192);
        ISS4L(B12,B13,B14,B15,Ahi + 12288);
      }

      f32x4 ac0 = {0.f,0.f,0.f,0.f}, ac1 = {0.f,0.f,0.f,0.f};
      f32x4 ac2 = {0.f,0.f,0.f,0.f}, ac3 = {0.f,0.f,0.f,0.f};

      // 36 loads outstanding; consume batch c once first 8+4c are done (v2-exact)
      WAITV(28); MMK(A0,0)  MMK(A1,1)  MMK(A2,2)  MMK(A3,3)
      WAITV(24); MMK(A4,4)  MMK(A5,5)  MMK(A6,6)  MMK(A7,7)
      WAITV(20); MMK(A8,8)  MMK(A9,9)  MMK(A10,10) MMK(A11,11)
      WAITV(16); MMK(A12,12) MMK(A13,13) MMK(A14,14) MMK(A15,15)
      WAITV(12); MMK(B0,16) MMK(B1,17) MMK(B2,18) MMK(B3,19)
      WAITV(8);  MMK(B4,20) MMK(B5,21) MMK(B6,22) MMK(B7,23)
      WAITV(4);  MMK(B8,24) MMK(B9,25) MMK(B10,26) MMK(B11,27)
      WAITV(0);  MMK(B12,28) MMK(B13,29) MMK(B14,30) MMK(B15,31)

      // epilogue: gates (i,j,f,o), state update (register c-state), out via regs
      const u32 hnv[4] = {hn0, hn1, hn2, hn3};
#pragma unroll
      for (int e = 0; e < 4; ++e) {
        float zi = ac0[e] + bg0, zj = ac1[e] + bg1, zf = ac2[e] + bg2, zo = ac3[e] + bg3;
        float cprev = creg[e];
        float cn = cprev * sigm(zf + 1.0f) + sigm(zi) * tanhe(zj);
        float hn = tanhe(cn) * sigm(zo);
        bool valid = tcur < sl[e];
        float hk = valid ? hn : hkeep[e];
        creg[e] = valid ? cn : cprev;
        hkeep[e] = hk;
        stg[rf * 256 + (((lane & 15) >> 3) * 16 + (lane >> 4) * 4 + e) * 8 + (lane & 7)] = f2bf(hk);
        if (role) {
          union { float f; u32 u; } hv; hv.u = hnv[e] << 16;               // h0n (bf16)
          out[((size_t)(rowB + e) * Tn + tcur) * Dn + d0] = valid ? (hn + hv.f) : 0.0f;
        }
      }
      __syncthreads();
      {  // coalesced h store: role-local L2 copy (sc0); role0 also exports to LLC
        u64 v = reinterpret_cast<const u64*>(stg)[tid];
        u64* ha = reinterpret_cast<u64*>(hfSelf + (size_t)Wp * 131072) + o8;
        asm volatile("global_store_dwordx2 %0, %1, off sc0" :: "v"(ha), "v"(v) : "memory");
        if (role == 0) {
          u64* he = reinterpret_cast<u64*>(hx + (size_t)Wp * 131072) + o8;
          asm volatile("global_store_dwordx2 %0, %1, off sc0 sc1" :: "v"(he), "v"(v) : "memory");
        }
      }
      asm volatile("s_waitcnt vmcnt(0)" ::: "memory");   // h slices committed (L2 / LLC)
    }

    if (p == Tn) break;                            // nothing reads after the last step

    // ---- per-mtile 64-block barrier: per-block flag store + one-wave poll (v2-exact) ----
    __syncthreads();                               // all block writes drained
    if (tid == 0) {
      u32 tv = (u32)(p + 1);
      asm volatile("global_store_dword %0, %1, off sc0 sc1" :: "v"(flagme), "v"(tv) : "memory");
    }
    if (tid < 64) {                                // wave 0: lane l watches flag l
      const int tgt = p + 1;
      u32 fv;
      do {
        asm volatile("global_load_dword %0, %1, off sc0 sc1\n\t"
                     "s_waitcnt vmcnt(0)"
                     : "=v"(fv) : "v"(fb) : "memory");
      } while (!__all((int)fv >= tgt));
    }
    __syncthreads();
  }
}

// ---------- fallback per-step kernel (only used if cooperative launch is rejected) ----------
#define LDA(kk) (*reinterpret_cast<const short8*>(                           \
    (kk) < 16 ? (Alo + (size_t)(kk) * 1024) : (Ahi + (size_t)((kk) - 16) * 1024)))

extern "C" __global__ void __launch_bounds__(256, 1)
rnn_step(const u16* __restrict__ xf, const u16* __restrict__ Wf,
         const float* __restrict__ b0, const float* __restrict__ b1,
         const int* __restrict__ seq,
         u16* __restrict__ hf0, u16* __restrict__ hf1,
         float* __restrict__ cbuf, float* __restrict__ out, int p) {
  extern __shared__ __align__(16) char smem[];
  const int blk = blockIdx.x;
  const int role = blk & 1;
  const int mtile = (blk >> 1) & 3;
  const int dsl = blk >> 3;
  const bool act = role ? (p >= 1) : (p < Tn);
  if (!act) return;

  const int tid = threadIdx.x;
  const int rf = tid >> 6, lane = tid & 63;
  const int Rp = (p & 1) ^ 1, Wp = p & 1;
  const int tcur = role ? (p - 1) : p;

  {
    const char* gsrc = reinterpret_cast<const char*>(Wf)
                     + (size_t)(role * 32 + dsl) * 131072 + tid * 16;
    char* lds = smem + tid * 16;
#pragma unroll
    for (int i = 0; i < 32; ++i)
      GLOAD_LDS(gsrc + i * 4096, lds + i * 4096);
  }

  const char* h0base = reinterpret_cast<const char*>(hf0);
  const char* h1base = reinterpret_cast<const char*>(hf1);
  const size_t hRp = (size_t)Rp * 262144 + (size_t)mtile * 65536;
  const int aoff = rf * 16384 + lane * 16;

  const char* Alo;
  const char* Ahi;
  if (role == 0) {
    Alo = reinterpret_cast<const char*>(xf) + ((size_t)mtile * Tn + p) * 65536 + aoff;
    Ahi = h0base + hRp + aoff;
  } else {
    Alo = h0base + hRp + aoff;
    Ahi = h1base + hRp + aoff;
  }
  const char* WL = smem + lane * 16;

  short8 ca0 = LDA(0), ca1 = LDA(1), ca2 = LDA(2), ca3 = LDA(3);

  const int d0 = dsl * 16 + (lane & 15);
  const float* bias = role ? b1 : b0;
  const float bg0 = bias[d0], bg1 = bias[512 + d0], bg2 = bias[1024 + d0], bg3 = bias[1536 + d0];
  const int rowB = mtile * 64 + rf * 16 + (lane >> 4) * 4;
  int sl[4];
#pragma unroll
  for (int e = 0; e < 4; ++e) sl[e] = seq[rowB + e];

  const int kkd = dsl >> 1;
  const int lane_t_base = ((((dsl & 1) << 1) | ((lane & 15) >> 3)) << 4) + (lane >> 4) * 4;
  const size_t hoff0 = (size_t)mtile * 32768 + (size_t)(rf * 16 + kkd) * 512
                     + (size_t)lane_t_base * 8 + (lane & 7);

  u16 h0nraw[4];
  if (role) {
    const u16* hr = reinterpret_cast<const u16*>(h0base) + (size_t)Rp * 131072;
#pragma unroll
    for (int e = 0; e < 4; ++e) h0nraw[e] = hr[hoff0 + e * 8];
  }
  float* cme = cbuf + ((size_t)blk * 256 + tid) * 4;
  float cpre[4];
#pragma unroll
  for (int e = 0; e < 4; ++e) cpre[e] = cme[e];
  u16* hfSelf = role ? hf1 : hf0;
  const u16* hprev = hfSelf + (size_t)Rp * 131072;
  u16 hp16[4];
#pragma unroll
  for (int e = 0; e < 4; ++e) hp16[e] = hprev[hoff0 + e * 8];

  __syncthreads();

  f32x4 ac0 = {0.f,0.f,0.f,0.f}, ac1 = {0.f,0.f,0.f,0.f};
  f32x4 ac2 = {0.f,0.f,0.f,0.f}, ac3 = {0.f,0.f,0.f,0.f};
  short8 na0, na1, na2, na3;
#pragma unroll
  for (int c = 0; c < 8; ++c) {
    const int k0 = c * 4;
    if (c < 7) {
      na0 = LDA(k0 + 4); na1 = LDA(k0 + 5); na2 = LDA(k0 + 6); na3 = LDA(k0 + 7);
    }
#pragma unroll
    for (int j = 0; j < 4; ++j) {
      const int kk = k0 + j;
      short8 a = (j == 0) ? ca0 : (j == 1) ? ca1 : (j == 2) ? ca2 : ca3;
      short8 w0 = *reinterpret_cast<const short8*>(WL + kk * 1024);
      short8 w1 = *reinterpret_cast<const short8*>(WL + 32768 + kk * 1024);
      short8 w2 = *reinterpret_cast<const short8*>(WL + 65536 + kk * 1024);
      short8 w3 = *reinterpret_cast<const short8*>(WL + 98304 + kk * 1024);
      ac0 = MFMA16(a, w0, ac0, 0, 0, 0);
      ac1 = MFMA16(a, w1, ac1, 0, 0, 0);
      ac2 = MFMA16(a, w2, ac2, 0, 0, 0);
      ac3 = MFMA16(a, w3, ac3, 0, 0, 0);
    }
    ca0 = na0; ca1 = na1; ca2 = na2; ca3 = na3;
  }

  u16* stg = reinterpret_cast<u16*>(smem + 131072);
#pragma unroll
  for (int e = 0; e < 4; ++e) {
    float zi = ac0[e] + bg0, zj = ac1[e] + bg1, zf = ac2[e] + bg2, zo = ac3[e] + bg3;
    float cprev = cpre[e];
    float cn = cprev * sigm(zf + 1.0f) + sigm(zi) * tanhe(zj);
    float hn = tanhe(cn) * sigm(zo);
    bool valid = tcur < sl[e];
    union { float f; u32 u; } hp; hp.u = ((u32)hp16[e]) << 16;
    float hkeep = valid ? hn : hp.f;
    cme[e] = valid ? cn : cprev;
    stg[rf * 256 + (((lane & 15) >> 3) * 16 + (lane >> 4) * 4 + e) * 8 + (lane & 7)] = f2bf(hkeep);
    if (role) {
      union { float f; u32 u; } hv; hv.u = ((u32)h0nraw[e]) << 16;
      out[((size_t)(rowB + e) * Tn + tcur) * Dn + d0] = valid ? (hn + hv.f) : 0.0f;
    }
  }
  __syncthreads();
  {
    const int rft = tid >> 6, u = tid & 63;
    u64 v = reinterpret_cast<const u64*>(stg)[tid];
    u64* hw8 = reinterpret_cast<u64*>(hfSelf + (size_t)Wp * 131072);
    size_t o8 = (size_t)((mtile * 4 + rft) * 16 + kkd) * 128 + ((dsl & 1) * 32 + (u >> 1)) * 2 + (u & 1);
    hw8[o8] = v;
  }
}

extern "C" void kernel_launch(void* const* d_in, const int* in_sizes, int n_in,
                              void* d_out, int out_size, void* d_ws, size_t ws_size,
                              hipStream_t stream) {
  (void)in_sizes; (void)n_in; (void)out_size; (void)ws_size;
  const float* x  = (const float*)d_in[0];
  const int* seq  = (const int*)d_in[1];
  const float* W0 = (const float*)d_in[2];
  const float* b0 = (const float*)d_in[3];
  const float* W1 = (const float*)d_in[4];
  const float* b1 = (const float*)d_in[5];
  float* out = (float*)d_out;

  char* ws = (char*)d_ws;
  // ws layout (bytes):
  //   xf   : 0          .. 52,428,800   bf16 fragment-major x
  //   Wf   : 52,428,800 .. 60,817,408   bf16 fragment-major weights
  //   hf0  : 60,817,408 .. 61,341,696   bf16 frag h0 [2 parities] (role0-local, L2)
  //   hf1  : 61,341,696 .. 61,865,984   bf16 frag h1 [2 parities] (role1-local, L2)
  //   bar  : 61,865,984 .. 61,867,008   u32 flags (4 mtiles x 64 blocks)
  //   hx   : 61,870,080 .. 62,394,368   h0 EXPORT copy [2 parities] (LLC, cross-XCD)
  //          (bar..62,914,560 doubles as cbuf for the fallback path)
  u16*  xf   = (u16*)(ws);
  u16*  Wf   = (u16*)(ws + 52428800);
  u16*  hf0  = (u16*)(ws + 60817408);
  u16*  hf1  = (u16*)(ws + 61341696);
  u32*  bar  = (u32*)(ws + 61865984);
  u16*  hx   = (u16*)(ws + 61870080);
  float* cbuf = (float*)(ws + 61865984);

  hipMemsetAsync(ws + 60817408, 0, 2097152, stream);  // h frags + flags + export
  hipLaunchKernelGGL(cvt_x_frag, dim3(12800), dim3(256), 0, stream, x, xf);
  hipLaunchKernelGGL(cvt_w_frag, dim3(1024), dim3(256), 0, stream, W0, W1, Wf);

  hipFuncSetAttribute((const void*)rnn_persist,
                      hipFuncAttributeMaxDynamicSharedMemorySize, 133120);
  hipFuncSetAttribute((const void*)rnn_step,
                      hipFuncAttributeMaxDynamicSharedMemorySize, 133120);

  void* args[] = { (void*)&xf, (void*)&Wf, (void*)&b0, (void*)&b1, (void*)&seq,
                   (void*)&hf0, (void*)&hf1, (void*)&hx, (void*)&bar, (void*)&out };
  hipError_t err = hipLaunchCooperativeKernel((void*)rnn_persist, dim3(256), dim3(256),
                                              args, 133120, stream);
  if (err != hipSuccess) {
    // fallback: proven multi-launch skewed pipeline
    for (int p = 0; p <= Tn; ++p) {
      hipLaunchKernelGGL(rnn_step, dim3(256), dim3(256), 133120, stream,
                         xf, Wf, b0, b1, seq, hf0, hf1, cbuf, out, p);
    }
  }
}

// Round 11
// 1132.505 us; speedup vs baseline: 1.8561x; 1.0097x over previous
//
#include <hip/hip_runtime.h>

using short8 = __attribute__((ext_vector_type(8))) short;
using f32x4  = __attribute__((ext_vector_type(4))) float;
typedef unsigned short u16;
typedef unsigned int   u32;
typedef unsigned long long u64;

constexpr int Bn = 256;   // batch
constexpr int Tn = 200;   // time steps
constexpr int Dn = 512;   // hidden size

__device__ __forceinline__ u16 f2bf(float x) {
  union { float f; unsigned u; } v; v.f = x;
  unsigned r = v.u + 0x7FFFu + ((v.u >> 16) & 1u);  // RNE
  return (u16)(r >> 16);
}
__device__ __forceinline__ float sigm(float x) { return 1.0f / (1.0f + __expf(-x)); }
__device__ __forceinline__ float tanhe(float x) { return 1.0f - 2.0f / (__expf(2.0f * x) + 1.0f); }

// ---------- prep: x f32 [B][T][D] -> xf fragment-major bf16 [mtile4][t200][rf4][kkd16][lane64][8] ----------
__global__ void cvt_x_frag(const float* __restrict__ x, u16* __restrict__ xf) {
  int i = blockIdx.x * 256 + threadIdx.x;          // exactly 3,276,800 lane-tasks
  int lane = i & 63;
  int kkd  = (i >> 6) & 15;
  int rf   = (i >> 10) & 3;
  int mt_t = i >> 12;                              // mtile*200 + t
  int t = mt_t % 200, mtile = mt_t / 200;
  int row = mtile * 64 + rf * 16 + (lane & 15);
  int k0  = kkd * 32 + (lane >> 4) * 8;
  const float* s = x + ((size_t)row * Tn + t) * Dn + k0;
  float4 v0 = *reinterpret_cast<const float4*>(s);
  float4 v1 = *reinterpret_cast<const float4*>(s + 4);
  short8 r;
  r[0]=(short)f2bf(v0.x); r[1]=(short)f2bf(v0.y); r[2]=(short)f2bf(v0.z); r[3]=(short)f2bf(v0.w);
  r[4]=(short)f2bf(v1.x); r[5]=(short)f2bf(v1.y); r[6]=(short)f2bf(v1.z); r[7]=(short)f2bf(v1.w);
  reinterpret_cast<short8*>(xf)[i] = r;
}

// ---------- prep: W [1024][2048] f32 -> Wf fragment-major bf16 [role2][dsl32][g4][kk32][lane64][8] ----------
__global__ void cvt_w_frag(const float* __restrict__ W0, const float* __restrict__ W1,
                           u16* __restrict__ Wf) {
  __shared__ u16 T[64][65];                        // [k][n] tile, padded
  int b = blockIdx.x;                              // 1024 blocks: role(2) x kt(16) x nt(32)
  int nt = b & 31, kt = (b >> 5) & 15, role = b >> 9;
  const float* W = role ? W1 : W0;
  int t = threadIdx.x;
  int k0 = kt * 64, n0 = nt * 64;
  int kr = t >> 6, nl = t & 63;
#pragma unroll
  for (int r = 0; r < 16; ++r) {
    int k = r * 4 + kr;
    T[k][nl] = f2bf(W[(size_t)(k0 + k) * 2048 + n0 + nl]);   // coalesced over n
  }
  __syncthreads();
  int g = n0 >> 9;
  int dslBase = (n0 & 511) >> 4;
  int kkBase  = k0 >> 5;
  int lane = t & 63, grp = t >> 6;
  int lr = lane & 15, lk = lane >> 4;
#pragma unroll
  for (int c = grp; c < 8; c += 4) {
    int dslL = c & 3, kkL = c >> 2;
    int dsl = dslBase + dslL, kk = kkBase + kkL;
    short8 v;
#pragma unroll
    for (int e = 0; e < 8; ++e)
      v[e] = (short)T[kkL * 32 + lk * 8 + e][dslL * 16 + lr];
    *reinterpret_cast<short8*>(Wf + ((((size_t)(role * 32 + dsl) * 4 + g) * 32 + kk) * 64 + lane) * 8) = v;
  }
}

#define MFMA16 __builtin_amdgcn_mfma_f32_16x16x32_bf16
#define GLOAD_LDS(g, l) __builtin_amdgcn_global_load_lds(                    \
    (const __attribute__((address_space(1))) void*)(g),                      \
    (__attribute__((address_space(3))) void*)(l), 16, 0, 0)

// LLC-coherent (cross-XCD) 4x16B load batch: bypasses L1+L2 via sc0 sc1
#define ISS4C(A0, A1, A2, A3, P)                                             \
  asm volatile("global_load_dwordx4 %0, %4, off sc0 sc1\n\t"                 \
               "global_load_dwordx4 %1, %4, off offset:1024 sc0 sc1\n\t"     \
               "global_load_dwordx4 %2, %4, off offset:2048 sc0 sc1\n\t"     \
               "global_load_dwordx4 %3, %4, off offset:3072 sc0 sc1"         \
               : "=v"(A0), "=v"(A1), "=v"(A2), "=v"(A3) : "v"(P))
// XCD-L2-coherent 4x16B load batch: sc0 only (L1 bypassed, served by local L2).
// Producer blocks are on the SAME XCD (q=blk&7 grouping + blk%8 round-robin dispatch).
#define ISS4L(A0, A1, A2, A3, P)                                             \
  asm volatile("global_load_dwordx4 %0, %4, off sc0\n\t"                     \
               "global_load_dwordx4 %1, %4, off offset:1024 sc0\n\t"         \
               "global_load_dwordx4 %2, %4, off offset:2048 sc0\n\t"         \
               "global_load_dwordx4 %3, %4, off offset:3072 sc0"             \
               : "=v"(A0), "=v"(A1), "=v"(A2), "=v"(A3) : "v"(P))
// normal cached 4x16B load batch (iteration-private x data)
#define ISS4N(A0, A1, A2, A3, P)                                             \
  asm volatile("global_load_dwordx4 %0, %4, off\n\t"                         \
               "global_load_dwordx4 %1, %4, off offset:1024\n\t"             \
               "global_load_dwordx4 %2, %4, off offset:2048\n\t"             \
               "global_load_dwordx4 %3, %4, off offset:3072"                 \
               : "=v"(A0), "=v"(A1), "=v"(A2), "=v"(A3) : "v"(P))
// counted wait + scheduling fence (v2-exact: MFMA must not hoist above the wait)
#define WAITV(N)                                                             \
  asm volatile("s_waitcnt vmcnt(" #N ")" ::: "memory");                      \
  __builtin_amdgcn_sched_barrier(0)
#define MMK(av, kk) {                                                        \
    short8 w0 = *reinterpret_cast<const short8*>(WL + (kk) * 1024);          \
    short8 w1 = *reinterpret_cast<const short8*>(WL + 32768 + (kk) * 1024);  \
    short8 w2 = *reinterpret_cast<const short8*>(WL + 65536 + (kk) * 1024);  \
    short8 w3 = *reinterpret_cast<const short8*>(WL + 98304 + (kk) * 1024);  \
    ac0 = MFMA16(av, w0, ac0, 0, 0, 0);                                      \
    ac1 = MFMA16(av, w1, ac1, 0, 0, 0);                                      \
    ac2 = MFMA16(av, w2, ac2, 0, 0, 0);                                      \
    ac3 = MFMA16(av, w3, ac3, 0, 0, 0); }

// ---------- persistent cooperative kernel: entire 200-step scan in ONE launch ----------
// v11 = v8 (proven 1190us: XCD-local h via sc0 + LLC export for role0->role1) with
// EXACTLY ONE delta: FAST-FIRST LADDER. Issue order per iteration becomes
// {16 fast local-L2 B loads, 4 hra, 16 slow A loads}; consumption covers the fast
// half (kk 16..31) first, so the ladder-entry stall is the ~250cy local-L2 latency
// instead of the ~600-900cy LLC/HBM latency, and the slow loads land under the
// fast-half MFMA stream. Pure within-iteration straight-line reorder (no loads
// cross any barrier — the v9/v10 failure mechanism is structurally excluded).
// vmcnt ladder (36 outstanding, in-order retirement):
//   WAITV(32)/(28)/(24)/(20) -> B0..B15 (kk16..31); WAITV(12) retires hra+A0-3;
//   WAITV(8)/(4)/(0) -> remaining A (kk0..15); hra retired before epilogue.
extern "C" __global__ void __launch_bounds__(256, 1)
rnn_persist(const u16* __restrict__ xf, const u16* __restrict__ Wf,
            const float* __restrict__ b0, const float* __restrict__ b1,
            const int* __restrict__ seq,
            u16* __restrict__ hf0, u16* __restrict__ hf1, u16* __restrict__ hx,
            u32* __restrict__ bar, float* __restrict__ out) {
  extern __shared__ __align__(16) char smem[];
  const int blk = blockIdx.x;
  const int q = blk & 7;
  const int role = q & 1;
  const int mtile = q >> 1;
  const int dsl = blk >> 3;
  const int tid = threadIdx.x;
  const int rf = tid >> 6, lane = tid & 63;

  // ---- one-time W staging: 32 direct global->LDS 16B ops per thread ----
  {
    const char* gsrc = reinterpret_cast<const char*>(Wf)
                     + (size_t)(role * 32 + dsl) * 131072 + tid * 16;
    char* lds = smem + tid * 16;
#pragma unroll
    for (int i = 0; i < 32; ++i)
      GLOAD_LDS(gsrc + i * 4096, lds + i * 4096);
  }

  const char* xfb = reinterpret_cast<const char*>(xf);
  const char* h0b = reinterpret_cast<const char*>(hf0);
  const char* h1b = reinterpret_cast<const char*>(hf1);
  const char* hxb = reinterpret_cast<const char*>(hx);
  const int aoff = rf * 16384 + lane * 16;
  const char* WL = smem + lane * 16;               // + g*32768 + kk*1024 (ds_read_b128)

  const int d0 = dsl * 16 + (lane & 15);
  const float* bias = role ? b1 : b0;
  const float bg0 = bias[d0], bg1 = bias[512 + d0], bg2 = bias[1024 + d0], bg3 = bias[1536 + d0];
  const int rowB = mtile * 64 + rf * 16 + (lane >> 4) * 4;
  int sl[4];
#pragma unroll
  for (int e = 0; e < 4; ++e) sl[e] = seq[rowB + e];

  // fragment-layout u16 offset of this thread's (rowB+e, d0) values in h buffers
  const int kkd = dsl >> 1;
  const int lane_t_base = ((((dsl & 1) << 1) | ((lane & 15) >> 3)) << 4) + (lane >> 4) * 4;
  const size_t hoff0 = (size_t)mtile * 32768 + (size_t)(rf * 16 + kkd) * 512
                     + (size_t)lane_t_base * 8 + (lane & 7);

  u16* hfSelf = role ? hf1 : hf0;
  u16* stg = reinterpret_cast<u16*>(smem + 131072);
  const size_t o8 = (size_t)((mtile * 4 + rf) * 16 + kkd) * 128
                  + ((dsl & 1) * 32 + (lane >> 1)) * 2 + (lane & 1);
  u32* flagme = bar + mtile * 64 + role * 32 + dsl;
  const u32* fb = bar + mtile * 64 + tid;          // poll address (tid<64 only)

  float creg[4]  = {0.f, 0.f, 0.f, 0.f};           // c-state in registers
  float hkeep[4] = {0.f, 0.f, 0.f, 0.f};           // copy-through h in registers

  __syncthreads();                                 // W resident in LDS from here on

#pragma unroll 1
  for (int p = 0; p <= Tn; ++p) {
    const bool act = role ? (p >= 1) : (p < Tn);
    const int Rp = (p & 1) ^ 1, Wp = p & 1;
    if (act) {
      const int tcur = role ? (p - 1) : p;
      const size_t hRp = (size_t)Rp * 262144 + (size_t)mtile * 65536;

      short8 A0,A1,A2,A3,A4,A5,A6,A7,A8,A9,A10,A11,A12,A13,A14,A15;
      short8 B0,B1,B2,B3,B4,B5,B6,B7,B8,B9,B10,B11,B12,B13,B14,B15;
      u32 hn0, hn1, hn2, hn3;

      // (1) FAST local-L2 B loads first (role0: own h0; role1: own h1) — sc0
      {
        const char* Bh = (role == 0) ? h0b + hRp + aoff : h1b + hRp + aoff;
        ISS4L(B0,B1,B2,B3,    Bh);
        ISS4L(B4,B5,B6,B7,    Bh + 4096);
        ISS4L(B8,B9,B10,B11,  Bh + 8192);
        ISS4L(B12,B13,B14,B15,Bh + 12288);
      }
      // (2) residual h0n: role1 reads cross-XCD EXPORT (sc0sc1);
      //     role0 issues same-count local loads (sc0) for vmcnt parity.
      if (role) {
        const char* hra = hxb + (size_t)Rp * 262144 + hoff0 * 2;
        asm volatile("global_load_ushort %0, %4, off sc0 sc1\n\t"
                     "global_load_ushort %1, %4, off offset:16 sc0 sc1\n\t"
                     "global_load_ushort %2, %4, off offset:32 sc0 sc1\n\t"
                     "global_load_ushort %3, %4, off offset:48 sc0 sc1"
                     : "=v"(hn0), "=v"(hn1), "=v"(hn2), "=v"(hn3) : "v"(hra));
      } else {
        const char* hra = h0b + (size_t)Rp * 262144 + hoff0 * 2;
        asm volatile("global_load_ushort %0, %4, off sc0\n\t"
                     "global_load_ushort %1, %4, off offset:16 sc0\n\t"
                     "global_load_ushort %2, %4, off offset:32 sc0\n\t"
                     "global_load_ushort %3, %4, off offset:48 sc0"
                     : "=v"(hn0), "=v"(hn1), "=v"(hn2), "=v"(hn3) : "v"(hra));
      }
      // (3) SLOW A loads last (role0: x, normal cached; role1: hx export, LLC)
      if (role == 0) {
        const char* Alo = xfb + ((size_t)mtile * Tn + p) * 65536 + aoff;
        ISS4N(A0,A1,A2,A3,    Alo);
        ISS4N(A4,A5,A6,A7,    Alo + 4096);
        ISS4N(A8,A9,A10,A11,  Alo + 8192);
        ISS4N(A12,A13,A14,A15,Alo + 12288);
      } else {
        const char* Alo = hxb + hRp + aoff;
        ISS4C(A0,A1,A2,A3,    Alo);
        ISS4C(A4,A5,A6,A7,    Alo + 4096);
        ISS4C(A8,A9,A10,A11,  Alo + 8192);
        ISS4C(A12,A13,A14,A15,Alo + 12288);
      }

      f32x4 ac0 = {0.f,0.f,0.f,0.f}, ac1 = {0.f,0.f,0.f,0.f};
      f32x4 ac2 = {0.f,0.f,0.f,0.f}, ac3 = {0.f,0.f,0.f,0.f};

      // fast-first ladder: B (kk16..31) consumed while A lands under it
      WAITV(32); MMK(B0,16) MMK(B1,17) MMK(B2,18) MMK(B3,19)
      WAITV(28); MMK(B4,20) MMK(B5,21) MMK(B6,22) MMK(B7,23)
      WAITV(24); MMK(B8,24) MMK(B9,25) MMK(B10,26) MMK(B11,27)
      WAITV(20); MMK(B12,28) MMK(B13,29) MMK(B14,30) MMK(B15,31)
      WAITV(12); MMK(A0,0)  MMK(A1,1)  MMK(A2,2)  MMK(A3,3)
      WAITV(8);  MMK(A4,4)  MMK(A5,5)  MMK(A6,6)  MMK(A7,7)
      WAITV(4);  MMK(A8,8)  MMK(A9,9)  MMK(A10,10) MMK(A11,11)
      WAITV(0);  MMK(A12,12) MMK(A13,13) MMK(A14,14) MMK(A15,15)

      // epilogue: gates (i,j,f,o), state update (register c-state), out (v8-exact)
      const u32 hnv[4] = {hn0, hn1, hn2, hn3};
#pragma unroll
      for (int e = 0; e < 4; ++e) {
        float zi = ac0[e] + bg0, zj = ac1[e] + bg1, zf = ac2[e] + bg2, zo = ac3[e] + bg3;
        float cprev = creg[e];
        float cn = cprev * sigm(zf + 1.0f) + sigm(zi) * tanhe(zj);
        float hn = tanhe(cn) * sigm(zo);
        bool valid = tcur < sl[e];
        float hk = valid ? hn : hkeep[e];
        creg[e] = valid ? cn : cprev;
        hkeep[e] = hk;
        stg[rf * 256 + (((lane & 15) >> 3) * 16 + (lane >> 4) * 4 + e) * 8 + (lane & 7)] = f2bf(hk);
        if (role) {
          union { float f; u32 u; } hv; hv.u = hnv[e] << 16;               // h0n (bf16)
          out[((size_t)(rowB + e) * Tn + tcur) * Dn + d0] = valid ? (hn + hv.f) : 0.0f;
        }
      }
      __syncthreads();                             // v8-exact: stg + outs drained
      {  // coalesced h store: role-local L2 copy (sc0); role0 also exports to LLC
        u64 v = reinterpret_cast<const u64*>(stg)[tid];
        u64* ha = reinterpret_cast<u64*>(hfSelf + (size_t)Wp * 131072) + o8;
        asm volatile("global_store_dwordx2 %0, %1, off sc0" :: "v"(ha), "v"(v) : "memory");
        if (role == 0) {
          u64* he = reinterpret_cast<u64*>(hx + (size_t)Wp * 131072) + o8;
          asm volatile("global_store_dwordx2 %0, %1, off sc0 sc1" :: "v"(he), "v"(v) : "memory");
        }
      }
      asm volatile("s_waitcnt vmcnt(0)" ::: "memory");   // h slices committed (L2 / LLC)
    }

    if (p == Tn) break;                            // nothing reads after the last step

    // ---- per-mtile 64-block barrier: per-block flag store + one-wave poll (v8-exact) ----
    __syncthreads();                               // all block writes drained
    if (tid == 0) {
      u32 tv = (u32)(p + 1);
      asm volatile("global_store_dword %0, %1, off sc0 sc1" :: "v"(flagme), "v"(tv) : "memory");
    }
    if (tid < 64) {                                // wave 0: lane l watches flag l
      const int tgt = p + 1;
      u32 fv;
      do {
        asm volatile("global_load_dword %0, %1, off sc0 sc1\n\t"
                     "s_waitcnt vmcnt(0)"
                     : "=v"(fv) : "v"(fb) : "memory");
      } while (!__all((int)fv >= tgt));
    }
    __syncthreads();
  }
}

// ---------- fallback per-step kernel (only used if cooperative launch is rejected) ----------
#define LDA(kk) (*reinterpret_cast<const short8*>(                           \
    (kk) < 16 ? (Alo + (size_t)(kk) * 1024) : (Ahi + (size_t)((kk) - 16) * 1024)))

extern "C" __global__ void __launch_bounds__(256, 1)
rnn_step(const u16* __restrict__ xf, const u16* __restrict__ Wf,
         const float* __restrict__ b0, const float* __restrict__ b1,
         const int* __restrict__ seq,
         u16* __restrict__ hf0, u16* __restrict__ hf1,
         float* __restrict__ cbuf, float* __restrict__ out, int p) {
  extern __shared__ __align__(16) char smem[];
  const int blk = blockIdx.x;
  const int role = blk & 1;
  const int mtile = (blk >> 1) & 3;
  const int dsl = blk >> 3;
  const bool act = role ? (p >= 1) : (p < Tn);
  if (!act) return;

  const int tid = threadIdx.x;
  const int rf = tid >> 6, lane = tid & 63;
  const int Rp = (p & 1) ^ 1, Wp = p & 1;
  const int tcur = role ? (p - 1) : p;

  {
    const char* gsrc = reinterpret_cast<const char*>(Wf)
                     + (size_t)(role * 32 + dsl) * 131072 + tid * 16;
    char* lds = smem + tid * 16;
#pragma unroll
    for (int i = 0; i < 32; ++i)
      GLOAD_LDS(gsrc + i * 4096, lds + i * 4096);
  }

  const char* h0base = reinterpret_cast<const char*>(hf0);
  const char* h1base = reinterpret_cast<const char*>(hf1);
  const size_t hRp = (size_t)Rp * 262144 + (size_t)mtile * 65536;
  const int aoff = rf * 16384 + lane * 16;

  const char* Alo;
  const char* Ahi;
  if (role == 0) {
    Alo = reinterpret_cast<const char*>(xf) + ((size_t)mtile * Tn + p) * 65536 + aoff;
    Ahi = h0base + hRp + aoff;
  } else {
    Alo = h0base + hRp + aoff;
    Ahi = h1base + hRp + aoff;
  }
  const char* WL = smem + lane * 16;

  short8 ca0 = LDA(0), ca1 = LDA(1), ca2 = LDA(2), ca3 = LDA(3);

  const int d0 = dsl * 16 + (lane & 15);
  const float* bias = role ? b1 : b0;
  const float bg0 = bias[d0], bg1 = bias[512 + d0], bg2 = bias[1024 + d0], bg3 = bias[1536 + d0];
  const int rowB = mtile * 64 + rf * 16 + (lane >> 4) * 4;
  int sl[4];
#pragma unroll
  for (int e = 0; e < 4; ++e) sl[e] = seq[rowB + e];

  const int kkd = dsl >> 1;
  const int lane_t_base = ((((dsl & 1) << 1) | ((lane & 15) >> 3)) << 4) + (lane >> 4) * 4;
  const size_t hoff0 = (size_t)mtile * 32768 + (size_t)(rf * 16 + kkd) * 512
                     + (size_t)lane_t_base * 8 + (lane & 7);

  u16 h0nraw[4];
  if (role) {
    const u16* hr = reinterpret_cast<const u16*>(h0base) + (size_t)Rp * 131072;
#pragma unroll
    for (int e = 0; e < 4; ++e) h0nraw[e] = hr[hoff0 + e * 8];
  }
  float* cme = cbuf + ((size_t)blk * 256 + tid) * 4;
  float cpre[4];
#pragma unroll
  for (int e = 0; e < 4; ++e) cpre[e] = cme[e];
  u16* hfSelf = role ? hf1 : hf0;
  const u16* hprev = hfSelf + (size_t)Rp * 131072;
  u16 hp16[4];
#pragma unroll
  for (int e = 0; e < 4; ++e) hp16[e] = hprev[hoff0 + e * 8];

  __syncthreads();

  f32x4 ac0 = {0.f,0.f,0.f,0.f}, ac1 = {0.f,0.f,0.f,0.f};
  f32x4 ac2 = {0.f,0.f,0.f,0.f}, ac3 = {0.f,0.f,0.f,0.f};
  short8 na0, na1, na2, na3;
#pragma unroll
  for (int c = 0; c < 8; ++c) {
    const int k0 = c * 4;
    if (c < 7) {
      na0 = LDA(k0 + 4); na1 = LDA(k0 + 5); na2 = LDA(k0 + 6); na3 = LDA(k0 + 7);
    }
#pragma unroll
    for (int j = 0; j < 4; ++j) {
      const int kk = k0 + j;
      short8 a = (j == 0) ? ca0 : (j == 1) ? ca1 : (j == 2) ? ca2 : ca3;
      short8 w0 = *reinterpret_cast<const short8*>(WL + kk * 1024);
      short8 w1 = *reinterpret_cast<const short8*>(WL + 32768 + kk * 1024);
      short8 w2 = *reinterpret_cast<const short8*>(WL + 65536 + kk * 1024);
      short8 w3 = *reinterpret_cast<const short8*>(WL + 98304 + kk * 1024);
      ac0 = MFMA16(a, w0, ac0, 0, 0, 0);
      ac1 = MFMA16(a, w1, ac1, 0, 0, 0);
      ac2 = MFMA16(a, w2, ac2, 0, 0, 0);
      ac3 = MFMA16(a, w3, ac3, 0, 0, 0);
    }
    ca0 = na0; ca1 = na1; ca2 = na2; ca3 = na3;
  }

  u16* stg = reinterpret_cast<u16*>(smem + 131072);
#pragma unroll
  for (int e = 0; e < 4; ++e) {
    float zi = ac0[e] + bg0, zj = ac1[e] + bg1, zf = ac2[e] + bg2, zo = ac3[e] + bg3;
    float cprev = cpre[e];
    float cn = cprev * sigm(zf + 1.0f) + sigm(zi) * tanhe(zj);
    float hn = tanhe(cn) * sigm(zo);
    bool valid = tcur < sl[e];
    union { float f; u32 u; } hp; hp.u = ((u32)hp16[e]) << 16;
    float hkeep = valid ? hn : hp.f;
    cme[e] = valid ? cn : cprev;
    stg[rf * 256 + (((lane & 15) >> 3) * 16 + (lane >> 4) * 4 + e) * 8 + (lane & 7)] = f2bf(hkeep);
    if (role) {
      union { float f; u32 u; } hv; hv.u = ((u32)h0nraw[e]) << 16;
      out[((size_t)(rowB + e) * Tn + tcur) * Dn + d0] = valid ? (hn + hv.f) : 0.0f;
    }
  }
  __syncthreads();
  {
    const int rft = tid >> 6, u = tid & 63;
    u64 v = reinterpret_cast<const u64*>(stg)[tid];
    u64* hw8 = reinterpret_cast<u64*>(hfSelf + (size_t)Wp * 131072);
    size_t o8 = (size_t)((mtile * 4 + rft) * 16 + kkd) * 128 + ((dsl & 1) * 32 + (u >> 1)) * 2 + (u & 1);
    hw8[o8] = v;
  }
}

extern "C" void kernel_launch(void* const* d_in, const int* in_sizes, int n_in,
                              void* d_out, int out_size, void* d_ws, size_t ws_size,
                              hipStream_t stream) {
  (void)in_sizes; (void)n_in; (void)out_size; (void)ws_size;
  const float* x  = (const float*)d_in[0];
  const int* seq  = (const int*)d_in[1];
  const float* W0 = (const float*)d_in[2];
  const float* b0 = (const float*)d_in[3];
  const float* W1 = (const float*)d_in[4];
  const float* b1 = (const float*)d_in[5];
  float* out = (float*)d_out;

  char* ws = (char*)d_ws;
  // ws layout (bytes):
  //   xf   : 0          .. 52,428,800   bf16 fragment-major x
  //   Wf   : 52,428,800 .. 60,817,408   bf16 fragment-major weights
  //   hf0  : 60,817,408 .. 61,341,696   bf16 frag h0 [2 parities] (role0-local, L2)
  //   hf1  : 61,341,696 .. 61,865,984   bf16 frag h1 [2 parities] (role1-local, L2)
  //   bar  : 61,865,984 .. 61,867,008   u32 flags (4 mtiles x 64 blocks)
  //   hx   : 61,870,080 .. 62,394,368   h0 EXPORT copy [2 parities] (LLC, cross-XCD)
  //          (bar..62,914,560 doubles as cbuf for the fallback path)
  u16*  xf   = (u16*)(ws);
  u16*  Wf   = (u16*)(ws + 52428800);
  u16*  hf0  = (u16*)(ws + 60817408);
  u16*  hf1  = (u16*)(ws + 61341696);
  u32*  bar  = (u32*)(ws + 61865984);
  u16*  hx   = (u16*)(ws + 61870080);
  float* cbuf = (float*)(ws + 61865984);

  hipMemsetAsync(ws + 60817408, 0, 2097152, stream);  // h frags + flags + export
  hipLaunchKernelGGL(cvt_x_frag, dim3(12800), dim3(256), 0, stream, x, xf);
  hipLaunchKernelGGL(cvt_w_frag, dim3(1024), dim3(256), 0, stream, W0, W1, Wf);

  hipFuncSetAttribute((const void*)rnn_persist,
                      hipFuncAttributeMaxDynamicSharedMemorySize, 133120);
  hipFuncSetAttribute((const void*)rnn_step,
                      hipFuncAttributeMaxDynamicSharedMemorySize, 133120);

  void* args[] = { (void*)&xf, (void*)&Wf, (void*)&b0, (void*)&b1, (void*)&seq,
                   (void*)&hf0, (void*)&hf1, (void*)&hx, (void*)&bar, (void*)&out };
  hipError_t err = hipLaunchCooperativeKernel((void*)rnn_persist, dim3(256), dim3(256),
                                              args, 133120, stream);
  if (err != hipSuccess) {
    // fallback: proven multi-launch skewed pipeline
    for (int p = 0; p <= Tn; ++p) {
      hipLaunchKernelGGL(rnn_step, dim3(256), dim3(256), 133120, stream,
                         xf, Wf, b0, b1, seq, hf0, hf1, cbuf, out, p);
    }
  }
}

// Round 12
// 1119.180 us; speedup vs baseline: 1.8782x; 1.0119x over previous
//
#include <hip/hip_runtime.h>

using short8 = __attribute__((ext_vector_type(8))) short;
using f32x4  = __attribute__((ext_vector_type(4))) float;
typedef unsigned short u16;
typedef unsigned int   u32;
typedef unsigned long long u64;

constexpr int Bn = 256;   // batch
constexpr int Tn = 200;   // time steps
constexpr int Dn = 512;   // hidden size

__device__ __forceinline__ u16 f2bf(float x) {
  union { float f; unsigned u; } v; v.f = x;
  unsigned r = v.u + 0x7FFFu + ((v.u >> 16) & 1u);  // RNE
  return (u16)(r >> 16);
}
__device__ __forceinline__ float sigm(float x) { return 1.0f / (1.0f + __expf(-x)); }
__device__ __forceinline__ float tanhe(float x) { return 1.0f - 2.0f / (__expf(2.0f * x) + 1.0f); }

// ---------- prep: x f32 [B][T][D] -> xf fragment-major bf16 [mtile4][t200][rf4][kkd16][lane64][8] ----------
__global__ void cvt_x_frag(const float* __restrict__ x, u16* __restrict__ xf) {
  int i = blockIdx.x * 256 + threadIdx.x;          // exactly 3,276,800 lane-tasks
  int lane = i & 63;
  int kkd  = (i >> 6) & 15;
  int rf   = (i >> 10) & 3;
  int mt_t = i >> 12;                              // mtile*200 + t
  int t = mt_t % 200, mtile = mt_t / 200;
  int row = mtile * 64 + rf * 16 + (lane & 15);
  int k0  = kkd * 32 + (lane >> 4) * 8;
  const float* s = x + ((size_t)row * Tn + t) * Dn + k0;
  float4 v0 = *reinterpret_cast<const float4*>(s);
  float4 v1 = *reinterpret_cast<const float4*>(s + 4);
  short8 r;
  r[0]=(short)f2bf(v0.x); r[1]=(short)f2bf(v0.y); r[2]=(short)f2bf(v0.z); r[3]=(short)f2bf(v0.w);
  r[4]=(short)f2bf(v1.x); r[5]=(short)f2bf(v1.y); r[6]=(short)f2bf(v1.z); r[7]=(short)f2bf(v1.w);
  reinterpret_cast<short8*>(xf)[i] = r;
}

// ---------- prep: W [1024][2048] f32 -> Wf fragment-major bf16 [role2][dsl32][g4][kk32][lane64][8] ----------
__global__ void cvt_w_frag(const float* __restrict__ W0, const float* __restrict__ W1,
                           u16* __restrict__ Wf) {
  __shared__ u16 T[64][65];                        // [k][n] tile, padded
  int b = blockIdx.x;                              // 1024 blocks: role(2) x kt(16) x nt(32)
  int nt = b & 31, kt = (b >> 5) & 15, role = b >> 9;
  const float* W = role ? W1 : W0;
  int t = threadIdx.x;
  int k0 = kt * 64, n0 = nt * 64;
  int kr = t >> 6, nl = t & 63;
#pragma unroll
  for (int r = 0; r < 16; ++r) {
    int k = r * 4 + kr;
    T[k][nl] = f2bf(W[(size_t)(k0 + k) * 2048 + n0 + nl]);   // coalesced over n
  }
  __syncthreads();
  int g = n0 >> 9;
  int dslBase = (n0 & 511) >> 4;
  int kkBase  = k0 >> 5;
  int lane = t & 63, grp = t >> 6;
  int lr = lane & 15, lk = lane >> 4;
#pragma unroll
  for (int c = grp; c < 8; c += 4) {
    int dslL = c & 3, kkL = c >> 2;
    int dsl = dslBase + dslL, kk = kkBase + kkL;
    short8 v;
#pragma unroll
    for (int e = 0; e < 8; ++e)
      v[e] = (short)T[kkL * 32 + lk * 8 + e][dslL * 16 + lr];
    *reinterpret_cast<short8*>(Wf + ((((size_t)(role * 32 + dsl) * 4 + g) * 32 + kk) * 64 + lane) * 8) = v;
  }
}

#define MFMA16 __builtin_amdgcn_mfma_f32_16x16x32_bf16
#define GLOAD_LDS(g, l) __builtin_amdgcn_global_load_lds(                    \
    (const __attribute__((address_space(1))) void*)(g),                      \
    (__attribute__((address_space(3))) void*)(l), 16, 0, 0)

// LLC-coherent (cross-XCD) 4x16B load batch: bypasses L1+L2 via sc0 sc1
#define ISS4C(A0, A1, A2, A3, P)                                             \
  asm volatile("global_load_dwordx4 %0, %4, off sc0 sc1\n\t"                 \
               "global_load_dwordx4 %1, %4, off offset:1024 sc0 sc1\n\t"     \
               "global_load_dwordx4 %2, %4, off offset:2048 sc0 sc1\n\t"     \
               "global_load_dwordx4 %3, %4, off offset:3072 sc0 sc1"         \
               : "=v"(A0), "=v"(A1), "=v"(A2), "=v"(A3) : "v"(P))
// XCD-L2-coherent 4x16B load batch: sc0 only (L1 bypassed, served by local L2).
#define ISS4L(A0, A1, A2, A3, P)                                             \
  asm volatile("global_load_dwordx4 %0, %4, off sc0\n\t"                     \
               "global_load_dwordx4 %1, %4, off offset:1024 sc0\n\t"         \
               "global_load_dwordx4 %2, %4, off offset:2048 sc0\n\t"         \
               "global_load_dwordx4 %3, %4, off offset:3072 sc0"             \
               : "=v"(A0), "=v"(A1), "=v"(A2), "=v"(A3) : "v"(P))
// normal cached 4x16B load batch (iteration-private x data)
#define ISS4N(A0, A1, A2, A3, P)                                             \
  asm volatile("global_load_dwordx4 %0, %4, off\n\t"                         \
               "global_load_dwordx4 %1, %4, off offset:1024\n\t"             \
               "global_load_dwordx4 %2, %4, off offset:2048\n\t"             \
               "global_load_dwordx4 %3, %4, off offset:3072"                 \
               : "=v"(A0), "=v"(A1), "=v"(A2), "=v"(A3) : "v"(P))
// counted wait + scheduling fence (v2-exact: MFMA must not hoist above the wait)
#define WAITV(N)                                                             \
  asm volatile("s_waitcnt vmcnt(" #N ")" ::: "memory");                      \
  __builtin_amdgcn_sched_barrier(0)
// one kki step for TWO row-fragments sharing one set of W reads (LDS-BW halving)
#define MMK2(alo, ahi, kki) {                                                \
    short8 w0 = *reinterpret_cast<const short8*>(WK + (kki) * 1024);         \
    short8 w1 = *reinterpret_cast<const short8*>(WK + 32768 + (kki) * 1024); \
    short8 w2 = *reinterpret_cast<const short8*>(WK + 65536 + (kki) * 1024); \
    short8 w3 = *reinterpret_cast<const short8*>(WK + 98304 + (kki) * 1024); \
    pa0 = MFMA16(alo, w0, pa0, 0, 0, 0); qa0 = MFMA16(ahi, w0, qa0, 0, 0, 0);\
    pa1 = MFMA16(alo, w1, pa1, 0, 0, 0); qa1 = MFMA16(ahi, w1, qa1, 0, 0, 0);\
    pa2 = MFMA16(alo, w2, pa2, 0, 0, 0); qa2 = MFMA16(ahi, w2, qa2, 0, 0, 0);\
    pa3 = MFMA16(alo, w3, pa3, 0, 0, 0); qa3 = MFMA16(ahi, w3, qa3, 0, 0, 0); }

// ---------- persistent cooperative kernel: entire 200-step scan in ONE launch ----------
// v12 = v11 (XCD-local h + export + fast-first, proven 1176us) with K-SPLIT WAVE
// PAIRING to halve the dominant LDS W-stream while KEEPING 4 waves (v5's mistake):
//   wave w: rr=w&1, ks=w>>1. Computes partials for rfrags {2rr,2rr+1} over K-half ks
//   (16 kki x MMK2 = 128 MFMA/wave, unchanged) reading only its K-half of W from LDS
//   (64 ds_read_b128 = 64KB/wave, HALF of v11). Partial combine: wave ships rfrag
//   rO=2rr+(1-ks) partials to LDS red[], keeps rF=2rr+ks; after __syncthreads, adds
//   partner's partial for rF. Epilogue/stg/h-store/o8/hoff0: v8-exact, keyed by rF.
//   A-load source per wave is single-type: role0 ks0=x(ISS4N), ks1=h0-local(ISS4L);
//   role1 ks0=hx-export(ISS4C), ks1=h1-local(ISS4L). Ladder: 4 hra + 8x4 A-batches
//   = 36 outstanding, WAITV(24/16/8/0) per chunk — straight-line issue->consume.
// LDS: [0,131072) W, [131072,147456) red (4 slots x 4 g x 64 lanes x 16B), [147456,149504) stg.
extern "C" __global__ void __launch_bounds__(256, 1)
rnn_persist(const u16* __restrict__ xf, const u16* __restrict__ Wf,
            const float* __restrict__ b0, const float* __restrict__ b1,
            const int* __restrict__ seq,
            u16* __restrict__ hf0, u16* __restrict__ hf1, u16* __restrict__ hx,
            u32* __restrict__ bar, float* __restrict__ out) {
  extern __shared__ __align__(16) char smem[];
  const int blk = blockIdx.x;
  const int q = blk & 7;
  const int role = q & 1;
  const int mtile = q >> 1;
  const int dsl = blk >> 3;
  const int tid = threadIdx.x;
  const int wid = tid >> 6, lane = tid & 63;
  const int rr = wid & 1, ks = wid >> 1;
  const int rLo = rr * 2;                          // lower rfrag this wave computes
  const int rF  = rr * 2 + ks;                     // rfrag this wave FINALIZES
  const int rO  = rr * 2 + (1 - ks);               // rfrag this wave SHIPS

  // ---- one-time W staging: 32 direct global->LDS 16B ops per thread ----
  {
    const char* gsrc = reinterpret_cast<const char*>(Wf)
                     + (size_t)(role * 32 + dsl) * 131072 + tid * 16;
    char* lds = smem + tid * 16;
#pragma unroll
    for (int i = 0; i < 32; ++i)
      GLOAD_LDS(gsrc + i * 4096, lds + i * 4096);
  }

  const char* xfb = reinterpret_cast<const char*>(xf);
  const char* h0b = reinterpret_cast<const char*>(hf0);
  const char* h1b = reinterpret_cast<const char*>(hf1);
  const char* hxb = reinterpret_cast<const char*>(hx);
  const char* WK = smem + lane * 16 + ks * 16384;  // this wave's K-half of W
  f32x4* redv = reinterpret_cast<f32x4*>(smem + 131072);
  u16* stg = reinterpret_cast<u16*>(smem + 147456);

  const int d0 = dsl * 16 + (lane & 15);
  const float* bias = role ? b1 : b0;
  const float bg0 = bias[d0], bg1 = bias[512 + d0], bg2 = bias[1024 + d0], bg3 = bias[1536 + d0];
  const int rowB = mtile * 64 + rF * 16 + (lane >> 4) * 4;
  int sl[4];
#pragma unroll
  for (int e = 0; e < 4; ++e) sl[e] = seq[rowB + e];

  // fragment-layout u16 offset of this thread's (rowB+e, d0) values in h buffers (keyed rF)
  const int kkd = dsl >> 1;
  const int lane_t_base = ((((dsl & 1) << 1) | ((lane & 15) >> 3)) << 4) + (lane >> 4) * 4;
  const size_t hoff0 = (size_t)mtile * 32768 + (size_t)(rF * 16 + kkd) * 512
                     + (size_t)lane_t_base * 8 + (lane & 7);

  u16* hfSelf = role ? hf1 : hf0;
  const size_t o8 = (size_t)((mtile * 4 + rF) * 16 + kkd) * 128
                  + ((dsl & 1) * 32 + (lane >> 1)) * 2 + (lane & 1);
  u32* flagme = bar + mtile * 64 + role * 32 + dsl;
  const u32* fb = bar + mtile * 64 + tid;          // poll address (tid<64 only)

  const int aoffLo = rLo * 16384 + lane * 16;      // A bases for the two rfrags
  const int aoffHi = aoffLo + 16384;

  float creg[4]  = {0.f, 0.f, 0.f, 0.f};           // c-state in registers (rfrag rF)
  float hkeep[4] = {0.f, 0.f, 0.f, 0.f};           // copy-through h in registers

  __syncthreads();                                 // W resident in LDS from here on

#pragma unroll 1
  for (int p = 0; p <= Tn; ++p) {
    const bool act = role ? (p >= 1) : (p < Tn);
    const int Rp = (p & 1) ^ 1, Wp = p & 1;
    if (act) {
      const int tcur = role ? (p - 1) : p;
      const size_t hRp = (size_t)Rp * 262144 + (size_t)mtile * 65536;

      short8 A0,A1,A2,A3,A4,A5,A6,A7,A8,A9,A10,A11,A12,A13,A14,A15;  // rfrag rLo
      short8 B0,B1,B2,B3,B4,B5,B6,B7,B8,B9,B10,B11,B12,B13,B14,B15;  // rfrag rLo+1
      u32 hn0, hn1, hn2, hn3;

      // (1) residual h0n (keyed rF): role1 reads cross-XCD EXPORT (sc0sc1);
      //     role0 issues same-count local loads (sc0) for vmcnt parity.
      if (role) {
        const char* hra = hxb + (size_t)Rp * 262144 + hoff0 * 2;
        asm volatile("global_load_ushort %0, %4, off sc0 sc1\n\t"
                     "global_load_ushort %1, %4, off offset:16 sc0 sc1\n\t"
                     "global_load_ushort %2, %4, off offset:32 sc0 sc1\n\t"
                     "global_load_ushort %3, %4, off offset:48 sc0 sc1"
                     : "=v"(hn0), "=v"(hn1), "=v"(hn2), "=v"(hn3) : "v"(hra));
      } else {
        const char* hra = h0b + (size_t)Rp * 262144 + hoff0 * 2;
        asm volatile("global_load_ushort %0, %4, off sc0\n\t"
                     "global_load_ushort %1, %4, off offset:16 sc0\n\t"
                     "global_load_ushort %2, %4, off offset:32 sc0\n\t"
                     "global_load_ushort %3, %4, off offset:48 sc0"
                     : "=v"(hn0), "=v"(hn1), "=v"(hn2), "=v"(hn3) : "v"(hra));
      }
      // (2) A loads: this wave's K-half for BOTH rfrags, 8 batches of 4 (interleaved)
      if (role == 0 && ks == 0) {                  // x, normal cached
        const char* base = xfb + ((size_t)mtile * Tn + p) * 65536;
        const char* Lb = base + aoffLo; const char* Hb = base + aoffHi;
        ISS4N(A0,A1,A2,A3,    Lb);          ISS4N(B0,B1,B2,B3,    Hb);
        ISS4N(A4,A5,A6,A7,    Lb + 4096);   ISS4N(B4,B5,B6,B7,    Hb + 4096);
        ISS4N(A8,A9,A10,A11,  Lb + 8192);   ISS4N(B8,B9,B10,B11,  Hb + 8192);
        ISS4N(A12,A13,A14,A15,Lb + 12288);  ISS4N(B12,B13,B14,B15,Hb + 12288);
      } else if (role == 0) {                      // h0 local, sc0
        const char* base = h0b + hRp;
        const char* Lb = base + aoffLo; const char* Hb = base + aoffHi;
        ISS4L(A0,A1,A2,A3,    Lb);          ISS4L(B0,B1,B2,B3,    Hb);
        ISS4L(A4,A5,A6,A7,    Lb + 4096);   ISS4L(B4,B5,B6,B7,    Hb + 4096);
        ISS4L(A8,A9,A10,A11,  Lb + 8192);   ISS4L(B8,B9,B10,B11,  Hb + 8192);
        ISS4L(A12,A13,A14,A15,Lb + 12288);  ISS4L(B12,B13,B14,B15,Hb + 12288);
      } else if (ks == 0) {                        // hx export, LLC
        const char* base = hxb + hRp;
        const char* Lb = base + aoffLo; const char* Hb = base + aoffHi;
        ISS4C(A0,A1,A2,A3,    Lb);          ISS4C(B0,B1,B2,B3,    Hb);
        ISS4C(A4,A5,A6,A7,    Lb + 4096);   ISS4C(B4,B5,B6,B7,    Hb + 4096);
        ISS4C(A8,A9,A10,A11,  Lb + 8192);   ISS4C(B8,B9,B10,B11,  Hb + 8192);
        ISS4C(A12,A13,A14,A15,Lb + 12288);  ISS4C(B12,B13,B14,B15,Hb + 12288);
      } else {                                     // h1 local, sc0
        const char* base = h1b + hRp;
        const char* Lb = base + aoffLo; const char* Hb = base + aoffHi;
        ISS4L(A0,A1,A2,A3,    Lb);          ISS4L(B0,B1,B2,B3,    Hb);
        ISS4L(A4,A5,A6,A7,    Lb + 4096);   ISS4L(B4,B5,B6,B7,    Hb + 4096);
        ISS4L(A8,A9,A10,A11,  Lb + 8192);   ISS4L(B8,B9,B10,B11,  Hb + 8192);
        ISS4L(A12,A13,A14,A15,Lb + 12288);  ISS4L(B12,B13,B14,B15,Hb + 12288);
      }

      f32x4 pa0 = {0.f,0.f,0.f,0.f}, pa1 = {0.f,0.f,0.f,0.f};
      f32x4 pa2 = {0.f,0.f,0.f,0.f}, pa3 = {0.f,0.f,0.f,0.f};
      f32x4 qa0 = {0.f,0.f,0.f,0.f}, qa1 = {0.f,0.f,0.f,0.f};
      f32x4 qa2 = {0.f,0.f,0.f,0.f}, qa3 = {0.f,0.f,0.f,0.f};

      // ladder: 36 outstanding (4 hra + 32 A); chunk c needs 4+8(c+1) retired
      WAITV(24); MMK2(A0,B0,0)   MMK2(A1,B1,1)   MMK2(A2,B2,2)   MMK2(A3,B3,3)
      WAITV(16); MMK2(A4,B4,4)   MMK2(A5,B5,5)   MMK2(A6,B6,6)   MMK2(A7,B7,7)
      WAITV(8);  MMK2(A8,B8,8)   MMK2(A9,B9,9)   MMK2(A10,B10,10) MMK2(A11,B11,11)
      WAITV(0);  MMK2(A12,B12,12) MMK2(A13,B13,13) MMK2(A14,B14,14) MMK2(A15,B15,15)

      // (3) pairwise K-half combine: ship rO partials, keep rF partials
      {
        f32x4 s0 = (ks == 0) ? qa0 : pa0;
        f32x4 s1 = (ks == 0) ? qa1 : pa1;
        f32x4 s2 = (ks == 0) ? qa2 : pa2;
        f32x4 s3 = (ks == 0) ? qa3 : pa3;
        redv[(rO * 4 + 0) * 64 + lane] = s0;
        redv[(rO * 4 + 1) * 64 + lane] = s1;
        redv[(rO * 4 + 2) * 64 + lane] = s2;
        redv[(rO * 4 + 3) * 64 + lane] = s3;
      }
      __syncthreads();                             // partials visible block-wide
      f32x4 ac0 = (ks == 0) ? pa0 : qa0;
      f32x4 ac1 = (ks == 0) ? pa1 : qa1;
      f32x4 ac2 = (ks == 0) ? pa2 : qa2;
      f32x4 ac3 = (ks == 0) ? pa3 : qa3;
      ac0 += redv[(rF * 4 + 0) * 64 + lane];
      ac1 += redv[(rF * 4 + 1) * 64 + lane];
      ac2 += redv[(rF * 4 + 2) * 64 + lane];
      ac3 += redv[(rF * 4 + 3) * 64 + lane];

      // epilogue (v8-exact shape, keyed rF): gates (i,j,f,o), state update, out
      const u32 hnv[4] = {hn0, hn1, hn2, hn3};
#pragma unroll
      for (int e = 0; e < 4; ++e) {
        float zi = ac0[e] + bg0, zj = ac1[e] + bg1, zf = ac2[e] + bg2, zo = ac3[e] + bg3;
        float cprev = creg[e];
        float cn = cprev * sigm(zf + 1.0f) + sigm(zi) * tanhe(zj);
        float hn = tanhe(cn) * sigm(zo);
        bool valid = tcur < sl[e];
        float hk = valid ? hn : hkeep[e];
        creg[e] = valid ? cn : cprev;
        hkeep[e] = hk;
        stg[rF * 256 + (((lane & 15) >> 3) * 16 + (lane >> 4) * 4 + e) * 8 + (lane & 7)] = f2bf(hk);
        if (role) {
          union { float f; u32 u; } hv; hv.u = hnv[e] << 16;               // h0n (bf16)
          out[((size_t)(rowB + e) * Tn + tcur) * Dn + d0] = valid ? (hn + hv.f) : 0.0f;
        }
      }
      // stg region for rF written only by this wave: own-LDS drain suffices (v6-proven)
      asm volatile("s_waitcnt lgkmcnt(0)" ::: "memory");
      {  // coalesced h store: role-local L2 copy (sc0); role0 also exports to LLC
        u64 v = reinterpret_cast<const u64*>(stg)[rF * 64 + lane];
        u64* ha = reinterpret_cast<u64*>(hfSelf + (size_t)Wp * 131072) + o8;
        asm volatile("global_store_dwordx2 %0, %1, off sc0" :: "v"(ha), "v"(v) : "memory");
        if (role == 0) {
          u64* he = reinterpret_cast<u64*>(hx + (size_t)Wp * 131072) + o8;
          asm volatile("global_store_dwordx2 %0, %1, off sc0 sc1" :: "v"(he), "v"(v) : "memory");
        }
      }
      asm volatile("s_waitcnt vmcnt(0)" ::: "memory");   // h slices committed (L2 / LLC)
    }

    if (p == Tn) break;                            // nothing reads after the last step

    // ---- per-mtile 64-block barrier: per-block flag store + one-wave poll (v8-exact) ----
    __syncthreads();                               // all block writes drained
    if (tid == 0) {
      u32 tv = (u32)(p + 1);
      asm volatile("global_store_dword %0, %1, off sc0 sc1" :: "v"(flagme), "v"(tv) : "memory");
    }
    if (tid < 64) {                                // wave 0: lane l watches flag l
      const int tgt = p + 1;
      u32 fv;
      do {
        asm volatile("global_load_dword %0, %1, off sc0 sc1\n\t"
                     "s_waitcnt vmcnt(0)"
                     : "=v"(fv) : "v"(fb) : "memory");
      } while (!__all((int)fv >= tgt));
    }
    __syncthreads();
  }
}

// ---------- fallback per-step kernel (only used if cooperative launch is rejected) ----------
#define MMK(av, kk) {                                                        \
    short8 w0 = *reinterpret_cast<const short8*>(WL + (kk) * 1024);          \
    short8 w1 = *reinterpret_cast<const short8*>(WL + 32768 + (kk) * 1024);  \
    short8 w2 = *reinterpret_cast<const short8*>(WL + 65536 + (kk) * 1024);  \
    short8 w3 = *reinterpret_cast<const short8*>(WL + 98304 + (kk) * 1024);  \
    ac0 = MFMA16(av, w0, ac0, 0, 0, 0);                                      \
    ac1 = MFMA16(av, w1, ac1, 0, 0, 0);                                      \
    ac2 = MFMA16(av, w2, ac2, 0, 0, 0);                                      \
    ac3 = MFMA16(av, w3, ac3, 0, 0, 0); }
#define LDA(kk) (*reinterpret_cast<const short8*>(                           \
    (kk) < 16 ? (Alo + (size_t)(kk) * 1024) : (Ahi + (size_t)((kk) - 16) * 1024)))

extern "C" __global__ void __launch_bounds__(256, 1)
rnn_step(const u16* __restrict__ xf, const u16* __restrict__ Wf,
         const float* __restrict__ b0, const float* __restrict__ b1,
         const int* __restrict__ seq,
         u16* __restrict__ hf0, u16* __restrict__ hf1,
         float* __restrict__ cbuf, float* __restrict__ out, int p) {
  extern __shared__ __align__(16) char smem[];
  const int blk = blockIdx.x;
  const int role = blk & 1;
  const int mtile = (blk >> 1) & 3;
  const int dsl = blk >> 3;
  const bool act = role ? (p >= 1) : (p < Tn);
  if (!act) return;

  const int tid = threadIdx.x;
  const int rf = tid >> 6, lane = tid & 63;
  const int Rp = (p & 1) ^ 1, Wp = p & 1;
  const int tcur = role ? (p - 1) : p;

  {
    const char* gsrc = reinterpret_cast<const char*>(Wf)
                     + (size_t)(role * 32 + dsl) * 131072 + tid * 16;
    char* lds = smem + tid * 16;
#pragma unroll
    for (int i = 0; i < 32; ++i)
      GLOAD_LDS(gsrc + i * 4096, lds + i * 4096);
  }

  const char* h0base = reinterpret_cast<const char*>(hf0);
  const char* h1base = reinterpret_cast<const char*>(hf1);
  const size_t hRp = (size_t)Rp * 262144 + (size_t)mtile * 65536;
  const int aoff = rf * 16384 + lane * 16;

  const char* Alo;
  const char* Ahi;
  if (role == 0) {
    Alo = reinterpret_cast<const char*>(xf) + ((size_t)mtile * Tn + p) * 65536 + aoff;
    Ahi = h0base + hRp + aoff;
  } else {
    Alo = h0base + hRp + aoff;
    Ahi = h1base + hRp + aoff;
  }
  const char* WL = smem + lane * 16;

  short8 ca0 = LDA(0), ca1 = LDA(1), ca2 = LDA(2), ca3 = LDA(3);

  const int d0 = dsl * 16 + (lane & 15);
  const float* bias = role ? b1 : b0;
  const float bg0 = bias[d0], bg1 = bias[512 + d0], bg2 = bias[1024 + d0], bg3 = bias[1536 + d0];
  const int rowB = mtile * 64 + rf * 16 + (lane >> 4) * 4;
  int sl[4];
#pragma unroll
  for (int e = 0; e < 4; ++e) sl[e] = seq[rowB + e];

  const int kkd = dsl >> 1;
  const int lane_t_base = ((((dsl & 1) << 1) | ((lane & 15) >> 3)) << 4) + (lane >> 4) * 4;
  const size_t hoff0 = (size_t)mtile * 32768 + (size_t)(rf * 16 + kkd) * 512
                     + (size_t)lane_t_base * 8 + (lane & 7);

  u16 h0nraw[4];
  if (role) {
    const u16* hr = reinterpret_cast<const u16*>(h0base) + (size_t)Rp * 131072;
#pragma unroll
    for (int e = 0; e < 4; ++e) h0nraw[e] = hr[hoff0 + e * 8];
  }
  float* cme = cbuf + ((size_t)blk * 256 + tid) * 4;
  float cpre[4];
#pragma unroll
  for (int e = 0; e < 4; ++e) cpre[e] = cme[e];
  u16* hfSelf = role ? hf1 : hf0;
  const u16* hprev = hfSelf + (size_t)Rp * 131072;
  u16 hp16[4];
#pragma unroll
  for (int e = 0; e < 4; ++e) hp16[e] = hprev[hoff0 + e * 8];

  __syncthreads();

  f32x4 ac0 = {0.f,0.f,0.f,0.f}, ac1 = {0.f,0.f,0.f,0.f};
  f32x4 ac2 = {0.f,0.f,0.f,0.f}, ac3 = {0.f,0.f,0.f,0.f};
  short8 na0, na1, na2, na3;
#pragma unroll
  for (int c = 0; c < 8; ++c) {
    const int k0 = c * 4;
    if (c < 7) {
      na0 = LDA(k0 + 4); na1 = LDA(k0 + 5); na2 = LDA(k0 + 6); na3 = LDA(k0 + 7);
    }
#pragma unroll
    for (int j = 0; j < 4; ++j) {
      const int kk = k0 + j;
      short8 a = (j == 0) ? ca0 : (j == 1) ? ca1 : (j == 2) ? ca2 : ca3;
      MMK(a, kk)
    }
    ca0 = na0; ca1 = na1; ca2 = na2; ca3 = na3;
  }

  u16* stg = reinterpret_cast<u16*>(smem + 131072);
#pragma unroll
  for (int e = 0; e < 4; ++e) {
    float zi = ac0[e] + bg0, zj = ac1[e] + bg1, zf = ac2[e] + bg2, zo = ac3[e] + bg3;
    float cprev = cpre[e];
    float cn = cprev * sigm(zf + 1.0f) + sigm(zi) * tanhe(zj);
    float hn = tanhe(cn) * sigm(zo);
    bool valid = tcur < sl[e];
    union { float f; u32 u; } hp; hp.u = ((u32)hp16[e]) << 16;
    float hkeep = valid ? hn : hp.f;
    cme[e] = valid ? cn : cprev;
    stg[rf * 256 + (((lane & 15) >> 3) * 16 + (lane >> 4) * 4 + e) * 8 + (lane & 7)] = f2bf(hkeep);
    if (role) {
      union { float f; u32 u; } hv; hv.u = ((u32)h0nraw[e]) << 16;
      out[((size_t)(rowB + e) * Tn + tcur) * Dn + d0] = valid ? (hn + hv.f) : 0.0f;
    }
  }
  __syncthreads();
  {
    const int rft = tid >> 6, u = tid & 63;
    u64 v = reinterpret_cast<const u64*>(stg)[tid];
    u64* hw8 = reinterpret_cast<u64*>(hfSelf + (size_t)Wp * 131072);
    size_t o8 = (size_t)((mtile * 4 + rft) * 16 + kkd) * 128 + ((dsl & 1) * 32 + (u >> 1)) * 2 + (u & 1);
    hw8[o8] = v;
  }
}

extern "C" void kernel_launch(void* const* d_in, const int* in_sizes, int n_in,
                              void* d_out, int out_size, void* d_ws, size_t ws_size,
                              hipStream_t stream) {
  (void)in_sizes; (void)n_in; (void)out_size; (void)ws_size;
  const float* x  = (const float*)d_in[0];
  const int* seq  = (const int*)d_in[1];
  const float* W0 = (const float*)d_in[2];
  const float* b0 = (const float*)d_in[3];
  const float* W1 = (const float*)d_in[4];
  const float* b1 = (const float*)d_in[5];
  float* out = (float*)d_out;

  char* ws = (char*)d_ws;
  // ws layout (bytes):
  //   xf   : 0          .. 52,428,800   bf16 fragment-major x
  //   Wf   : 52,428,800 .. 60,817,408   bf16 fragment-major weights
  //   hf0  : 60,817,408 .. 61,341,696   bf16 frag h0 [2 parities] (role0-local, L2)
  //   hf1  : 61,341,696 .. 61,865,984   bf16 frag h1 [2 parities] (role1-local, L2)
  //   bar  : 61,865,984 .. 61,867,008   u32 flags (4 mtiles x 64 blocks)
  //   hx   : 61,870,080 .. 62,394,368   h0 EXPORT copy [2 parities] (LLC, cross-XCD)
  //          (bar..62,914,560 doubles as cbuf for the fallback path)
  u16*  xf   = (u16*)(ws);
  u16*  Wf   = (u16*)(ws + 52428800);
  u16*  hf0  = (u16*)(ws + 60817408);
  u16*  hf1  = (u16*)(ws + 61341696);
  u32*  bar  = (u32*)(ws + 61865984);
  u16*  hx   = (u16*)(ws + 61870080);
  float* cbuf = (float*)(ws + 61865984);

  hipMemsetAsync(ws + 60817408, 0, 2097152, stream);  // h frags + flags + export
  hipLaunchKernelGGL(cvt_x_frag, dim3(12800), dim3(256), 0, stream, x, xf);
  hipLaunchKernelGGL(cvt_w_frag, dim3(1024), dim3(256), 0, stream, W0, W1, Wf);

  hipFuncSetAttribute((const void*)rnn_persist,
                      hipFuncAttributeMaxDynamicSharedMemorySize, 149504);
  hipFuncSetAttribute((const void*)rnn_step,
                      hipFuncAttributeMaxDynamicSharedMemorySize, 133120);

  void* args[] = { (void*)&xf, (void*)&Wf, (void*)&b0, (void*)&b1, (void*)&seq,
                   (void*)&hf0, (void*)&hf1, (void*)&hx, (void*)&bar, (void*)&out };
  hipError_t err = hipLaunchCooperativeKernel((void*)rnn_persist, dim3(256), dim3(256),
                                              args, 149504, stream);
  if (err != hipSuccess) {
    // fallback: proven multi-launch skewed pipeline
    for (int p = 0; p <= Tn; ++p) {
      hipLaunchKernelGGL(rnn_step, dim3(256), dim3(256), 133120, stream,
                         xf, Wf, b0, b1, seq, hf0, hf1, cbuf, out, p);
    }
  }
}

// Round 14
// 1109.803 us; speedup vs baseline: 1.8941x; 1.0084x over previous
//
#include <hip/hip_runtime.h>

using short8 = __attribute__((ext_vector_type(8))) short;
using f32x4  = __attribute__((ext_vector_type(4))) float;
typedef unsigned short u16;
typedef unsigned int   u32;
typedef unsigned long long u64;

constexpr int Bn = 256;   // batch
constexpr int Tn = 200;   // time steps
constexpr int Dn = 512;   // hidden size

__device__ __forceinline__ u16 f2bf(float x) {
  union { float f; unsigned u; } v; v.f = x;
  unsigned r = v.u + 0x7FFFu + ((v.u >> 16) & 1u);  // RNE
  return (u16)(r >> 16);
}
__device__ __forceinline__ float sigm(float x) { return 1.0f / (1.0f + __expf(-x)); }
__device__ __forceinline__ float tanhe(float x) { return 1.0f - 2.0f / (__expf(2.0f * x) + 1.0f); }

// ---------- prep: x f32 [B][T][D] -> xf fragment-major bf16 [mtile4][t200][rf4][kkd16][lane64][8] ----------
__global__ void cvt_x_frag(const float* __restrict__ x, u16* __restrict__ xf) {
  int i = blockIdx.x * 256 + threadIdx.x;          // exactly 3,276,800 lane-tasks
  int lane = i & 63;
  int kkd  = (i >> 6) & 15;
  int rf   = (i >> 10) & 3;
  int mt_t = i >> 12;                              // mtile*200 + t
  int t = mt_t % 200, mtile = mt_t / 200;
  int row = mtile * 64 + rf * 16 + (lane & 15);
  int k0  = kkd * 32 + (lane >> 4) * 8;
  const float* s = x + ((size_t)row * Tn + t) * Dn + k0;
  float4 v0 = *reinterpret_cast<const float4*>(s);
  float4 v1 = *reinterpret_cast<const float4*>(s + 4);
  short8 r;
  r[0]=(short)f2bf(v0.x); r[1]=(short)f2bf(v0.y); r[2]=(short)f2bf(v0.z); r[3]=(short)f2bf(v0.w);
  r[4]=(short)f2bf(v1.x); r[5]=(short)f2bf(v1.y); r[6]=(short)f2bf(v1.z); r[7]=(short)f2bf(v1.w);
  reinterpret_cast<short8*>(xf)[i] = r;
}

// ---------- prep: W [1024][2048] f32 -> Wf fragment-major bf16 [role2][dsl32][g4][kk32][lane64][8] ----------
__global__ void cvt_w_frag(const float* __restrict__ W0, const float* __restrict__ W1,
                           u16* __restrict__ Wf) {
  __shared__ u16 T[64][65];                        // [k][n] tile, padded
  int b = blockIdx.x;                              // 1024 blocks: role(2) x kt(16) x nt(32)
  int nt = b & 31, kt = (b >> 5) & 15, role = b >> 9;
  const float* W = role ? W1 : W0;
  int t = threadIdx.x;
  int k0 = kt * 64, n0 = nt * 64;
  int kr = t >> 6, nl = t & 63;
#pragma unroll
  for (int r = 0; r < 16; ++r) {
    int k = r * 4 + kr;
    T[k][nl] = f2bf(W[(size_t)(k0 + k) * 2048 + n0 + nl]);   // coalesced over n
  }
  __syncthreads();
  int g = n0 >> 9;
  int dslBase = (n0 & 511) >> 4;
  int kkBase  = k0 >> 5;
  int lane = t & 63, grp = t >> 6;
  int lr = lane & 15, lk = lane >> 4;
#pragma unroll
  for (int c = grp; c < 8; c += 4) {
    int dslL = c & 3, kkL = c >> 2;
    int dsl = dslBase + dslL, kk = kkBase + kkL;
    short8 v;
#pragma unroll
    for (int e = 0; e < 8; ++e)
      v[e] = (short)T[kkL * 32 + lk * 8 + e][dslL * 16 + lr];
    *reinterpret_cast<short8*>(Wf + ((((size_t)(role * 32 + dsl) * 4 + g) * 32 + kk) * 64 + lane) * 8) = v;
  }
}

#define MFMA16 __builtin_amdgcn_mfma_f32_16x16x32_bf16
#define GLOAD_LDS(g, l) __builtin_amdgcn_global_load_lds(                    \
    (const __attribute__((address_space(1))) void*)(g),                      \
    (__attribute__((address_space(3))) void*)(l), 16, 0, 0)

// LLC-coherent (cross-XCD) 4x16B load batch: bypasses L1+L2 via sc0 sc1
#define ISS4C(A0, A1, A2, A3, P)                                             \
  asm volatile("global_load_dwordx4 %0, %4, off sc0 sc1\n\t"                 \
               "global_load_dwordx4 %1, %4, off offset:1024 sc0 sc1\n\t"     \
               "global_load_dwordx4 %2, %4, off offset:2048 sc0 sc1\n\t"     \
               "global_load_dwordx4 %3, %4, off offset:3072 sc0 sc1"         \
               : "=v"(A0), "=v"(A1), "=v"(A2), "=v"(A3) : "v"(P))
// XCD-L2-coherent 4x16B load batch: sc0 only (L1 bypassed, served by local L2).
#define ISS4L(A0, A1, A2, A3, P)                                             \
  asm volatile("global_load_dwordx4 %0, %4, off sc0\n\t"                     \
               "global_load_dwordx4 %1, %4, off offset:1024 sc0\n\t"         \
               "global_load_dwordx4 %2, %4, off offset:2048 sc0\n\t"         \
               "global_load_dwordx4 %3, %4, off offset:3072 sc0"             \
               : "=v"(A0), "=v"(A1), "=v"(A2), "=v"(A3) : "v"(P))
// normal cached 4x16B load batch (iteration-private x data)
#define ISS4N(A0, A1, A2, A3, P)                                             \
  asm volatile("global_load_dwordx4 %0, %4, off\n\t"                         \
               "global_load_dwordx4 %1, %4, off offset:1024\n\t"             \
               "global_load_dwordx4 %2, %4, off offset:2048\n\t"             \
               "global_load_dwordx4 %3, %4, off offset:3072"                 \
               : "=v"(A0), "=v"(A1), "=v"(A2), "=v"(A3) : "v"(P))
// counted wait + scheduling fence (v2-exact: MFMA must not hoist above the wait)
#define WAITV(N)                                                             \
  asm volatile("s_waitcnt vmcnt(" #N ")" ::: "memory");                      \
  __builtin_amdgcn_sched_barrier(0)
// one kki step for TWO row-fragments sharing one set of W reads (LDS-BW halving)
#define MMK2(alo, ahi, kki) {                                                \
    short8 w0 = *reinterpret_cast<const short8*>(WK + (kki) * 1024);         \
    short8 w1 = *reinterpret_cast<const short8*>(WK + 32768 + (kki) * 1024); \
    short8 w2 = *reinterpret_cast<const short8*>(WK + 65536 + (kki) * 1024); \
    short8 w3 = *reinterpret_cast<const short8*>(WK + 98304 + (kki) * 1024); \
    pa0 = MFMA16(alo, w0, pa0, 0, 0, 0); qa0 = MFMA16(ahi, w0, qa0, 0, 0, 0);\
    pa1 = MFMA16(alo, w1, pa1, 0, 0, 0); qa1 = MFMA16(ahi, w1, qa1, 0, 0, 0);\
    pa2 = MFMA16(alo, w2, pa2, 0, 0, 0); qa2 = MFMA16(ahi, w2, qa2, 0, 0, 0);\
    pa3 = MFMA16(alo, w3, pa3, 0, 0, 0); qa3 = MFMA16(ahi, w3, qa3, 0, 0, 0); }

// ---------- persistent cooperative kernel: entire 200-step scan in ONE launch ----------
// v14 = v12 VERBATIM (best harness-verified: 1119us total / 1146us persist).
// v13's serial-chain slimming bundle crashed (like v7/v9/v10); reverted per discipline.
// Structure: XCD-local h (sc0) + LLC export for role0->role1 (sc0sc1) + fast-first
// single-type A ladders + K-split wave pairing (halved LDS W-stream, 4 waves kept).
// LDS: [0,131072) W, [131072,147456) red, [147456,149504) stg.
extern "C" __global__ void __launch_bounds__(256, 1)
rnn_persist(const u16* __restrict__ xf, const u16* __restrict__ Wf,
            const float* __restrict__ b0, const float* __restrict__ b1,
            const int* __restrict__ seq,
            u16* __restrict__ hf0, u16* __restrict__ hf1, u16* __restrict__ hx,
            u32* __restrict__ bar, float* __restrict__ out) {
  extern __shared__ __align__(16) char smem[];
  const int blk = blockIdx.x;
  const int q = blk & 7;
  const int role = q & 1;
  const int mtile = q >> 1;
  const int dsl = blk >> 3;
  const int tid = threadIdx.x;
  const int wid = tid >> 6, lane = tid & 63;
  const int rr = wid & 1, ks = wid >> 1;
  const int rLo = rr * 2;                          // lower rfrag this wave computes
  const int rF  = rr * 2 + ks;                     // rfrag this wave FINALIZES
  const int rO  = rr * 2 + (1 - ks);               // rfrag this wave SHIPS

  // ---- one-time W staging: 32 direct global->LDS 16B ops per thread ----
  {
    const char* gsrc = reinterpret_cast<const char*>(Wf)
                     + (size_t)(role * 32 + dsl) * 131072 + tid * 16;
    char* lds = smem + tid * 16;
#pragma unroll
    for (int i = 0; i < 32; ++i)
      GLOAD_LDS(gsrc + i * 4096, lds + i * 4096);
  }

  const char* xfb = reinterpret_cast<const char*>(xf);
  const char* h0b = reinterpret_cast<const char*>(hf0);
  const char* h1b = reinterpret_cast<const char*>(hf1);
  const char* hxb = reinterpret_cast<const char*>(hx);
  const char* WK = smem + lane * 16 + ks * 16384;  // this wave's K-half of W
  f32x4* redv = reinterpret_cast<f32x4*>(smem + 131072);
  u16* stg = reinterpret_cast<u16*>(smem + 147456);

  const int d0 = dsl * 16 + (lane & 15);
  const float* bias = role ? b1 : b0;
  const float bg0 = bias[d0], bg1 = bias[512 + d0], bg2 = bias[1024 + d0], bg3 = bias[1536 + d0];
  const int rowB = mtile * 64 + rF * 16 + (lane >> 4) * 4;
  int sl[4];
#pragma unroll
  for (int e = 0; e < 4; ++e) sl[e] = seq[rowB + e];

  // fragment-layout u16 offset of this thread's (rowB+e, d0) values in h buffers (keyed rF)
  const int kkd = dsl >> 1;
  const int lane_t_base = ((((dsl & 1) << 1) | ((lane & 15) >> 3)) << 4) + (lane >> 4) * 4;
  const size_t hoff0 = (size_t)mtile * 32768 + (size_t)(rF * 16 + kkd) * 512
                     + (size_t)lane_t_base * 8 + (lane & 7);

  u16* hfSelf = role ? hf1 : hf0;
  const size_t o8 = (size_t)((mtile * 4 + rF) * 16 + kkd) * 128
                  + ((dsl & 1) * 32 + (lane >> 1)) * 2 + (lane & 1);
  u32* flagme = bar + mtile * 64 + role * 32 + dsl;
  const u32* fb = bar + mtile * 64 + tid;          // poll address (tid<64 only)

  const int aoffLo = rLo * 16384 + lane * 16;      // A bases for the two rfrags
  const int aoffHi = aoffLo + 16384;

  float creg[4]  = {0.f, 0.f, 0.f, 0.f};           // c-state in registers (rfrag rF)
  float hkeep[4] = {0.f, 0.f, 0.f, 0.f};           // copy-through h in registers

  __syncthreads();                                 // W resident in LDS from here on

#pragma unroll 1
  for (int p = 0; p <= Tn; ++p) {
    const bool act = role ? (p >= 1) : (p < Tn);
    const int Rp = (p & 1) ^ 1, Wp = p & 1;
    if (act) {
      const int tcur = role ? (p - 1) : p;
      const size_t hRp = (size_t)Rp * 262144 + (size_t)mtile * 65536;

      short8 A0,A1,A2,A3,A4,A5,A6,A7,A8,A9,A10,A11,A12,A13,A14,A15;  // rfrag rLo
      short8 B0,B1,B2,B3,B4,B5,B6,B7,B8,B9,B10,B11,B12,B13,B14,B15;  // rfrag rLo+1
      u32 hn0, hn1, hn2, hn3;

      // (1) residual h0n (keyed rF): role1 reads cross-XCD EXPORT (sc0sc1);
      //     role0 issues same-count local loads (sc0) for vmcnt parity.
      if (role) {
        const char* hra = hxb + (size_t)Rp * 262144 + hoff0 * 2;
        asm volatile("global_load_ushort %0, %4, off sc0 sc1\n\t"
                     "global_load_ushort %1, %4, off offset:16 sc0 sc1\n\t"
                     "global_load_ushort %2, %4, off offset:32 sc0 sc1\n\t"
                     "global_load_ushort %3, %4, off offset:48 sc0 sc1"
                     : "=v"(hn0), "=v"(hn1), "=v"(hn2), "=v"(hn3) : "v"(hra));
      } else {
        const char* hra = h0b + (size_t)Rp * 262144 + hoff0 * 2;
        asm volatile("global_load_ushort %0, %4, off sc0\n\t"
                     "global_load_ushort %1, %4, off offset:16 sc0\n\t"
                     "global_load_ushort %2, %4, off offset:32 sc0\n\t"
                     "global_load_ushort %3, %4, off offset:48 sc0"
                     : "=v"(hn0), "=v"(hn1), "=v"(hn2), "=v"(hn3) : "v"(hra));
      }
      // (2) A loads: this wave's K-half for BOTH rfrags, 8 batches of 4 (interleaved)
      if (role == 0 && ks == 0) {                  // x, normal cached
        const char* base = xfb + ((size_t)mtile * Tn + p) * 65536;
        const char* Lb = base + aoffLo; const char* Hb = base + aoffHi;
        ISS4N(A0,A1,A2,A3,    Lb);          ISS4N(B0,B1,B2,B3,    Hb);
        ISS4N(A4,A5,A6,A7,    Lb + 4096);   ISS4N(B4,B5,B6,B7,    Hb + 4096);
        ISS4N(A8,A9,A10,A11,  Lb + 8192);   ISS4N(B8,B9,B10,B11,  Hb + 8192);
        ISS4N(A12,A13,A14,A15,Lb + 12288);  ISS4N(B12,B13,B14,B15,Hb + 12288);
      } else if (role == 0) {                      // h0 local, sc0
        const char* base = h0b + hRp;
        const char* Lb = base + aoffLo; const char* Hb = base + aoffHi;
        ISS4L(A0,A1,A2,A3,    Lb);          ISS4L(B0,B1,B2,B3,    Hb);
        ISS4L(A4,A5,A6,A7,    Lb + 4096);   ISS4L(B4,B5,B6,B7,    Hb + 4096);
        ISS4L(A8,A9,A10,A11,  Lb + 8192);   ISS4L(B8,B9,B10,B11,  Hb + 8192);
        ISS4L(A12,A13,A14,A15,Lb + 12288);  ISS4L(B12,B13,B14,B15,Hb + 12288);
      } else if (ks == 0) {                        // hx export, LLC
        const char* base = hxb + hRp;
        const char* Lb = base + aoffLo; const char* Hb = base + aoffHi;
        ISS4C(A0,A1,A2,A3,    Lb);          ISS4C(B0,B1,B2,B3,    Hb);
        ISS4C(A4,A5,A6,A7,    Lb + 4096);   ISS4C(B4,B5,B6,B7,    Hb + 4096);
        ISS4C(A8,A9,A10,A11,  Lb + 8192);   ISS4C(B8,B9,B10,B11,  Hb + 8192);
        ISS4C(A12,A13,A14,A15,Lb + 12288);  ISS4C(B12,B13,B14,B15,Hb + 12288);
      } else {                                     // h1 local, sc0
        const char* base = h1b + hRp;
        const char* Lb = base + aoffLo; const char* Hb = base + aoffHi;
        ISS4L(A0,A1,A2,A3,    Lb);          ISS4L(B0,B1,B2,B3,    Hb);
        ISS4L(A4,A5,A6,A7,    Lb + 4096);   ISS4L(B4,B5,B6,B7,    Hb + 4096);
        ISS4L(A8,A9,A10,A11,  Lb + 8192);   ISS4L(B8,B9,B10,B11,  Hb + 8192);
        ISS4L(A12,A13,A14,A15,Lb + 12288);  ISS4L(B12,B13,B14,B15,Hb + 12288);
      }

      f32x4 pa0 = {0.f,0.f,0.f,0.f}, pa1 = {0.f,0.f,0.f,0.f};
      f32x4 pa2 = {0.f,0.f,0.f,0.f}, pa3 = {0.f,0.f,0.f,0.f};
      f32x4 qa0 = {0.f,0.f,0.f,0.f}, qa1 = {0.f,0.f,0.f,0.f};
      f32x4 qa2 = {0.f,0.f,0.f,0.f}, qa3 = {0.f,0.f,0.f,0.f};

      // ladder: 36 outstanding (4 hra + 32 A); chunk c needs 4+8(c+1) retired
      WAITV(24); MMK2(A0,B0,0)   MMK2(A1,B1,1)   MMK2(A2,B2,2)   MMK2(A3,B3,3)
      WAITV(16); MMK2(A4,B4,4)   MMK2(A5,B5,5)   MMK2(A6,B6,6)   MMK2(A7,B7,7)
      WAITV(8);  MMK2(A8,B8,8)   MMK2(A9,B9,9)   MMK2(A10,B10,10) MMK2(A11,B11,11)
      WAITV(0);  MMK2(A12,B12,12) MMK2(A13,B13,13) MMK2(A14,B14,14) MMK2(A15,B15,15)

      // (3) pairwise K-half combine: ship rO partials, keep rF partials
      {
        f32x4 s0 = (ks == 0) ? qa0 : pa0;
        f32x4 s1 = (ks == 0) ? qa1 : pa1;
        f32x4 s2 = (ks == 0) ? qa2 : pa2;
        f32x4 s3 = (ks == 0) ? qa3 : pa3;
        redv[(rO * 4 + 0) * 64 + lane] = s0;
        redv[(rO * 4 + 1) * 64 + lane] = s1;
        redv[(rO * 4 + 2) * 64 + lane] = s2;
        redv[(rO * 4 + 3) * 64 + lane] = s3;
      }
      __syncthreads();                             // partials visible block-wide
      f32x4 ac0 = (ks == 0) ? pa0 : qa0;
      f32x4 ac1 = (ks == 0) ? pa1 : qa1;
      f32x4 ac2 = (ks == 0) ? pa2 : qa2;
      f32x4 ac3 = (ks == 0) ? pa3 : qa3;
      ac0 += redv[(rF * 4 + 0) * 64 + lane];
      ac1 += redv[(rF * 4 + 1) * 64 + lane];
      ac2 += redv[(rF * 4 + 2) * 64 + lane];
      ac3 += redv[(rF * 4 + 3) * 64 + lane];

      // epilogue (v8-exact shape, keyed rF): gates (i,j,f,o), state update, out
      const u32 hnv[4] = {hn0, hn1, hn2, hn3};
#pragma unroll
      for (int e = 0; e < 4; ++e) {
        float zi = ac0[e] + bg0, zj = ac1[e] + bg1, zf = ac2[e] + bg2, zo = ac3[e] + bg3;
        float cprev = creg[e];
        float cn = cprev * sigm(zf + 1.0f) + sigm(zi) * tanhe(zj);
        float hn = tanhe(cn) * sigm(zo);
        bool valid = tcur < sl[e];
        float hk = valid ? hn : hkeep[e];
        creg[e] = valid ? cn : cprev;
        hkeep[e] = hk;
        stg[rF * 256 + (((lane & 15) >> 3) * 16 + (lane >> 4) * 4 + e) * 8 + (lane & 7)] = f2bf(hk);
        if (role) {
          union { float f; u32 u; } hv; hv.u = hnv[e] << 16;               // h0n (bf16)
          out[((size_t)(rowB + e) * Tn + tcur) * Dn + d0] = valid ? (hn + hv.f) : 0.0f;
        }
      }
      // stg region for rF written only by this wave: own-LDS drain suffices
      asm volatile("s_waitcnt lgkmcnt(0)" ::: "memory");
      {  // coalesced h store: role-local L2 copy (sc0); role0 also exports to LLC
        u64 v = reinterpret_cast<const u64*>(stg)[rF * 64 + lane];
        u64* ha = reinterpret_cast<u64*>(hfSelf + (size_t)Wp * 131072) + o8;
        asm volatile("global_store_dwordx2 %0, %1, off sc0" :: "v"(ha), "v"(v) : "memory");
        if (role == 0) {
          u64* he = reinterpret_cast<u64*>(hx + (size_t)Wp * 131072) + o8;
          asm volatile("global_store_dwordx2 %0, %1, off sc0 sc1" :: "v"(he), "v"(v) : "memory");
        }
      }
      asm volatile("s_waitcnt vmcnt(0)" ::: "memory");   // h slices committed (L2 / LLC)
    }

    if (p == Tn) break;                            // nothing reads after the last step

    // ---- per-mtile 64-block barrier: per-block flag store + one-wave poll (v8-exact) ----
    __syncthreads();                               // all block writes drained
    if (tid == 0) {
      u32 tv = (u32)(p + 1);
      asm volatile("global_store_dword %0, %1, off sc0 sc1" :: "v"(flagme), "v"(tv) : "memory");
    }
    if (tid < 64) {                                // wave 0: lane l watches flag l
      const int tgt = p + 1;
      u32 fv;
      do {
        asm volatile("global_load_dword %0, %1, off sc0 sc1\n\t"
                     "s_waitcnt vmcnt(0)"
                     : "=v"(fv) : "v"(fb) : "memory");
      } while (!__all((int)fv >= tgt));
    }
    __syncthreads();
  }
}

// ---------- fallback per-step kernel (only used if cooperative launch is rejected) ----------
#define MMK(av, kk) {                                                        \
    short8 w0 = *reinterpret_cast<const short8*>(WL + (kk) * 1024);          \
    short8 w1 = *reinterpret_cast<const short8*>(WL + 32768 + (kk) * 1024);  \
    short8 w2 = *reinterpret_cast<const short8*>(WL + 65536 + (kk) * 1024);  \
    short8 w3 = *reinterpret_cast<const short8*>(WL + 98304 + (kk) * 1024);  \
    ac0 = MFMA16(av, w0, ac0, 0, 0, 0);                                      \
    ac1 = MFMA16(av, w1, ac1, 0, 0, 0);                                      \
    ac2 = MFMA16(av, w2, ac2, 0, 0, 0);                                      \
    ac3 = MFMA16(av, w3, ac3, 0, 0, 0); }
#define LDA(kk) (*reinterpret_cast<const short8*>(                           \
    (kk) < 16 ? (Alo + (size_t)(kk) * 1024) : (Ahi + (size_t)((kk) - 16) * 1024)))

extern "C" __global__ void __launch_bounds__(256, 1)
rnn_step(const u16* __restrict__ xf, const u16* __restrict__ Wf,
         const float* __restrict__ b0, const float* __restrict__ b1,
         const int* __restrict__ seq,
         u16* __restrict__ hf0, u16* __restrict__ hf1,
         float* __restrict__ cbuf, float* __restrict__ out, int p) {
  extern __shared__ __align__(16) char smem[];
  const int blk = blockIdx.x;
  const int role = blk & 1;
  const int mtile = (blk >> 1) & 3;
  const int dsl = blk >> 3;
  const bool act = role ? (p >= 1) : (p < Tn);
  if (!act) return;

  const int tid = threadIdx.x;
  const int rf = tid >> 6, lane = tid & 63;
  const int Rp = (p & 1) ^ 1, Wp = p & 1;
  const int tcur = role ? (p - 1) : p;

  {
    const char* gsrc = reinterpret_cast<const char*>(Wf)
                     + (size_t)(role * 32 + dsl) * 131072 + tid * 16;
    char* lds = smem + tid * 16;
#pragma unroll
    for (int i = 0; i < 32; ++i)
      GLOAD_LDS(gsrc + i * 4096, lds + i * 4096);
  }

  const char* h0base = reinterpret_cast<const char*>(hf0);
  const char* h1base = reinterpret_cast<const char*>(hf1);
  const size_t hRp = (size_t)Rp * 262144 + (size_t)mtile * 65536;
  const int aoff = rf * 16384 + lane * 16;

  const char* Alo;
  const char* Ahi;
  if (role == 0) {
    Alo = reinterpret_cast<const char*>(xf) + ((size_t)mtile * Tn + p) * 65536 + aoff;
    Ahi = h0base + hRp + aoff;
  } else {
    Alo = h0base + hRp + aoff;
    Ahi = h1base + hRp + aoff;
  }
  const char* WL = smem + lane * 16;

  short8 ca0 = LDA(0), ca1 = LDA(1), ca2 = LDA(2), ca3 = LDA(3);

  const int d0 = dsl * 16 + (lane & 15);
  const float* bias = role ? b1 : b0;
  const float bg0 = bias[d0], bg1 = bias[512 + d0], bg2 = bias[1024 + d0], bg3 = bias[1536 + d0];
  const int rowB = mtile * 64 + rf * 16 + (lane >> 4) * 4;
  int sl[4];
#pragma unroll
  for (int e = 0; e < 4; ++e) sl[e] = seq[rowB + e];

  const int kkd = dsl >> 1;
  const int lane_t_base = ((((dsl & 1) << 1) | ((lane & 15) >> 3)) << 4) + (lane >> 4) * 4;
  const size_t hoff0 = (size_t)mtile * 32768 + (size_t)(rf * 16 + kkd) * 512
                     + (size_t)lane_t_base * 8 + (lane & 7);

  u16 h0nraw[4];
  if (role) {
    const u16* hr = reinterpret_cast<const u16*>(h0base) + (size_t)Rp * 131072;
#pragma unroll
    for (int e = 0; e < 4; ++e) h0nraw[e] = hr[hoff0 + e * 8];
  }
  float* cme = cbuf + ((size_t)blk * 256 + tid) * 4;
  float cpre[4];
#pragma unroll
  for (int e = 0; e < 4; ++e) cpre[e] = cme[e];
  u16* hfSelf = role ? hf1 : hf0;
  const u16* hprev = hfSelf + (size_t)Rp * 131072;
  u16 hp16[4];
#pragma unroll
  for (int e = 0; e < 4; ++e) hp16[e] = hprev[hoff0 + e * 8];

  __syncthreads();

  f32x4 ac0 = {0.f,0.f,0.f,0.f}, ac1 = {0.f,0.f,0.f,0.f};
  f32x4 ac2 = {0.f,0.f,0.f,0.f}, ac3 = {0.f,0.f,0.f,0.f};
  short8 na0, na1, na2, na3;
#pragma unroll
  for (int c = 0; c < 8; ++c) {
    const int k0 = c * 4;
    if (c < 7) {
      na0 = LDA(k0 + 4); na1 = LDA(k0 + 5); na2 = LDA(k0 + 6); na3 = LDA(k0 + 7);
    }
#pragma unroll
    for (int j = 0; j < 4; ++j) {
      const int kk = k0 + j;
      short8 a = (j == 0) ? ca0 : (j == 1) ? ca1 : (j == 2) ? ca2 : ca3;
      MMK(a, kk)
    }
    ca0 = na0; ca1 = na1; ca2 = na2; ca3 = na3;
  }

  u16* stg = reinterpret_cast<u16*>(smem + 131072);
#pragma unroll
  for (int e = 0; e < 4; ++e) {
    float zi = ac0[e] + bg0, zj = ac1[e] + bg1, zf = ac2[e] + bg2, zo = ac3[e] + bg3;
    float cprev = cpre[e];
    float cn = cprev * sigm(zf + 1.0f) + sigm(zi) * tanhe(zj);
    float hn = tanhe(cn) * sigm(zo);
    bool valid = tcur < sl[e];
    union { float f; u32 u; } hp; hp.u = ((u32)hp16[e]) << 16;
    float hkeep = valid ? hn : hp.f;
    cme[e] = valid ? cn : cprev;
    stg[rf * 256 + (((lane & 15) >> 3) * 16 + (lane >> 4) * 4 + e) * 8 + (lane & 7)] = f2bf(hkeep);
    if (role) {
      union { float f; u32 u; } hv; hv.u = ((u32)h0nraw[e]) << 16;
      out[((size_t)(rowB + e) * Tn + tcur) * Dn + d0] = valid ? (hn + hv.f) : 0.0f;
    }
  }
  __syncthreads();
  {
    const int rft = tid >> 6, u = tid & 63;
    u64 v = reinterpret_cast<const u64*>(stg)[tid];
    u64* hw8 = reinterpret_cast<u64*>(hfSelf + (size_t)Wp * 131072);
    size_t o8 = (size_t)((mtile * 4 + rft) * 16 + kkd) * 128 + ((dsl & 1) * 32 + (u >> 1)) * 2 + (u & 1);
    hw8[o8] = v;
  }
}

extern "C" void kernel_launch(void* const* d_in, const int* in_sizes, int n_in,
                              void* d_out, int out_size, void* d_ws, size_t ws_size,
                              hipStream_t stream) {
  (void)in_sizes; (void)n_in; (void)out_size; (void)ws_size;
  const float* x  = (const float*)d_in[0];
  const int* seq  = (const int*)d_in[1];
  const float* W0 = (const float*)d_in[2];
  const float* b0 = (const float*)d_in[3];
  const float* W1 = (const float*)d_in[4];
  const float* b1 = (const float*)d_in[5];
  float* out = (float*)d_out;

  char* ws = (char*)d_ws;
  // ws layout (bytes):
  //   xf   : 0          .. 52,428,800   bf16 fragment-major x
  //   Wf   : 52,428,800 .. 60,817,408   bf16 fragment-major weights
  //   hf0  : 60,817,408 .. 61,341,696   bf16 frag h0 [2 parities] (role0-local, L2)
  //   hf1  : 61,341,696 .. 61,865,984   bf16 frag h1 [2 parities] (role1-local, L2)
  //   bar  : 61,865,984 .. 61,867,008   u32 flags (4 mtiles x 64 blocks)
  //   hx   : 61,870,080 .. 62,394,368   h0 EXPORT copy [2 parities] (LLC, cross-XCD)
  //          (bar..62,914,560 doubles as cbuf for the fallback path)
  u16*  xf   = (u16*)(ws);
  u16*  Wf   = (u16*)(ws + 52428800);
  u16*  hf0  = (u16*)(ws + 60817408);
  u16*  hf1  = (u16*)(ws + 61341696);
  u32*  bar  = (u32*)(ws + 61865984);
  u16*  hx   = (u16*)(ws + 61870080);
  float* cbuf = (float*)(ws + 61865984);

  hipMemsetAsync(ws + 60817408, 0, 2097152, stream);  // h frags + flags + export
  hipLaunchKernelGGL(cvt_x_frag, dim3(12800), dim3(256), 0, stream, x, xf);
  hipLaunchKernelGGL(cvt_w_frag, dim3(1024), dim3(256), 0, stream, W0, W1, Wf);

  hipFuncSetAttribute((const void*)rnn_persist,
                      hipFuncAttributeMaxDynamicSharedMemorySize, 149504);
  hipFuncSetAttribute((const void*)rnn_step,
                      hipFuncAttributeMaxDynamicSharedMemorySize, 133120);

  void* args[] = { (void*)&xf, (void*)&Wf, (void*)&b0, (void*)&b1, (void*)&seq,
                   (void*)&hf0, (void*)&hf1, (void*)&hx, (void*)&bar, (void*)&out };
  hipError_t err = hipLaunchCooperativeKernel((void*)rnn_persist, dim3(256), dim3(256),
                                              args, 149504, stream);
  if (err != hipSuccess) {
    // fallback: proven multi-launch skewed pipeline
    for (int p = 0; p <= Tn; ++p) {
      hipLaunchKernelGGL(rnn_step, dim3(256), dim3(256), 133120, stream,
                         xf, Wf, b0, b1, seq, hf0, hf1, cbuf, out, p);
    }
  }
}